// Round 1
// baseline (9403.579 us; speedup 1.0000x reference)
//
#include <hip/hip_runtime.h>
#include <math.h>

#define BN 8
#define TN 1024
#define HN 192
#define NHN 2
#define KCN 96
#define LN 6
#define FFNN 768
#define OUTN 192

// ---------------------------------------------------------------------------
// Embedding: x[b,c,t] = emb[tok[b,t], c] * sqrt(H) * (t < len[b])
// ---------------------------------------------------------------------------
__global__ void k_embed(const int* __restrict__ tok, const int* __restrict__ lens,
                        const float* __restrict__ emb, float* __restrict__ x) {
    int idx = blockIdx.x * 256 + threadIdx.x;
    int t = idx % TN;
    int c = (idx / TN) % HN;
    int b = idx / (TN * HN);
    float v = 0.f;
    if (t < lens[b]) v = emb[tok[b * TN + t] * HN + c] * 13.856406460551018f; // sqrt(192)
    x[idx] = v;
}

// ---------------------------------------------------------------------------
// Generic batched GEMM / 1-D conv (SAME, K taps):
//   Y[b,m,t] = act( sum_{c,tap} W[m,c,tap] * Xin[b,c,t+tap-P] + bias[m] )
// W layout (M, Cin, TAPS) row-major. X,Y layout (B, C, T) row-major.
// MASK_IN : Xin = X * (t < len).  MASK_OUT: Y *= (t < len).  RELU: max(0,.)
// Block: 256 threads -> 64(m) x 64(t) tile, 4x4 per thread. K-step 16.
// ---------------------------------------------------------------------------
template <int TAPS, bool RELU, bool MASK_IN, bool MASK_OUT>
__global__ __launch_bounds__(256) void k_gemm(
        const float* __restrict__ W, const float* __restrict__ X,
        const float* __restrict__ bias, float* __restrict__ Y,
        const int* __restrict__ lens, int M, int Cin) {
    constexpr int P = (TAPS - 1) / 2;
    constexpr int TW = 64 + 2 * P;
    __shared__ float Wt[TAPS][16][64];
    __shared__ float Xt[16][TW];

    const int b = blockIdx.z;
    const int m0 = blockIdx.y * 64;
    const int t0 = blockIdx.x * 64;
    const int len = lens[b];
    const int tid = threadIdx.x;
    const int tx = tid % 16, ty = tid / 16;

    float acc[4][4];
#pragma unroll
    for (int i = 0; i < 4; ++i)
#pragma unroll
        for (int j = 0; j < 4; ++j) acc[i][j] = 0.f;

    for (int c0 = 0; c0 < Cin; c0 += 16) {
        for (int idx = tid; idx < 64 * 16 * TAPS; idx += 256) {
            int mm = idx / (16 * TAPS);
            int rem = idx % (16 * TAPS);
            int cc = rem / TAPS;
            int tap = rem % TAPS;
            Wt[tap][cc][mm] = W[((m0 + mm) * Cin + (c0 + cc)) * TAPS + tap];
        }
        for (int idx = tid; idx < 16 * TW; idx += 256) {
            int cc = idx / TW;
            int tt = idx % TW;
            int t = t0 + tt - P;
            float v = 0.f;
            if (t >= 0 && t < TN) {
                v = X[(b * Cin + c0 + cc) * TN + t];
                if (MASK_IN && t >= len) v = 0.f;
            }
            Xt[cc][tt] = v;
        }
        __syncthreads();
#pragma unroll
        for (int kk = 0; kk < 16; ++kk) {
            float xv[4 + 2 * P];
#pragma unroll
            for (int j = 0; j < 4 + 2 * P; ++j) xv[j] = Xt[kk][tx * 4 + j];
#pragma unroll
            for (int tap = 0; tap < TAPS; ++tap) {
                float a[4];
#pragma unroll
                for (int i = 0; i < 4; ++i) a[i] = Wt[tap][kk][ty * 4 + i];
#pragma unroll
                for (int i = 0; i < 4; ++i)
#pragma unroll
                    for (int j = 0; j < 4; ++j) acc[i][j] += a[i] * xv[j + tap];
            }
        }
        __syncthreads();
    }

#pragma unroll
    for (int i = 0; i < 4; ++i) {
        int m = m0 + ty * 4 + i;
        float bs = bias[m];
#pragma unroll
        for (int j = 0; j < 4; ++j) {
            int t = t0 + tx * 4 + j;
            float v = acc[i][j] + bs;
            if (RELU) v = fmaxf(v, 0.f);
            if (MASK_OUT && t >= len) v = 0.f;
            Y[(b * M + m) * TN + t] = v;
        }
    }
}

// ---------------------------------------------------------------------------
// Flash attention with windowed relative position bias (WIN=4).
// Q,K,V,O in (B, H, T) layout, head h occupies channels [h*KC, (h+1)*KC).
// One block per (b, h, 32-row tile). 256 threads = 32 rows x 8.
// scores[t,s] = (q[t]/sqrt(KC))·k[s] + rel_s[t][s-t+4] (|s-t|<=4), mask->-10000
// o[t] = sum_s p[t,s] * (v[s] + rel_v[s-t+4] (|s-t|<=4)) / l[t]
// ---------------------------------------------------------------------------
__global__ __launch_bounds__(256) void k_attn(
        const float* __restrict__ Q, const float* __restrict__ K,
        const float* __restrict__ V, const float* __restrict__ relk,
        const float* __restrict__ relv, float* __restrict__ O,
        const int* __restrict__ lens) {
    __shared__ float qt[KCN][33];
    __shared__ float kt[KCN][33];
    __shared__ float vt[KCN][33];
    __shared__ float Pt[32][33];
    __shared__ float rk[9][KCN];
    __shared__ float rv[9][KCN];
    __shared__ float rels[32][9];

    const int b = blockIdx.z, h = blockIdx.y;
    const int t0 = blockIdx.x * 32;
    const int len = lens[b];
    const int tid = threadIdx.x;
    const float* Qh = Q + ((size_t)(b * HN) + h * KCN) * TN;
    const float* Kh = K + ((size_t)(b * HN) + h * KCN) * TN;
    const float* Vh = V + ((size_t)(b * HN) + h * KCN) * TN;
    const float scale = 0.10206207261596575f; // 1/sqrt(96)

    for (int idx = tid; idx < KCN * 32; idx += 256) {
        int ch = idx >> 5, r = idx & 31;
        qt[ch][r] = Qh[ch * TN + t0 + r] * scale;
    }
    for (int idx = tid; idx < 9 * KCN; idx += 256) {
        rk[idx / KCN][idx % KCN] = relk[idx];
        rv[idx / KCN][idx % KCN] = relv[idx];
    }
    __syncthreads();
    // per-row rel-k scores (uses scaled q, matching reference qs·rel_k)
    for (int idx = tid; idx < 32 * 9; idx += 256) {
        int r = idx / 9, d = idx % 9;
        float s = 0.f;
        for (int ch = 0; ch < KCN; ++ch) s += qt[ch][r] * rk[d][ch];
        rels[r][d] = s;
    }

    const int row = tid >> 3; // 0..31
    const int th = tid & 7;   // 0..7
    const int tglob = t0 + row;
    const bool rowvalid = (tglob < len);
    const int ch0 = th * 12;

    float mrun = -1e30f, lrun = 0.f;
    float accv[12];
#pragma unroll
    for (int c = 0; c < 12; ++c) accv[c] = 0.f;

    for (int s0 = 0; s0 < TN; s0 += 32) {
        __syncthreads(); // rels visible (iter 0) / previous PV done (iter > 0)
        for (int idx = tid; idx < KCN * 32; idx += 256) {
            int ch = idx >> 5, r = idx & 31;
            kt[ch][r] = Kh[ch * TN + s0 + r];
            vt[ch][r] = Vh[ch * TN + s0 + r];
        }
        __syncthreads();

        float sc[4];
#pragma unroll
        for (int j = 0; j < 4; ++j) sc[j] = 0.f;
        for (int ch = 0; ch < KCN; ++ch) {
            float qv = qt[ch][row];
#pragma unroll
            for (int j = 0; j < 4; ++j) sc[j] += qv * kt[ch][th * 4 + j];
        }
        float tmax = -1e30f;
#pragma unroll
        for (int j = 0; j < 4; ++j) {
            int sg = s0 + th * 4 + j;
            int d = sg - tglob;
            float v = sc[j];
            if (d >= -4 && d <= 4) v += rels[row][d + 4];
            bool valid = rowvalid && (sg < len);
            v = valid ? v : -10000.0f;
            sc[j] = v;
            tmax = fmaxf(tmax, v);
        }
        for (int off = 1; off < 8; off <<= 1)
            tmax = fmaxf(tmax, __shfl_xor(tmax, off));
        float mnew = fmaxf(mrun, tmax);
        float rescale = __expf(mrun - mnew);
        float psum = 0.f;
#pragma unroll
        for (int j = 0; j < 4; ++j) {
            float p = __expf(sc[j] - mnew);
            Pt[row][th * 4 + j] = p;
            psum += p;
        }
        for (int off = 1; off < 8; off <<= 1)
            psum += __shfl_xor(psum, off);
        lrun = lrun * rescale + psum;
        mrun = mnew;
#pragma unroll
        for (int c = 0; c < 12; ++c) accv[c] *= rescale;
        // Pt written+read by the same wave (8 threads of a row live in one
        // wave) -> compiler lgkmcnt suffices, no barrier needed here.
        for (int s = 0; s < 32; ++s) {
            float p = Pt[row][s];
            int d = (s0 + s) - tglob;
            bool inwin = (d >= -4 && d <= 4);
#pragma unroll
            for (int c = 0; c < 12; ++c) {
                float vv = vt[ch0 + c][s];
                if (inwin) vv += rv[d + 4][ch0 + c];
                accv[c] += p * vv;
            }
        }
    }

    float inv = 1.f / lrun;
#pragma unroll
    for (int c = 0; c < 12; ++c)
        O[((size_t)(b * HN) + h * KCN + ch0 + c) * TN + tglob] = accv[c] * inv;
}

// ---------------------------------------------------------------------------
// Residual + LayerNorm over channel dim: x = LN(x + y) * g + b  (per (b,t))
// Block per (b, 64-t tile). mean/var denom = H (matches jnp.var ddof=0).
// ---------------------------------------------------------------------------
__global__ __launch_bounds__(256) void k_ln(float* __restrict__ x,
        const float* __restrict__ y, const float* __restrict__ g,
        const float* __restrict__ bb) {
    __shared__ float s[HN][65];
    __shared__ float red1[256], red2[256];
    __shared__ float mu[64], rs[64];
    const int b = blockIdx.y;
    const int t0 = blockIdx.x * 64;
    const int tid = threadIdx.x;

    for (int idx = tid; idx < HN * 64; idx += 256) {
        int c = idx >> 6, tt = idx & 63;
        size_t gi = ((size_t)(b * HN) + c) * TN + t0 + tt;
        s[c][tt] = x[gi] + y[gi];
    }
    __syncthreads();
    int tt = tid & 63, grp = tid >> 6;
    float sum = 0.f, sum2 = 0.f;
    for (int c = grp * 48; c < grp * 48 + 48; ++c) {
        float v = s[c][tt];
        sum += v;
        sum2 += v * v;
    }
    red1[tid] = sum;
    red2[tid] = sum2;
    __syncthreads();
    if (grp == 0) {
        float tot = red1[tt] + red1[64 + tt] + red1[128 + tt] + red1[192 + tt];
        float tot2 = red2[tt] + red2[64 + tt] + red2[128 + tt] + red2[192 + tt];
        float mean = tot / (float)HN;
        float var = tot2 / (float)HN - mean * mean;
        mu[tt] = mean;
        rs[tt] = rsqrtf(var + 1e-5f);
    }
    __syncthreads();
    for (int idx = tid; idx < HN * 64; idx += 256) {
        int c = idx >> 6, t2 = idx & 63;
        float v = (s[c][t2] - mu[t2]) * rs[t2] * g[c] + bb[c];
        x[((size_t)(b * HN) + c) * TN + t0 + t2] = v;
    }
}

// ---------------------------------------------------------------------------
// Final: z = m + eps*exp(logs)*mask ; outputs (z, m, logs, x*mask, mask)
// stats layout (B, 2*OUT, T), already masked by the producing GEMM.
// ---------------------------------------------------------------------------
__global__ void k_final(const float* __restrict__ stats, const float* __restrict__ x,
        const float* __restrict__ eps, const int* __restrict__ lens,
        float* __restrict__ out) {
    int idx = blockIdx.x * 256 + threadIdx.x;
    int t = idx % TN;
    int o = (idx / TN) % OUTN;
    int b = idx / (TN * OUTN);
    float maskv = (t < lens[b]) ? 1.f : 0.f;
    const size_t S = (size_t)BN * OUTN * TN;
    float m = stats[((size_t)(b * 2 * OUTN) + o) * TN + t];
    float ls = stats[((size_t)(b * 2 * OUTN) + OUTN + o) * TN + t];
    float e = eps[idx];
    out[idx] = m + e * expf(ls) * maskv;
    out[S + idx] = m;
    out[2 * S + idx] = ls;
    out[3 * S + idx] = x[idx] * maskv;
    if (o == 0) out[4 * S + (size_t)b * TN + t] = maskv;
}

// ---------------------------------------------------------------------------
extern "C" void kernel_launch(void* const* d_in, const int* in_sizes, int n_in,
                              void* d_out, int out_size, void* d_ws, size_t ws_size,
                              hipStream_t stream) {
    const int* tok = (const int*)d_in[0];
    const int* lens = (const int*)d_in[1];
    const float* emb = (const float*)d_in[2];
    const float* qw = (const float*)d_in[3];
    const float* qb = (const float*)d_in[4];
    const float* kw = (const float*)d_in[5];
    const float* kb = (const float*)d_in[6];
    const float* vw = (const float*)d_in[7];
    const float* vb = (const float*)d_in[8];
    const float* ow = (const float*)d_in[9];
    const float* ob = (const float*)d_in[10];
    const float* relk = (const float*)d_in[11];
    const float* relv = (const float*)d_in[12];
    const float* ln1g = (const float*)d_in[13];
    const float* ln1b = (const float*)d_in[14];
    const float* f1w = (const float*)d_in[15];
    const float* f1b = (const float*)d_in[16];
    const float* f2w = (const float*)d_in[17];
    const float* f2b = (const float*)d_in[18];
    const float* ln2g = (const float*)d_in[19];
    const float* ln2b = (const float*)d_in[20];
    const float* pw = (const float*)d_in[21];
    const float* pb = (const float*)d_in[22];
    const float* eps = (const float*)d_in[23];

    const size_t BHT = (size_t)BN * HN * TN; // 1,572,864
    float* ws = (float*)d_ws;
    float* x = ws;
    float* q = ws + BHT;
    float* k = ws + 2 * BHT;
    float* v = ws + 3 * BHT;
    float* o = ws + 4 * BHT;
    float* y1 = ws + 5 * BHT; // B*FFN*T = 4*BHT floats; also reused for stats

    k_embed<<<dim3((unsigned)((BHT) / 256)), 256, 0, stream>>>(tok, lens, emb, x);

    dim3 gproj(TN / 64, HN / 64, BN);       // 16 x 3 x 8
    dim3 gf1(TN / 64, FFNN / 64, BN);       // 16 x 12 x 8
    dim3 gattn(TN / 32, NHN, BN);           // 32 x 2 x 8
    dim3 gln(TN / 64, BN);                  // 16 x 8

    for (int i = 0; i < LN; ++i) {
        const float* qwi = qw + (size_t)i * HN * HN;
        const float* qbi = qb + (size_t)i * HN;
        const float* kwi = kw + (size_t)i * HN * HN;
        const float* kbi = kb + (size_t)i * HN;
        const float* vwi = vw + (size_t)i * HN * HN;
        const float* vbi = vb + (size_t)i * HN;
        const float* owi = ow + (size_t)i * HN * HN;
        const float* obi = ob + (size_t)i * HN;
        const float* rki = relk + (size_t)i * 9 * KCN;
        const float* rvi = relv + (size_t)i * 9 * KCN;
        const float* l1gi = ln1g + (size_t)i * HN;
        const float* l1bi = ln1b + (size_t)i * HN;
        const float* f1wi = f1w + (size_t)i * FFNN * HN * 3;
        const float* f1bi = f1b + (size_t)i * FFNN;
        const float* f2wi = f2w + (size_t)i * HN * FFNN * 3;
        const float* f2bi = f2b + (size_t)i * HN;
        const float* l2gi = ln2g + (size_t)i * HN;
        const float* l2bi = ln2b + (size_t)i * HN;

        k_gemm<1, false, false, false><<<gproj, 256, 0, stream>>>(qwi, x, qbi, q, lens, HN, HN);
        k_gemm<1, false, false, false><<<gproj, 256, 0, stream>>>(kwi, x, kbi, k, lens, HN, HN);
        k_gemm<1, false, false, false><<<gproj, 256, 0, stream>>>(vwi, x, vbi, v, lens, HN, HN);
        k_attn<<<gattn, 256, 0, stream>>>(q, k, v, rki, rvi, o, lens);
        k_gemm<1, false, false, false><<<gproj, 256, 0, stream>>>(owi, o, obi, q, lens, HN, HN);
        k_ln<<<gln, 256, 0, stream>>>(x, q, l1gi, l1bi);
        k_gemm<3, true, true, false><<<gf1, 256, 0, stream>>>(f1wi, x, f1bi, y1, lens, FFNN, HN);
        k_gemm<3, false, true, true><<<gproj, 256, 0, stream>>>(f2wi, y1, f2bi, k, lens, HN, FFNN);
        k_ln<<<gln, 256, 0, stream>>>(x, k, l2gi, l2bi);
    }

    dim3 gstat(TN / 64, (2 * OUTN) / 64, BN); // 16 x 6 x 8
    k_gemm<1, false, true, true><<<gstat, 256, 0, stream>>>(pw, x, pb, y1, lens, 2 * OUTN, HN);
    k_final<<<dim3((unsigned)((BHT) / 256)), 256, 0, stream>>>(y1, x, eps, lens, (float*)d_out);
}

// Round 2
// 4553.687 us; speedup vs baseline: 2.0650x; 2.0650x over previous
//
#include <hip/hip_runtime.h>
#include <math.h>

#define BN 8
#define TN 1024
#define HN 192
#define NHN 2
#define KCN 96
#define LN 6
#define FFNN 768
#define OUTN 192

typedef short bfrag __attribute__((ext_vector_type(8)));
typedef float f32x4 __attribute__((ext_vector_type(4)));

__device__ __forceinline__ short f2bf(float f) {
    union { float f; unsigned u; } v; v.f = f;
    unsigned r = v.u + 0x7fffu + ((v.u >> 16) & 1u);
    return (short)(r >> 16);
}
__device__ __forceinline__ float bf2f(short s) {
    union { unsigned u; float f; } v;
    v.u = ((unsigned)(unsigned short)s) << 16;
    return v.f;
}

// ---------------------------------------------------------------------------
// Embedding: x[b,c,t] = emb[tok[b,t], c] * sqrt(H) * (t < len[b])
// ---------------------------------------------------------------------------
__global__ void k_embed(const int* __restrict__ tok, const int* __restrict__ lens,
                        const float* __restrict__ emb, float* __restrict__ x) {
    int idx = blockIdx.x * 256 + threadIdx.x;
    int t = idx % TN;
    int c = (idx / TN) % HN;
    int b = idx / (TN * HN);
    float v = 0.f;
    if (t < lens[b]) v = emb[tok[b * TN + t] * HN + c] * 13.856406460551018f; // sqrt(192)
    x[idx] = v;
}

// ---------------------------------------------------------------------------
// Generic batched GEMM / 1-D conv (SAME, K taps):
//   Y[b,m,t] = act( (sum_{c,tap} W[m,c,tap]*Xin[b,c,t+tap-P] + bias[m]) * oscale )
// OUTK: 0 = fp32 (B,M,T); 1 = bf16 t-major (B,NH,T,KC); 2 = bf16 (B,M,T)
// ---------------------------------------------------------------------------
template <int TAPS, bool RELU, bool MASK_IN, bool MASK_OUT, int OUTK>
__global__ __launch_bounds__(256) void k_gemm(
        const float* __restrict__ W, const float* __restrict__ X,
        const float* __restrict__ bias, void* __restrict__ Yv,
        const int* __restrict__ lens, int M, int Cin, float oscale) {
    constexpr int P = (TAPS - 1) / 2;
    constexpr int TW = 64 + 2 * P;
    __shared__ float Wt[TAPS][16][64];
    __shared__ float Xt[16][TW];

    const int b = blockIdx.z;
    const int m0 = blockIdx.y * 64;
    const int t0 = blockIdx.x * 64;
    const int len = lens[b];
    const int tid = threadIdx.x;
    const int tx = tid % 16, ty = tid / 16;

    float acc[4][4];
#pragma unroll
    for (int i = 0; i < 4; ++i)
#pragma unroll
        for (int j = 0; j < 4; ++j) acc[i][j] = 0.f;

    for (int c0 = 0; c0 < Cin; c0 += 16) {
        for (int idx = tid; idx < 64 * 16 * TAPS; idx += 256) {
            int mm = idx / (16 * TAPS);
            int rem = idx % (16 * TAPS);
            int cc = rem / TAPS;
            int tap = rem % TAPS;
            Wt[tap][cc][mm] = W[((m0 + mm) * Cin + (c0 + cc)) * TAPS + tap];
        }
        for (int idx = tid; idx < 16 * TW; idx += 256) {
            int cc = idx / TW;
            int tt = idx % TW;
            int t = t0 + tt - P;
            float v = 0.f;
            if (t >= 0 && t < TN) {
                v = X[(b * Cin + c0 + cc) * TN + t];
                if (MASK_IN && t >= len) v = 0.f;
            }
            Xt[cc][tt] = v;
        }
        __syncthreads();
#pragma unroll
        for (int kk = 0; kk < 16; ++kk) {
            float xv[4 + 2 * P];
#pragma unroll
            for (int j = 0; j < 4 + 2 * P; ++j) xv[j] = Xt[kk][tx * 4 + j];
#pragma unroll
            for (int tap = 0; tap < TAPS; ++tap) {
                float a[4];
#pragma unroll
                for (int i = 0; i < 4; ++i) a[i] = Wt[tap][kk][ty * 4 + i];
#pragma unroll
                for (int i = 0; i < 4; ++i)
#pragma unroll
                    for (int j = 0; j < 4; ++j) acc[i][j] += a[i] * xv[j + tap];
            }
        }
        __syncthreads();
    }

#pragma unroll
    for (int i = 0; i < 4; ++i) {
        int m = m0 + ty * 4 + i;
        float bs = bias[m];
#pragma unroll
        for (int j = 0; j < 4; ++j) {
            int t = t0 + tx * 4 + j;
            float v = (acc[i][j] + bs) * oscale;
            if (RELU) v = fmaxf(v, 0.f);
            if (OUTK == 0) {
                if (MASK_OUT && t >= len) v = 0.f;
                ((float*)Yv)[(b * M + m) * TN + t] = v;
            } else if (OUTK == 1) {
                ((short*)Yv)[(((size_t)b * NHN + m / KCN) * TN + t) * KCN + (m % KCN)] = f2bf(v);
            } else {
                ((short*)Yv)[((size_t)b * M + m) * TN + t] = f2bf(v);
            }
        }
    }
}

// ---------------------------------------------------------------------------
// MFMA bf16 flash attention with 9-wide relative-position band (WIN=4).
// Q,K bf16 t-major (B,NH,T,KC); V bf16 ch-major (B,NH,KC,T); O fp32 (B,H,T).
// Block = 4 waves, one (b,h,64 q-rows). Wave w owns q-rows [w*16, w*16+16).
// Per 64-wide s-tile: QK^T (12 MFMA 16x16x32) -> online softmax in C/D regs
// (row=quad*4+reg, col=lane&15) -> P to LDS bf16 -> PV (12 MFMA).
// Band scores (post-mask, pre-exp) logged to sband; epilogue adds
// sum_d exp(sband-m)/l * rel_v[d] exactly as the reference.
// Rows with q>=len are computed unmasked: they only affect masked-t outputs,
// which are forced to zero downstream.
// ---------------------------------------------------------------------------
__global__ __launch_bounds__(256) void k_attn_mfma(
        const short* __restrict__ Q, const short* __restrict__ K,
        const short* __restrict__ V, const float* __restrict__ relk,
        const float* __restrict__ relv, float* __restrict__ O,
        const int* __restrict__ lens) {
    __shared__ short qs[64 * 96];   // [q][ch]
    __shared__ short kt[64 * 96];   // [s][ch]
    __shared__ short vt[96 * 72];   // [ch][s] pad->72 (conflict-free b128)
    __shared__ short Pt[64 * 72];   // [q][s]  pad->72
    __shared__ float rels[64 * 12]; // [q][d]  qs·rel_k
    __shared__ float sband[64 * 12];// [q][d]  masked raw scores on the band
    __shared__ float rvs[9 * 96];   // rel_v staged

    const int b = blockIdx.z, h = blockIdx.y;
    const int t0 = blockIdx.x * 64;
    const int len = lens[b];
    const int tid = threadIdx.x;
    const int w = tid >> 6;
    const int lane = tid & 63;
    const int col = lane & 15;
    const int quad = lane >> 4;

    const short* Qb = Q + ((size_t)(b * NHN + h) * TN + t0) * KCN;
    const short* Kb = K + (size_t)(b * NHN + h) * TN * KCN;
    const short* Vb = V + (size_t)(b * NHN + h) * KCN * TN;

    for (int i = tid; i < 768; i += 256)
        *(int4*)(qs + i * 8) = *(const int4*)(Qb + i * 8);
    for (int i = tid; i < 9 * 96; i += 256) rvs[i] = relv[i];
    for (int i = tid; i < 768; i += 256) sband[i] = -1e30f;
    __syncthreads();
    for (int i = tid; i < 576; i += 256) {
        int lq = i / 9, d = i % 9;
        float s = 0.f;
        const float* rk = relk + d * 96;
        const short* qrow = qs + lq * 96;
        for (int c = 0; c < 96; ++c) s += bf2f(qrow[c]) * rk[c];
        rels[lq * 12 + d] = s;
    }

    float mrun[4], lrun[4];
    f32x4 accv[6];
#pragma unroll
    for (int r = 0; r < 4; ++r) { mrun[r] = -1e30f; lrun[r] = 0.f; }
#pragma unroll
    for (int n = 0; n < 6; ++n) accv[n] = (f32x4){0.f, 0.f, 0.f, 0.f};

    for (int s0 = 0; s0 < TN; s0 += 64) {
        __syncthreads(); // prev PV reads done (and rels/rvs visible on iter 0)
        for (int i = tid; i < 768; i += 256)
            *(int4*)(kt + i * 8) = *(const int4*)(Kb + s0 * 96 + i * 8);
        for (int i = tid; i < 768; i += 256) {
            int c = i >> 3, part = i & 7;
            *(int4*)(vt + c * 72 + part * 8) =
                *(const int4*)(Vb + c * TN + s0 + part * 8);
        }
        __syncthreads();

        f32x4 sacc[4];
#pragma unroll
        for (int st = 0; st < 4; ++st) sacc[st] = (f32x4){0.f, 0.f, 0.f, 0.f};
#pragma unroll
        for (int ks = 0; ks < 3; ++ks) {
            bfrag af = *(const bfrag*)(qs + (w * 16 + col) * 96 + ks * 32 + quad * 8);
#pragma unroll
            for (int st = 0; st < 4; ++st) {
                bfrag bf = *(const bfrag*)(kt + (st * 16 + col) * 96 + ks * 32 + quad * 8);
                sacc[st] = __builtin_amdgcn_mfma_f32_16x16x32_bf16(af, bf, sacc[st], 0, 0, 0);
            }
        }

#pragma unroll
        for (int reg = 0; reg < 4; ++reg) {
            const int lq = w * 16 + quad * 4 + reg;
            const int qg = t0 + lq;
            float sc[4];
            float tm = -1e30f;
#pragma unroll
            for (int st = 0; st < 4; ++st) {
                int sg = s0 + st * 16 + col;
                float v = sacc[st][reg];
                int d = sg - qg + 4;
                bool inb = (d >= 0) && (d <= 8);
                if (inb) v += rels[lq * 12 + d];
                if (sg >= len) v = -1e4f;
                if (inb) sband[lq * 12 + d] = v;
                sc[st] = v;
                tm = fmaxf(tm, v);
            }
            tm = fmaxf(tm, __shfl_xor(tm, 1));
            tm = fmaxf(tm, __shfl_xor(tm, 2));
            tm = fmaxf(tm, __shfl_xor(tm, 4));
            tm = fmaxf(tm, __shfl_xor(tm, 8));
            float mnew = fmaxf(mrun[reg], tm);
            float alpha = __expf(mrun[reg] - mnew);
            mrun[reg] = mnew;
            float ps = 0.f;
#pragma unroll
            for (int st = 0; st < 4; ++st) {
                float p = __expf(sc[st] - mnew);
                ps += p;
                Pt[lq * 72 + st * 16 + col] = f2bf(p);
            }
            ps += __shfl_xor(ps, 1);
            ps += __shfl_xor(ps, 2);
            ps += __shfl_xor(ps, 4);
            ps += __shfl_xor(ps, 8);
            lrun[reg] = lrun[reg] * alpha + ps;
#pragma unroll
            for (int nt = 0; nt < 6; ++nt) accv[nt][reg] *= alpha;
        }
        __syncthreads(); // Pt visible to all lanes of each wave
#pragma unroll
        for (int ks = 0; ks < 2; ++ks) {
            bfrag af = *(const bfrag*)(Pt + (w * 16 + col) * 72 + ks * 32 + quad * 8);
#pragma unroll
            for (int nt = 0; nt < 6; ++nt) {
                bfrag bf = *(const bfrag*)(vt + (nt * 16 + col) * 72 + ks * 32 + quad * 8);
                accv[nt] = __builtin_amdgcn_mfma_f32_16x16x32_bf16(af, bf, accv[nt], 0, 0, 0);
            }
        }
    }

    // epilogue: o = accv/l + exp(sband - m)/l · rel_v ; store fp32 (B,H,T)
#pragma unroll
    for (int reg = 0; reg < 4; ++reg) {
        const int lq = w * 16 + quad * 4 + reg;
        const int qg = t0 + lq;
        float linv = 1.f / lrun[reg];
        float pb[9];
#pragma unroll
        for (int d = 0; d < 9; ++d)
            pb[d] = __expf(sband[lq * 12 + d] - mrun[reg]) * linv;
#pragma unroll
        for (int nt = 0; nt < 6; ++nt) {
            int c = nt * 16 + col;
            float r = accv[nt][reg] * linv;
#pragma unroll
            for (int d = 0; d < 9; ++d) r += pb[d] * rvs[d * 96 + c];
            O[((size_t)(b * HN) + h * KCN + c) * TN + qg] = r;
        }
    }
}

// ---------------------------------------------------------------------------
// Residual + LayerNorm over channel dim: x = LN(x + y) * g + b  (per (b,t))
// ---------------------------------------------------------------------------
__global__ __launch_bounds__(256) void k_ln(float* __restrict__ x,
        const float* __restrict__ y, const float* __restrict__ g,
        const float* __restrict__ bb) {
    __shared__ float s[HN][65];
    __shared__ float red1[256], red2[256];
    __shared__ float mu[64], rs[64];
    const int b = blockIdx.y;
    const int t0 = blockIdx.x * 64;
    const int tid = threadIdx.x;

    for (int idx = tid; idx < HN * 64; idx += 256) {
        int c = idx >> 6, tt = idx & 63;
        size_t gi = ((size_t)(b * HN) + c) * TN + t0 + tt;
        s[c][tt] = x[gi] + y[gi];
    }
    __syncthreads();
    int tt = tid & 63, grp = tid >> 6;
    float sum = 0.f, sum2 = 0.f;
    for (int c = grp * 48; c < grp * 48 + 48; ++c) {
        float v = s[c][tt];
        sum += v;
        sum2 += v * v;
    }
    red1[tid] = sum;
    red2[tid] = sum2;
    __syncthreads();
    if (grp == 0) {
        float tot = red1[tt] + red1[64 + tt] + red1[128 + tt] + red1[192 + tt];
        float tot2 = red2[tt] + red2[64 + tt] + red2[128 + tt] + red2[192 + tt];
        float mean = tot / (float)HN;
        float var = tot2 / (float)HN - mean * mean;
        mu[tt] = mean;
        rs[tt] = rsqrtf(var + 1e-5f);
    }
    __syncthreads();
    for (int idx = tid; idx < HN * 64; idx += 256) {
        int c = idx >> 6, t2 = idx & 63;
        float v = (s[c][t2] - mu[t2]) * rs[t2] * g[c] + bb[c];
        x[((size_t)(b * HN) + c) * TN + t0 + t2] = v;
    }
}

// ---------------------------------------------------------------------------
// Final: z = m + eps*exp(logs)*mask ; outputs (z, m, logs, x*mask, mask)
// ---------------------------------------------------------------------------
__global__ void k_final(const float* __restrict__ stats, const float* __restrict__ x,
        const float* __restrict__ eps, const int* __restrict__ lens,
        float* __restrict__ out) {
    int idx = blockIdx.x * 256 + threadIdx.x;
    int t = idx % TN;
    int o = (idx / TN) % OUTN;
    int b = idx / (TN * OUTN);
    float maskv = (t < lens[b]) ? 1.f : 0.f;
    const size_t S = (size_t)BN * OUTN * TN;
    float m = stats[((size_t)(b * 2 * OUTN) + o) * TN + t];
    float ls = stats[((size_t)(b * 2 * OUTN) + OUTN + o) * TN + t];
    float e = eps[idx];
    out[idx] = m + e * expf(ls) * maskv;
    out[S + idx] = m;
    out[2 * S + idx] = ls;
    out[3 * S + idx] = x[idx] * maskv;
    if (o == 0) out[4 * S + (size_t)b * TN + t] = maskv;
}

// ---------------------------------------------------------------------------
extern "C" void kernel_launch(void* const* d_in, const int* in_sizes, int n_in,
                              void* d_out, int out_size, void* d_ws, size_t ws_size,
                              hipStream_t stream) {
    const int* tok = (const int*)d_in[0];
    const int* lens = (const int*)d_in[1];
    const float* emb = (const float*)d_in[2];
    const float* qw = (const float*)d_in[3];
    const float* qb = (const float*)d_in[4];
    const float* kw = (const float*)d_in[5];
    const float* kb = (const float*)d_in[6];
    const float* vw = (const float*)d_in[7];
    const float* vb = (const float*)d_in[8];
    const float* ow = (const float*)d_in[9];
    const float* ob = (const float*)d_in[10];
    const float* relk = (const float*)d_in[11];
    const float* relv = (const float*)d_in[12];
    const float* ln1g = (const float*)d_in[13];
    const float* ln1b = (const float*)d_in[14];
    const float* f1w = (const float*)d_in[15];
    const float* f1b = (const float*)d_in[16];
    const float* f2w = (const float*)d_in[17];
    const float* f2b = (const float*)d_in[18];
    const float* ln2g = (const float*)d_in[19];
    const float* ln2b = (const float*)d_in[20];
    const float* pw = (const float*)d_in[21];
    const float* pb = (const float*)d_in[22];
    const float* eps = (const float*)d_in[23];

    const size_t BHT = (size_t)BN * HN * TN; // 1,572,864
    float* ws = (float*)d_ws;
    float* x = ws;
    float* y_attn = ws + BHT;     // o-proj output (fp32), overlaps Q region tail use
    short* qb16 = (short*)(ws + BHT);
    short* kb16 = (short*)(ws + 2 * BHT);
    short* vb16 = (short*)(ws + 3 * BHT);
    float* o = ws + 4 * BHT;
    float* y1 = ws + 5 * BHT;     // B*FFN*T floats; also reused for stats
    float* f2out = ws + 2 * BHT;  // f2 conv output (fp32), reuses K region

    k_embed<<<dim3((unsigned)(BHT / 256)), 256, 0, stream>>>(tok, lens, emb, x);

    dim3 gproj(TN / 64, HN / 64, BN);       // 16 x 3 x 8
    dim3 gf1(TN / 64, FFNN / 64, BN);       // 16 x 12 x 8
    dim3 gattn(TN / 64, NHN, BN);           // 16 x 2 x 8
    dim3 gln(TN / 64, BN);                  // 16 x 8
    const float qscale = 0.10206207261596575f; // 1/sqrt(96)

    for (int i = 0; i < LN; ++i) {
        const float* qwi = qw + (size_t)i * HN * HN;
        const float* qbi = qb + (size_t)i * HN;
        const float* kwi = kw + (size_t)i * HN * HN;
        const float* kbi = kb + (size_t)i * HN;
        const float* vwi = vw + (size_t)i * HN * HN;
        const float* vbi = vb + (size_t)i * HN;
        const float* owi = ow + (size_t)i * HN * HN;
        const float* obi = ob + (size_t)i * HN;
        const float* rki = relk + (size_t)i * 9 * KCN;
        const float* rvi = relv + (size_t)i * 9 * KCN;
        const float* l1gi = ln1g + (size_t)i * HN;
        const float* l1bi = ln1b + (size_t)i * HN;
        const float* f1wi = f1w + (size_t)i * FFNN * HN * 3;
        const float* f1bi = f1b + (size_t)i * FFNN;
        const float* f2wi = f2w + (size_t)i * HN * FFNN * 3;
        const float* f2bi = f2b + (size_t)i * HN;
        const float* l2gi = ln2g + (size_t)i * HN;
        const float* l2bi = ln2b + (size_t)i * HN;

        k_gemm<1, false, false, false, 1><<<gproj, 256, 0, stream>>>(qwi, x, qbi, qb16, lens, HN, HN, qscale);
        k_gemm<1, false, false, false, 1><<<gproj, 256, 0, stream>>>(kwi, x, kbi, kb16, lens, HN, HN, 1.f);
        k_gemm<1, false, false, false, 2><<<gproj, 256, 0, stream>>>(vwi, x, vbi, vb16, lens, HN, HN, 1.f);
        k_attn_mfma<<<gattn, 256, 0, stream>>>(qb16, kb16, vb16, rki, rvi, o, lens);
        k_gemm<1, false, false, false, 0><<<gproj, 256, 0, stream>>>(owi, o, obi, y_attn, lens, HN, HN, 1.f);
        k_ln<<<gln, 256, 0, stream>>>(x, y_attn, l1gi, l1bi);
        k_gemm<3, true, true, false, 0><<<gf1, 256, 0, stream>>>(f1wi, x, f1bi, y1, lens, FFNN, HN, 1.f);
        k_gemm<3, false, true, true, 0><<<gproj, 256, 0, stream>>>(f2wi, y1, f2bi, f2out, lens, HN, FFNN, 1.f);
        k_ln<<<gln, 256, 0, stream>>>(x, f2out, l2gi, l2bi);
    }

    dim3 gstat(TN / 64, (2 * OUTN) / 64, BN); // 16 x 6 x 8
    k_gemm<1, false, true, true, 0><<<gstat, 256, 0, stream>>>(pw, x, pb, y1, lens, 2 * OUTN, HN, 1.f);
    k_final<<<dim3((unsigned)(BHT / 256)), 256, 0, stream>>>(y1, x, eps, lens, (float*)d_out);
}

// Round 3
// 1411.218 us; speedup vs baseline: 6.6635x; 3.2268x over previous
//
#include <hip/hip_runtime.h>
#include <math.h>

#define BN 8
#define TN 1024
#define HN 192
#define NHN 2
#define KCN 96
#define LN 6
#define FFNN 768
#define OUTN 192

typedef short bfrag __attribute__((ext_vector_type(8)));
typedef float f32x4 __attribute__((ext_vector_type(4)));

__device__ __forceinline__ short f2bf(float f) {
    union { float f; unsigned u; } v; v.f = f;
    unsigned r = v.u + 0x7fffu + ((v.u >> 16) & 1u);
    return (short)(r >> 16);
}
__device__ __forceinline__ float bf2f(short s) {
    union { unsigned u; float f; } v;
    v.u = ((unsigned)(unsigned short)s) << 16;
    return v.f;
}
__device__ __forceinline__ int pack2(float a, float b) {
    return (int)(unsigned short)f2bf(a) | (((int)(unsigned short)f2bf(b)) << 16);
}

// ---------------------------------------------------------------------------
// Weight conversions (run every call; weights live in d_ws).
// ---------------------------------------------------------------------------
__global__ void k_cvt(const float* __restrict__ src, short* __restrict__ dst, int n) {
    int i = blockIdx.x * 256 + threadIdx.x;
    if (i < n) dst[i] = f2bf(src[i]);
}
// src [L][M][Cin][3] -> dst [L][3][M][Cin]
__global__ void k_cvtconv(const float* __restrict__ src, short* __restrict__ dst,
                          int M, int Cin, int n) {
    int i = blockIdx.x * 256 + threadIdx.x;
    if (i >= n) return;
    int tap = i % 3;
    int c = (i / 3) % Cin;
    int m = (i / (3 * Cin)) % M;
    int l = i / (3 * Cin * M);
    dst[(((size_t)l * 3 + tap) * M + m) * Cin + c] = f2bf(src[i]);
}

// ---------------------------------------------------------------------------
// Embedding: x fp32 ch-major (B,H,T) + xb bf16 t-major (B,T,H), both masked.
// Block per (b, 64 t). LDS transpose for coalescing both ways.
// ---------------------------------------------------------------------------
__global__ __launch_bounds__(256) void k_embed(const int* __restrict__ tok,
        const int* __restrict__ lens, const float* __restrict__ emb,
        float* __restrict__ x, short* __restrict__ xb) {
    __shared__ float s[HN][65];
    const int b = blockIdx.y, t0 = blockIdx.x * 64, tid = threadIdx.x;
    const int len = lens[b];
    for (int idx = tid; idx < 64 * HN; idx += 256) {
        int tt = idx / HN, c = idx % HN;
        int t = t0 + tt;
        float v = 0.f;
        if (t < len) v = emb[tok[b * TN + t] * HN + c] * 13.856406460551018f; // sqrt(192)
        s[c][tt] = v;
    }
    __syncthreads();
    for (int idx = tid; idx < 64 * HN; idx += 256) {
        int c = idx >> 6, tt = idx & 63;
        x[((size_t)b * HN + c) * TN + t0 + tt] = s[c][tt];
    }
    for (int idx = tid; idx < 64 * 96; idx += 256) {
        int tt = idx / 96, p = idx % 96;
        ((int*)xb)[((size_t)(b * TN + t0 + tt)) * 96 + p] = pack2(s[2 * p][tt], s[2 * p + 1][tt]);
    }
}

// ---------------------------------------------------------------------------
// MFMA bf16 GEMM / K-tap SAME conv.
//   Y[b,m,t] = act((sum_{c,tap} W[tap][m][c]*X[b][t+tap-P][c] + bias[m])*oscale)
// W bf16 [TAPS][M][Cin]; X bf16 t-major (B,T,Cin), pre-masked where needed.
// Block: 4 waves, 64m x 64t tile; k-chunk 64 channels; LDS stride 72 shorts
// (granule stride 9 mod 8 -> at most 2-way, free).
// OUTK: 0 fp32 ch-major (B,M,T); 1 bf16 t-major (B,T,M); 2 bf16 ch-major.
// ---------------------------------------------------------------------------
template <int TAPS, bool RELU, bool MASK_OUT, int OUTK>
__global__ __launch_bounds__(256) void k_mgemm(
        const short* __restrict__ W, const short* __restrict__ X,
        const float* __restrict__ bias, void* __restrict__ Yv,
        const int* __restrict__ lens, int M, int Cin, float oscale) {
    constexpr int P = (TAPS - 1) / 2;
    constexpr int XS = 72;
    __shared__ short Wt[TAPS][64][XS];
    __shared__ short Xt[64 + 2 * P][XS];

    const int b = blockIdx.z;
    const int m0 = blockIdx.y * 64;
    const int t0 = blockIdx.x * 64;
    const int len = lens[b];
    const int tid = threadIdx.x;
    const int w = tid >> 6;
    const int lane = tid & 63;
    const int col = lane & 15;
    const int quad = lane >> 4;

    f32x4 acc[4];
#pragma unroll
    for (int st = 0; st < 4; ++st) acc[st] = (f32x4){0.f, 0.f, 0.f, 0.f};

    for (int c0 = 0; c0 < Cin; c0 += 64) {
        __syncthreads();
        for (int i = tid; i < TAPS * 64 * 8; i += 256) {
            int tap = i / (64 * 8);
            int mm = (i / 8) & 63;
            int part = i & 7;
            *(int4*)(&Wt[tap][mm][part * 8]) =
                *(const int4*)(W + ((size_t)tap * M + m0 + mm) * Cin + c0 + part * 8);
        }
        for (int i = tid; i < (64 + 2 * P) * 8; i += 256) {
            int tt = i >> 3;
            int part = i & 7;
            int t = t0 + tt - P;
            int4 v = {0, 0, 0, 0};
            if (t >= 0 && t < TN)
                v = *(const int4*)(X + ((size_t)b * TN + t) * Cin + c0 + part * 8);
            *(int4*)(&Xt[tt][part * 8]) = v;
        }
        __syncthreads();
#pragma unroll
        for (int ks = 0; ks < 2; ++ks) {
#pragma unroll
            for (int tap = 0; tap < TAPS; ++tap) {
                bfrag af = *(const bfrag*)(&Wt[tap][w * 16 + col][ks * 32 + quad * 8]);
#pragma unroll
                for (int st = 0; st < 4; ++st) {
                    bfrag bf = *(const bfrag*)(&Xt[st * 16 + col + tap][ks * 32 + quad * 8]);
                    acc[st] = __builtin_amdgcn_mfma_f32_16x16x32_bf16(af, bf, acc[st], 0, 0, 0);
                }
            }
        }
    }

    const int mbase = m0 + w * 16 + quad * 4;
    float bs[4];
#pragma unroll
    for (int reg = 0; reg < 4; ++reg) bs[reg] = bias[mbase + reg];
#pragma unroll
    for (int st = 0; st < 4; ++st) {
        int t = t0 + st * 16 + col;
        bool om = MASK_OUT && (t >= len);
        float v[4];
#pragma unroll
        for (int reg = 0; reg < 4; ++reg) {
            float u = (acc[st][reg] + bs[reg]) * oscale;
            if (RELU) u = fmaxf(u, 0.f);
            if (om) u = 0.f;
            v[reg] = u;
        }
        if (OUTK == 0) {
#pragma unroll
            for (int reg = 0; reg < 4; ++reg)
                ((float*)Yv)[((size_t)b * M + mbase + reg) * TN + t] = v[reg];
        } else if (OUTK == 1) {
            int2 pk;
            pk.x = pack2(v[0], v[1]);
            pk.y = pack2(v[2], v[3]);
            *(int2*)((short*)Yv + ((size_t)(b * TN + t)) * M + mbase) = pk;
        } else {
#pragma unroll
            for (int reg = 0; reg < 4; ++reg)
                ((short*)Yv)[((size_t)b * M + mbase + reg) * TN + t] = f2bf(v[reg]);
        }
    }
}

// ---------------------------------------------------------------------------
// MFMA bf16 flash attention, WIN=4 relative-position band.
// Q,K bf16 t-major (B,T,H) head at +h*96; V bf16 ch-major (B,H,T);
// O bf16 t-major (B,T,H).
// ---------------------------------------------------------------------------
__global__ __launch_bounds__(256) void k_attn_mfma(
        const short* __restrict__ Q, const short* __restrict__ K,
        const short* __restrict__ V, const float* __restrict__ relk,
        const float* __restrict__ relv, short* __restrict__ O,
        const int* __restrict__ lens) {
    __shared__ short qs[64 * 96];
    __shared__ short kt[64 * 96];
    __shared__ short vt[96 * 72];
    __shared__ short Pt[64 * 72];
    __shared__ float rels[64 * 12];
    __shared__ float sband[64 * 12];
    __shared__ float rvs[9 * 96];

    const int b = blockIdx.z, h = blockIdx.y;
    const int t0 = blockIdx.x * 64;
    const int len = lens[b];
    const int tid = threadIdx.x;
    const int w = tid >> 6;
    const int lane = tid & 63;
    const int col = lane & 15;
    const int quad = lane >> 4;

    const short* Qb = Q + ((size_t)b * TN + t0) * HN + h * KCN;
    const short* Kb = K + (size_t)b * TN * HN + h * KCN;
    const short* Vb = V + ((size_t)b * HN + h * KCN) * TN;
    short* Ob = O + (size_t)b * TN * HN + h * KCN;

    for (int i = tid; i < 768; i += 256) {
        int row = i / 12, part = i % 12;
        *(int4*)(qs + row * 96 + part * 8) = *(const int4*)(Qb + (size_t)row * HN + part * 8);
    }
    for (int i = tid; i < 9 * 96; i += 256) rvs[i] = relv[i];
    for (int i = tid; i < 768; i += 256) sband[i] = -1e30f;
    __syncthreads();
    for (int i = tid; i < 576; i += 256) {
        int lq = i / 9, d = i % 9;
        float s = 0.f;
        const float* rk = relk + d * 96;
        const short* qrow = qs + lq * 96;
        for (int c = 0; c < 96; ++c) s += bf2f(qrow[c]) * rk[c];
        rels[lq * 12 + d] = s;
    }

    float mrun[4], lrun[4];
    f32x4 accv[6];
#pragma unroll
    for (int r = 0; r < 4; ++r) { mrun[r] = -1e30f; lrun[r] = 0.f; }
#pragma unroll
    for (int n = 0; n < 6; ++n) accv[n] = (f32x4){0.f, 0.f, 0.f, 0.f};

    for (int s0 = 0; s0 < TN; s0 += 64) {
        __syncthreads();
        for (int i = tid; i < 768; i += 256) {
            int row = i / 12, part = i % 12;
            *(int4*)(kt + row * 96 + part * 8) =
                *(const int4*)(Kb + ((size_t)(s0 + row)) * HN + part * 8);
        }
        for (int i = tid; i < 768; i += 256) {
            int c = i >> 3, part = i & 7;
            *(int4*)(vt + c * 72 + part * 8) = *(const int4*)(Vb + (size_t)c * TN + s0 + part * 8);
        }
        __syncthreads();

        f32x4 sacc[4];
#pragma unroll
        for (int st = 0; st < 4; ++st) sacc[st] = (f32x4){0.f, 0.f, 0.f, 0.f};
#pragma unroll
        for (int ks = 0; ks < 3; ++ks) {
            bfrag af = *(const bfrag*)(qs + (w * 16 + col) * 96 + ks * 32 + quad * 8);
#pragma unroll
            for (int st = 0; st < 4; ++st) {
                bfrag bf = *(const bfrag*)(kt + (st * 16 + col) * 96 + ks * 32 + quad * 8);
                sacc[st] = __builtin_amdgcn_mfma_f32_16x16x32_bf16(af, bf, sacc[st], 0, 0, 0);
            }
        }

#pragma unroll
        for (int reg = 0; reg < 4; ++reg) {
            const int lq = w * 16 + quad * 4 + reg;
            const int qg = t0 + lq;
            float sc[4];
            float tm = -1e30f;
#pragma unroll
            for (int st = 0; st < 4; ++st) {
                int sg = s0 + st * 16 + col;
                float v = sacc[st][reg];
                int d = sg - qg + 4;
                bool inb = (d >= 0) && (d <= 8);
                if (inb) v += rels[lq * 12 + d];
                if (sg >= len) v = -1e4f;
                if (inb) sband[lq * 12 + d] = v;
                sc[st] = v;
                tm = fmaxf(tm, v);
            }
            tm = fmaxf(tm, __shfl_xor(tm, 1));
            tm = fmaxf(tm, __shfl_xor(tm, 2));
            tm = fmaxf(tm, __shfl_xor(tm, 4));
            tm = fmaxf(tm, __shfl_xor(tm, 8));
            float mnew = fmaxf(mrun[reg], tm);
            float alpha = __expf(mrun[reg] - mnew);
            mrun[reg] = mnew;
            float ps = 0.f;
#pragma unroll
            for (int st = 0; st < 4; ++st) {
                float p = __expf(sc[st] - mnew);
                ps += p;
                Pt[lq * 72 + st * 16 + col] = f2bf(p);
            }
            ps += __shfl_xor(ps, 1);
            ps += __shfl_xor(ps, 2);
            ps += __shfl_xor(ps, 4);
            ps += __shfl_xor(ps, 8);
            lrun[reg] = lrun[reg] * alpha + ps;
#pragma unroll
            for (int nt = 0; nt < 6; ++nt) accv[nt][reg] *= alpha;
        }
        __syncthreads();
#pragma unroll
        for (int ks = 0; ks < 2; ++ks) {
            bfrag af = *(const bfrag*)(Pt + (w * 16 + col) * 72 + ks * 32 + quad * 8);
#pragma unroll
            for (int nt = 0; nt < 6; ++nt) {
                bfrag bf = *(const bfrag*)(vt + (nt * 16 + col) * 72 + ks * 32 + quad * 8);
                accv[nt] = __builtin_amdgcn_mfma_f32_16x16x32_bf16(af, bf, accv[nt], 0, 0, 0);
            }
        }
    }

#pragma unroll
    for (int reg = 0; reg < 4; ++reg) {
        const int lq = w * 16 + quad * 4 + reg;
        const int qg = t0 + lq;
        float linv = 1.f / lrun[reg];
        float pb[9];
#pragma unroll
        for (int d = 0; d < 9; ++d)
            pb[d] = __expf(sband[lq * 12 + d] - mrun[reg]) * linv;
#pragma unroll
        for (int nt = 0; nt < 6; ++nt) {
            int c = nt * 16 + col;
            float r = accv[nt][reg] * linv;
#pragma unroll
            for (int d = 0; d < 9; ++d) r += pb[d] * rvs[d * 96 + c];
            Ob[(size_t)qg * HN + c] = f2bf(r);
        }
    }
}

// ---------------------------------------------------------------------------
// Residual + LayerNorm: x = LN(x + y)*g + b (fp32 in-place, ch-major)
// plus masked bf16 t-major copy xb for the next GEMM/conv input.
// ---------------------------------------------------------------------------
__global__ __launch_bounds__(256) void k_ln(float* __restrict__ x,
        const float* __restrict__ y, const float* __restrict__ g,
        const float* __restrict__ bb, short* __restrict__ xb,
        const int* __restrict__ lens) {
    __shared__ float s[HN][65];
    __shared__ float red1[256], red2[256];
    __shared__ float mu[64], rs[64];
    const int b = blockIdx.y;
    const int t0 = blockIdx.x * 64;
    const int tid = threadIdx.x;
    const int len = lens[b];

    for (int idx = tid; idx < HN * 64; idx += 256) {
        int c = idx >> 6, tt = idx & 63;
        size_t gi = ((size_t)b * HN + c) * TN + t0 + tt;
        s[c][tt] = x[gi] + y[gi];
    }
    __syncthreads();
    int tt = tid & 63, grp = tid >> 6;
    float sum = 0.f, sum2 = 0.f;
    for (int c = grp * 48; c < grp * 48 + 48; ++c) {
        float v = s[c][tt];
        sum += v;
        sum2 += v * v;
    }
    red1[tid] = sum;
    red2[tid] = sum2;
    __syncthreads();
    if (grp == 0) {
        float tot = red1[tt] + red1[64 + tt] + red1[128 + tt] + red1[192 + tt];
        float tot2 = red2[tt] + red2[64 + tt] + red2[128 + tt] + red2[192 + tt];
        float mean = tot / (float)HN;
        float var = tot2 / (float)HN - mean * mean;
        mu[tt] = mean;
        rs[tt] = rsqrtf(var + 1e-5f);
    }
    __syncthreads();
    for (int idx = tid; idx < HN * 64; idx += 256) {
        int c = idx >> 6, t2 = idx & 63;
        float v = (s[c][t2] - mu[t2]) * rs[t2] * g[c] + bb[c];
        x[((size_t)b * HN + c) * TN + t0 + t2] = v;
    }
    for (int idx = tid; idx < 64 * 96; idx += 256) {
        int t2 = idx / 96, p = idx % 96;
        int c0 = 2 * p;
        float v0 = (s[c0][t2] - mu[t2]) * rs[t2] * g[c0] + bb[c0];
        float v1 = (s[c0 + 1][t2] - mu[t2]) * rs[t2] * g[c0 + 1] + bb[c0 + 1];
        if (t0 + t2 >= len) { v0 = 0.f; v1 = 0.f; }
        ((int*)xb)[((size_t)(b * TN + t0 + t2)) * 96 + p] = pack2(v0, v1);
    }
}

// ---------------------------------------------------------------------------
// Final: z = m + eps*exp(logs)*mask ; outputs (z, m, logs, x*mask, mask)
// ---------------------------------------------------------------------------
__global__ void k_final(const float* __restrict__ stats, const float* __restrict__ x,
        const float* __restrict__ eps, const int* __restrict__ lens,
        float* __restrict__ out) {
    int idx = blockIdx.x * 256 + threadIdx.x;
    int t = idx % TN;
    int o = (idx / TN) % OUTN;
    int b = idx / (TN * OUTN);
    float maskv = (t < lens[b]) ? 1.f : 0.f;
    const size_t S = (size_t)BN * OUTN * TN;
    float m = stats[((size_t)(b * 2 * OUTN) + o) * TN + t];
    float ls = stats[((size_t)(b * 2 * OUTN) + OUTN + o) * TN + t];
    float e = eps[idx];
    out[idx] = m + e * expf(ls) * maskv;
    out[S + idx] = m;
    out[2 * S + idx] = ls;
    out[3 * S + idx] = x[idx] * maskv;
    if (o == 0) out[4 * S + (size_t)b * TN + t] = maskv;
}

// ---------------------------------------------------------------------------
extern "C" void kernel_launch(void* const* d_in, const int* in_sizes, int n_in,
                              void* d_out, int out_size, void* d_ws, size_t ws_size,
                              hipStream_t stream) {
    const int* tok = (const int*)d_in[0];
    const int* lens = (const int*)d_in[1];
    const float* emb = (const float*)d_in[2];
    const float* qw = (const float*)d_in[3];
    const float* qb = (const float*)d_in[4];
    const float* kw = (const float*)d_in[5];
    const float* kb = (const float*)d_in[6];
    const float* vw = (const float*)d_in[7];
    const float* vb = (const float*)d_in[8];
    const float* ow = (const float*)d_in[9];
    const float* ob = (const float*)d_in[10];
    const float* relk = (const float*)d_in[11];
    const float* relv = (const float*)d_in[12];
    const float* ln1g = (const float*)d_in[13];
    const float* ln1b = (const float*)d_in[14];
    const float* f1w = (const float*)d_in[15];
    const float* f1b = (const float*)d_in[16];
    const float* f2w = (const float*)d_in[17];
    const float* f2b = (const float*)d_in[18];
    const float* ln2g = (const float*)d_in[19];
    const float* ln2b = (const float*)d_in[20];
    const float* pw = (const float*)d_in[21];
    const float* pb = (const float*)d_in[22];
    const float* eps = (const float*)d_in[23];

    const size_t BHT = (size_t)BN * HN * TN; // 1,572,864
    float* ws = (float*)d_ws;
    float* x = ws;                       // fp32 ch-major
    float* yf = ws + BHT;                // fp32 ch-major (o-proj / f2 out)
    short* s_xb = (short*)(ws + 2 * BHT);            // bf16 t-major, qkv/stats input
    short* s_ln = (short*)(ws + 2 * BHT + BHT / 2);  // bf16 t-major, f1 input
    short* s_q  = (short*)(ws + 3 * BHT);
    short* s_k  = (short*)(ws + 3 * BHT + BHT / 2);
    short* s_v  = (short*)(ws + 4 * BHT);
    short* s_o  = (short*)(ws + 4 * BHT + BHT / 2);
    short* s_y1 = (short*)(ws + 5 * BHT);            // f1 out (B,T,FFN) = 4*BHT shorts
    float* stats = ws + 5 * BHT;                     // reused after layers
    float* wp = ws + 7 * BHT;
    short* wq16 = (short*)wp;
    short* wk16 = wq16 + (size_t)LN * HN * HN;
    short* wv16 = wk16 + (size_t)LN * HN * HN;
    short* wo16 = wv16 + (size_t)LN * HN * HN;
    short* wp16 = wo16 + (size_t)LN * HN * HN;
    short* wf1_16 = wp16 + (size_t)2 * OUTN * HN;
    short* wf2_16 = wf1_16 + (size_t)LN * 3 * FFNN * HN;

    // weight conversions
    {
        int n1 = LN * HN * HN;
        k_cvt<<<dim3((n1 + 255) / 256), 256, 0, stream>>>(qw, wq16, n1);
        k_cvt<<<dim3((n1 + 255) / 256), 256, 0, stream>>>(kw, wk16, n1);
        k_cvt<<<dim3((n1 + 255) / 256), 256, 0, stream>>>(vw, wv16, n1);
        k_cvt<<<dim3((n1 + 255) / 256), 256, 0, stream>>>(ow, wo16, n1);
        int n2 = 2 * OUTN * HN;
        k_cvt<<<dim3((n2 + 255) / 256), 256, 0, stream>>>(pw, wp16, n2);
        int n3 = LN * FFNN * HN * 3;
        k_cvtconv<<<dim3((n3 + 255) / 256), 256, 0, stream>>>(f1w, wf1_16, FFNN, HN, n3);
        k_cvtconv<<<dim3((n3 + 255) / 256), 256, 0, stream>>>(f2w, wf2_16, HN, FFNN, n3);
    }

    dim3 gemb(TN / 64, BN);
    k_embed<<<gemb, 256, 0, stream>>>(tok, lens, emb, x, s_xb);

    dim3 gproj(TN / 64, HN / 64, BN);   // 16 x 3 x 8
    dim3 gf1(TN / 64, FFNN / 64, BN);   // 16 x 12 x 8
    dim3 gattn(TN / 64, NHN, BN);       // 16 x 2 x 8
    dim3 gln(TN / 64, BN);              // 16 x 8
    const float qscale = 0.10206207261596575f; // 1/sqrt(96)

    for (int i = 0; i < LN; ++i) {
        const short* qwi = wq16 + (size_t)i * HN * HN;
        const short* kwi = wk16 + (size_t)i * HN * HN;
        const short* vwi = wv16 + (size_t)i * HN * HN;
        const short* owi = wo16 + (size_t)i * HN * HN;
        const short* f1wi = wf1_16 + (size_t)i * 3 * FFNN * HN;
        const short* f2wi = wf2_16 + (size_t)i * 3 * FFNN * HN;
        const float* qbi = qb + (size_t)i * HN;
        const float* kbi = kb + (size_t)i * HN;
        const float* vbi = vb + (size_t)i * HN;
        const float* obi = ob + (size_t)i * HN;
        const float* rki = relk + (size_t)i * 9 * KCN;
        const float* rvi = relv + (size_t)i * 9 * KCN;
        const float* l1gi = ln1g + (size_t)i * HN;
        const float* l1bi = ln1b + (size_t)i * HN;
        const float* f1bi = f1b + (size_t)i * FFNN;
        const float* f2bi = f2b + (size_t)i * HN;
        const float* l2gi = ln2g + (size_t)i * HN;
        const float* l2bi = ln2b + (size_t)i * HN;

        k_mgemm<1, false, false, 1><<<gproj, 256, 0, stream>>>(qwi, s_xb, qbi, s_q, lens, HN, HN, qscale);
        k_mgemm<1, false, false, 1><<<gproj, 256, 0, stream>>>(kwi, s_xb, kbi, s_k, lens, HN, HN, 1.f);
        k_mgemm<1, false, false, 2><<<gproj, 256, 0, stream>>>(vwi, s_xb, vbi, s_v, lens, HN, HN, 1.f);
        k_attn_mfma<<<gattn, 256, 0, stream>>>(s_q, s_k, s_v, rki, rvi, s_o, lens);
        k_mgemm<1, false, false, 0><<<gproj, 256, 0, stream>>>(owi, s_o, obi, yf, lens, HN, HN, 1.f);
        k_ln<<<gln, 256, 0, stream>>>(x, yf, l1gi, l1bi, s_ln, lens);
        k_mgemm<3, true, true, 1><<<gf1, 256, 0, stream>>>(f1wi, s_ln, f1bi, s_y1, lens, FFNN, HN, 1.f);
        k_mgemm<3, false, true, 0><<<gproj, 256, 0, stream>>>(f2wi, s_y1, f2bi, yf, lens, HN, FFNN, 1.f);
        k_ln<<<gln, 256, 0, stream>>>(x, yf, l2gi, l2bi, s_xb, lens);
    }

    dim3 gstat(TN / 64, (2 * OUTN) / 64, BN); // 16 x 6 x 8
    k_mgemm<1, false, true, 0><<<gstat, 256, 0, stream>>>(wp16, s_xb, pb, stats, lens, 2 * OUTN, HN, 1.f);
    k_final<<<dim3((unsigned)(BHT / 256)), 256, 0, stream>>>(stats, x, eps, lens, (float*)d_out);
}

// Round 4
// 1160.728 us; speedup vs baseline: 8.1014x; 1.2158x over previous
//
#include <hip/hip_runtime.h>
#include <math.h>

#define BN 8
#define TN 1024
#define HN 192
#define NHN 2
#define KCN 96
#define LN 6
#define FFNN 768
#define OUTN 192
#define QSTR 104  // qs/kt LDS row stride in shorts: 13 granule-groups (odd) -> conflict-free b128

typedef short bfrag __attribute__((ext_vector_type(8)));
typedef float f32x4 __attribute__((ext_vector_type(4)));

__device__ __forceinline__ short f2bf(float f) {
    union { float f; unsigned u; } v; v.f = f;
    unsigned r = v.u + 0x7fffu + ((v.u >> 16) & 1u);
    return (short)(r >> 16);
}
__device__ __forceinline__ float bf2f(short s) {
    union { unsigned u; float f; } v;
    v.u = ((unsigned)(unsigned short)s) << 16;
    return v.f;
}
__device__ __forceinline__ int pack2(float a, float b) {
    return (int)(unsigned short)f2bf(a) | (((int)(unsigned short)f2bf(b)) << 16);
}

#define QSCALE 0.10206207261596575f  // 1/sqrt(96)

// ---------------------------------------------------------------------------
// Weight conversions
// ---------------------------------------------------------------------------
__global__ void k_cvt(const float* __restrict__ src, short* __restrict__ dst, int n) {
    int i = blockIdx.x * 256 + threadIdx.x;
    if (i < n) dst[i] = f2bf(src[i]);
}
// src [L][M][Cin][3] -> dst [L][3][M][Cin]
__global__ void k_cvtconv(const float* __restrict__ src, short* __restrict__ dst,
                          int M, int Cin, int n) {
    int i = blockIdx.x * 256 + threadIdx.x;
    if (i >= n) return;
    int tap = i % 3;
    int c = (i / 3) % Cin;
    int m = (i / (3 * Cin)) % M;
    int l = i / (3 * Cin * M);
    dst[(((size_t)l * 3 + tap) * M + m) * Cin + c] = f2bf(src[i]);
}
// qw/kw/vw [L][192][192] -> wqkv [L][576][192], q rows pre-scaled by 1/sqrt(KC)
__global__ void k_cvt_qkv(const float* __restrict__ qw, const float* __restrict__ kw,
                          const float* __restrict__ vw, short* __restrict__ dst, int n) {
    int i = blockIdx.x * 256 + threadIdx.x;
    if (i >= n) return;
    int c = i % 192;
    int r = (i / 192) % 576;
    int l = i / (192 * 576);
    float val, sc = 1.f;
    if (r < 192) { val = qw[((size_t)l * 192 + r) * 192 + c]; sc = QSCALE; }
    else if (r < 384) val = kw[((size_t)l * 192 + (r - 192)) * 192 + c];
    else val = vw[((size_t)l * 192 + (r - 384)) * 192 + c];
    dst[i] = f2bf(val * sc);
}
__global__ void k_cvt_qkvb(const float* __restrict__ qb, const float* __restrict__ kb,
                           const float* __restrict__ vb, float* __restrict__ dst, int n) {
    int i = blockIdx.x * 256 + threadIdx.x;
    if (i >= n) return;
    int r = i % 576;
    int l = i / 576;
    dst[i] = (r < 192) ? qb[l * 192 + r] * QSCALE
           : (r < 384) ? kb[l * 192 + r - 192]
                       : vb[l * 192 + r - 384];
}

// ---------------------------------------------------------------------------
// Embedding: x fp32 ch-major (B,H,T) + xb bf16 t-major (B,T,H), both masked.
// ---------------------------------------------------------------------------
__global__ __launch_bounds__(256) void k_embed(const int* __restrict__ tok,
        const int* __restrict__ lens, const float* __restrict__ emb,
        float* __restrict__ x, short* __restrict__ xb) {
    __shared__ float s[HN][65];
    const int b = blockIdx.y, t0 = blockIdx.x * 64, tid = threadIdx.x;
    const int len = lens[b];
    for (int idx = tid; idx < 64 * HN; idx += 256) {
        int tt = idx / HN, c = idx % HN;
        int t = t0 + tt;
        float v = 0.f;
        if (t < len) v = emb[tok[b * TN + t] * HN + c] * 13.856406460551018f; // sqrt(192)
        s[c][tt] = v;
    }
    __syncthreads();
    for (int idx = tid; idx < 64 * HN; idx += 256) {
        int c = idx >> 6, tt = idx & 63;
        x[((size_t)b * HN + c) * TN + t0 + tt] = s[c][tt];
    }
    for (int idx = tid; idx < 64 * 96; idx += 256) {
        int tt = idx / 96, p = idx % 96;
        ((int*)xb)[((size_t)(b * TN + t0 + tt)) * 96 + p] = pack2(s[2 * p][tt], s[2 * p + 1][tt]);
    }
}

// ---------------------------------------------------------------------------
// MFMA bf16 GEMM / K-tap SAME conv (o-proj, f1, f2, stats).
// ---------------------------------------------------------------------------
template <int TAPS, bool RELU, bool MASK_OUT, int OUTK>
__global__ __launch_bounds__(256) void k_mgemm(
        const short* __restrict__ W, const short* __restrict__ X,
        const float* __restrict__ bias, void* __restrict__ Yv,
        const int* __restrict__ lens, int M, int Cin, float oscale) {
    constexpr int P = (TAPS - 1) / 2;
    constexpr int XS = 72;
    __shared__ short Wt[TAPS][64][XS];
    __shared__ short Xt[64 + 2 * P][XS];

    const int b = blockIdx.z;
    const int m0 = blockIdx.y * 64;
    const int t0 = blockIdx.x * 64;
    const int len = lens[b];
    const int tid = threadIdx.x;
    const int w = tid >> 6;
    const int lane = tid & 63;
    const int col = lane & 15;
    const int quad = lane >> 4;

    f32x4 acc[4];
#pragma unroll
    for (int st = 0; st < 4; ++st) acc[st] = (f32x4){0.f, 0.f, 0.f, 0.f};

    for (int c0 = 0; c0 < Cin; c0 += 64) {
        __syncthreads();
        for (int i = tid; i < TAPS * 64 * 8; i += 256) {
            int tap = i / (64 * 8);
            int mm = (i / 8) & 63;
            int part = i & 7;
            *(int4*)(&Wt[tap][mm][part * 8]) =
                *(const int4*)(W + ((size_t)tap * M + m0 + mm) * Cin + c0 + part * 8);
        }
        for (int i = tid; i < (64 + 2 * P) * 8; i += 256) {
            int tt = i >> 3;
            int part = i & 7;
            int t = t0 + tt - P;
            int4 v = {0, 0, 0, 0};
            if (t >= 0 && t < TN)
                v = *(const int4*)(X + ((size_t)b * TN + t) * Cin + c0 + part * 8);
            *(int4*)(&Xt[tt][part * 8]) = v;
        }
        __syncthreads();
#pragma unroll
        for (int ks = 0; ks < 2; ++ks) {
#pragma unroll
            for (int tap = 0; tap < TAPS; ++tap) {
                bfrag af = *(const bfrag*)(&Wt[tap][w * 16 + col][ks * 32 + quad * 8]);
#pragma unroll
                for (int st = 0; st < 4; ++st) {
                    bfrag bf = *(const bfrag*)(&Xt[st * 16 + col + tap][ks * 32 + quad * 8]);
                    acc[st] = __builtin_amdgcn_mfma_f32_16x16x32_bf16(af, bf, acc[st], 0, 0, 0);
                }
            }
        }
    }

    const int mbase = m0 + w * 16 + quad * 4;
    float bs[4];
#pragma unroll
    for (int reg = 0; reg < 4; ++reg) bs[reg] = bias[mbase + reg];
#pragma unroll
    for (int st = 0; st < 4; ++st) {
        int t = t0 + st * 16 + col;
        bool om = MASK_OUT && (t >= len);
        float v[4];
#pragma unroll
        for (int reg = 0; reg < 4; ++reg) {
            float u = (acc[st][reg] + bs[reg]) * oscale;
            if (RELU) u = fmaxf(u, 0.f);
            if (om) u = 0.f;
            v[reg] = u;
        }
        if (OUTK == 0) {
#pragma unroll
            for (int reg = 0; reg < 4; ++reg)
                ((float*)Yv)[((size_t)b * M + mbase + reg) * TN + t] = v[reg];
        } else if (OUTK == 1) {
            int2 pk;
            pk.x = pack2(v[0], v[1]);
            pk.y = pack2(v[2], v[3]);
            *(int2*)((short*)Yv + ((size_t)(b * TN + t)) * M + mbase) = pk;
        } else {
#pragma unroll
            for (int reg = 0; reg < 4; ++reg)
                ((short*)Yv)[((size_t)b * M + mbase + reg) * TN + t] = f2bf(v[reg]);
        }
    }
}

// ---------------------------------------------------------------------------
// Fused QKV projection: W [576][192] (q rows pre-scaled), X bf16 t-major.
// m0/192 selects output: q,k -> bf16 t-major (B,T,96*2ch per head grouping =
// (B,T,192)); v -> bf16 ch-major (B,192,T). Grid (16, 9, 8).
// ---------------------------------------------------------------------------
__global__ __launch_bounds__(256) void k_qkv(
        const short* __restrict__ W, const short* __restrict__ X,
        const float* __restrict__ bias, short* __restrict__ qo,
        short* __restrict__ ko, short* __restrict__ vo) {
    __shared__ short Wt[64][72];
    __shared__ short Xt[64][72];
    const int b = blockIdx.z;
    const int m0 = blockIdx.y * 64;
    const int t0 = blockIdx.x * 64;
    const int tid = threadIdx.x;
    const int w = tid >> 6;
    const int lane = tid & 63;
    const int col = lane & 15;
    const int quad = lane >> 4;

    f32x4 acc[4];
#pragma unroll
    for (int st = 0; st < 4; ++st) acc[st] = (f32x4){0.f, 0.f, 0.f, 0.f};

    for (int c0 = 0; c0 < 192; c0 += 64) {
        __syncthreads();
        for (int i = tid; i < 512; i += 256) {
            int mm = i >> 3, part = i & 7;
            *(int4*)(&Wt[mm][part * 8]) =
                *(const int4*)(W + ((size_t)(m0 + mm)) * 192 + c0 + part * 8);
        }
        for (int i = tid; i < 512; i += 256) {
            int tt = i >> 3, part = i & 7;
            *(int4*)(&Xt[tt][part * 8]) =
                *(const int4*)(X + ((size_t)(b * TN + t0 + tt)) * 192 + c0 + part * 8);
        }
        __syncthreads();
#pragma unroll
        for (int ks = 0; ks < 2; ++ks) {
            bfrag af = *(const bfrag*)(&Wt[w * 16 + col][ks * 32 + quad * 8]);
#pragma unroll
            for (int st = 0; st < 4; ++st) {
                bfrag bf = *(const bfrag*)(&Xt[st * 16 + col][ks * 32 + quad * 8]);
                acc[st] = __builtin_amdgcn_mfma_f32_16x16x32_bf16(af, bf, acc[st], 0, 0, 0);
            }
        }
    }

    const int mbase = m0 + w * 16 + quad * 4;
    const int proj = m0 / 192;           // block-uniform: 0=q 1=k 2=v
    const int mloc = mbase - proj * 192;
    float bs[4];
#pragma unroll
    for (int reg = 0; reg < 4; ++reg) bs[reg] = bias[mbase + reg];
#pragma unroll
    for (int st = 0; st < 4; ++st) {
        int t = t0 + st * 16 + col;
        float v[4];
#pragma unroll
        for (int reg = 0; reg < 4; ++reg) v[reg] = acc[st][reg] + bs[reg];
        if (proj < 2) {
            short* dst = (proj == 0) ? qo : ko;
            int2 pk;
            pk.x = pack2(v[0], v[1]);
            pk.y = pack2(v[2], v[3]);
            *(int2*)(dst + ((size_t)(b * TN + t)) * 192 + mloc) = pk;
        } else {
#pragma unroll
            for (int reg = 0; reg < 4; ++reg)
                vo[((size_t)b * 192 + mloc + reg) * TN + t] = f2bf(v[reg]);
        }
    }
}

// ---------------------------------------------------------------------------
// MFMA bf16 flash attention, 2 s-groups in-block (512 threads, 8 waves).
// Group g handles s in [g*512, g*512+512); in-LDS merge of (m,l,acc).
// Q,K bf16 t-major (B,T,192) head at +h*96; V bf16 ch-major (B,192,T);
// O bf16 t-major (B,T,192). Band rel scores merge-free (raw-score log).
// ---------------------------------------------------------------------------
__global__ __launch_bounds__(512) void k_attn2(
        const short* __restrict__ Q, const short* __restrict__ K,
        const short* __restrict__ V, const float* __restrict__ relk,
        const float* __restrict__ relv, short* __restrict__ O,
        const int* __restrict__ lens) {
    __shared__ short qs[64 * QSTR];
    __shared__ short kt[2][64 * QSTR];
    __shared__ short vt[2][96 * 72];
    __shared__ short Pt[2][64 * 72];
    __shared__ float rels[64 * 12];
    __shared__ float sband[64 * 12];
    __shared__ float rvs[9 * 96];
    __shared__ float mred[64], lred[64];

    const int b = blockIdx.z, h = blockIdx.y;
    const int t0 = blockIdx.x * 64;
    const int len = lens[b];
    const int tid = threadIdx.x;
    const int g = tid >> 8;          // s-group
    const int w = (tid >> 6) & 3;    // wave within group
    const int lane = tid & 63;
    const int col = lane & 15;
    const int quad = lane >> 4;

    const short* Qb = Q + ((size_t)b * TN + t0) * HN + h * KCN;
    const short* Kg = K + ((size_t)b * TN + g * 512) * HN + h * KCN;
    const short* Vg = V + ((size_t)b * HN + h * KCN) * TN + g * 512;
    short* Ob = O + (size_t)b * TN * HN + h * KCN;

    for (int i = tid; i < 768; i += 512) {
        int row = i / 12, part = i % 12;
        *(int4*)(qs + row * QSTR + part * 8) = *(const int4*)(Qb + (size_t)row * HN + part * 8);
    }
    for (int i = tid; i < 9 * 96; i += 512) rvs[i] = relv[i];
    for (int i = tid; i < 768; i += 512) sband[i] = -1e30f;
    __syncthreads();
    for (int i = tid; i < 576; i += 512) {
        int lq = i / 9, d = i % 9;
        float s = 0.f;
        const float* rk = relk + d * 96;
        const short* qrow = qs + lq * QSTR;
#pragma unroll 4
        for (int c = 0; c < 96; c += 2)
            s += bf2f(qrow[c]) * rk[c] + bf2f(qrow[c + 1]) * rk[c + 1];
        rels[lq * 12 + d] = s;
    }
    // rels/sband/rvs become visible at the first in-loop barrier pair.

    float mrun[4], lrun[4];
    f32x4 accv[6];
#pragma unroll
    for (int r = 0; r < 4; ++r) { mrun[r] = -1e30f; lrun[r] = 0.f; }
#pragma unroll
    for (int n = 0; n < 6; ++n) accv[n] = (f32x4){0.f, 0.f, 0.f, 0.f};

    const int lt = tid & 255;
    for (int j = 0; j < 8; ++j) {
        const int s0 = g * 512 + j * 64;
        const bool active = s0 < len;  // group 0: always (len >= 512)
        __syncthreads();  // prev iter's Pt/vt/kt reads done
        if (active) {
            for (int i = lt; i < 768; i += 256) {
                int row = i / 12, part = i % 12;
                *(int4*)(kt[g] + row * QSTR + part * 8) =
                    *(const int4*)(Kg + ((size_t)(j * 64 + row)) * HN + part * 8);
            }
            for (int i = lt; i < 768; i += 256) {
                int c = i >> 3, part = i & 7;
                *(int4*)(vt[g] + c * 72 + part * 8) =
                    *(const int4*)(Vg + (size_t)c * TN + j * 64 + part * 8);
            }
        }
        __syncthreads();
        if (!active) continue;

        f32x4 sacc[4];
#pragma unroll
        for (int st = 0; st < 4; ++st) sacc[st] = (f32x4){0.f, 0.f, 0.f, 0.f};
#pragma unroll
        for (int ks = 0; ks < 3; ++ks) {
            bfrag af = *(const bfrag*)(qs + (w * 16 + col) * QSTR + ks * 32 + quad * 8);
#pragma unroll
            for (int st = 0; st < 4; ++st) {
                bfrag bf = *(const bfrag*)(kt[g] + (st * 16 + col) * QSTR + ks * 32 + quad * 8);
                sacc[st] = __builtin_amdgcn_mfma_f32_16x16x32_bf16(af, bf, sacc[st], 0, 0, 0);
            }
        }

#pragma unroll
        for (int reg = 0; reg < 4; ++reg) {
            const int lq = w * 16 + quad * 4 + reg;
            const int qg = t0 + lq;
            float sc[4];
            float tm = -1e30f;
#pragma unroll
            for (int st = 0; st < 4; ++st) {
                int sg = s0 + st * 16 + col;
                float v = sacc[st][reg];
                int d = sg - qg + 4;
                bool inb = (d >= 0) && (d <= 8);
                if (inb) v += rels[lq * 12 + d];
                if (sg >= len) v = -1e4f;
                if (inb) sband[lq * 12 + d] = v;
                sc[st] = v;
                tm = fmaxf(tm, v);
            }
            tm = fmaxf(tm, __shfl_xor(tm, 1));
            tm = fmaxf(tm, __shfl_xor(tm, 2));
            tm = fmaxf(tm, __shfl_xor(tm, 4));
            tm = fmaxf(tm, __shfl_xor(tm, 8));
            float mnew = fmaxf(mrun[reg], tm);
            float alpha = __expf(mrun[reg] - mnew);
            mrun[reg] = mnew;
            float ps = 0.f;
#pragma unroll
            for (int st = 0; st < 4; ++st) {
                float p = __expf(sc[st] - mnew);
                ps += p;
                Pt[g][lq * 72 + st * 16 + col] = f2bf(p);
            }
            ps += __shfl_xor(ps, 1);
            ps += __shfl_xor(ps, 2);
            ps += __shfl_xor(ps, 4);
            ps += __shfl_xor(ps, 8);
            lrun[reg] = lrun[reg] * alpha + ps;
#pragma unroll
            for (int nt = 0; nt < 6; ++nt) accv[nt][reg] *= alpha;
        }
        // Pt rows w*16.. are written and read by the same wave: no barrier.
#pragma unroll
        for (int ks = 0; ks < 2; ++ks) {
            bfrag af = *(const bfrag*)(Pt[g] + (w * 16 + col) * 72 + ks * 32 + quad * 8);
#pragma unroll
            for (int nt = 0; nt < 6; ++nt) {
                bfrag bf = *(const bfrag*)(vt[g] + (nt * 16 + col) * 72 + ks * 32 + quad * 8);
                accv[nt] = __builtin_amdgcn_mfma_f32_16x16x32_bf16(af, bf, accv[nt], 0, 0, 0);
            }
        }
    }

    __syncthreads();
    float* facc = (float*)kt;  // 64*96 fp32 = 24.6 KB, fits in kt (26.6 KB)
    if (g == 1) {
#pragma unroll
        for (int reg = 0; reg < 4; ++reg) {
            const int lq = w * 16 + quad * 4 + reg;
            if (col == 0) { mred[lq] = mrun[reg]; lred[lq] = lrun[reg]; }
#pragma unroll
            for (int nt = 0; nt < 6; ++nt)
                facc[lq * 96 + nt * 16 + col] = accv[nt][reg];
        }
    }
    __syncthreads();
    if (g == 0) {
#pragma unroll
        for (int reg = 0; reg < 4; ++reg) {
            const int lq = w * 16 + quad * 4 + reg;
            const int qg = t0 + lq;
            float m1 = mred[lq], l1 = lred[lq];
            float m = fmaxf(mrun[reg], m1);
            float e0 = __expf(mrun[reg] - m);
            float e1 = __expf(m1 - m);
            float l = lrun[reg] * e0 + l1 * e1;
            float linv = 1.f / l;
            float pb[9];
#pragma unroll
            for (int d = 0; d < 9; ++d)
                pb[d] = __expf(sband[lq * 12 + d] - m) * linv;
#pragma unroll
            for (int nt = 0; nt < 6; ++nt) {
                int c = nt * 16 + col;
                float r = (accv[nt][reg] * e0 + facc[lq * 96 + c] * e1) * linv;
#pragma unroll
                for (int d = 0; d < 9; ++d) r += pb[d] * rvs[d * 96 + c];
                Ob[(size_t)qg * HN + c] = f2bf(r);
            }
        }
    }
}

// ---------------------------------------------------------------------------
// Residual + LayerNorm: x = LN(x + y)*g + b (fp32 in-place, ch-major)
// plus masked bf16 t-major copy xb.
// ---------------------------------------------------------------------------
__global__ __launch_bounds__(256) void k_ln(float* __restrict__ x,
        const float* __restrict__ y, const float* __restrict__ g,
        const float* __restrict__ bb, short* __restrict__ xb,
        const int* __restrict__ lens) {
    __shared__ float s[HN][65];
    __shared__ float red1[256], red2[256];
    __shared__ float mu[64], rs[64];
    const int b = blockIdx.y;
    const int t0 = blockIdx.x * 64;
    const int tid = threadIdx.x;
    const int len = lens[b];

    for (int idx = tid; idx < HN * 64; idx += 256) {
        int c = idx >> 6, tt = idx & 63;
        size_t gi = ((size_t)b * HN + c) * TN + t0 + tt;
        s[c][tt] = x[gi] + y[gi];
    }
    __syncthreads();
    int tt = tid & 63, grp = tid >> 6;
    float sum = 0.f, sum2 = 0.f;
    for (int c = grp * 48; c < grp * 48 + 48; ++c) {
        float v = s[c][tt];
        sum += v;
        sum2 += v * v;
    }
    red1[tid] = sum;
    red2[tid] = sum2;
    __syncthreads();
    if (grp == 0) {
        float tot = red1[tt] + red1[64 + tt] + red1[128 + tt] + red1[192 + tt];
        float tot2 = red2[tt] + red2[64 + tt] + red2[128 + tt] + red2[192 + tt];
        float mean = tot / (float)HN;
        float var = tot2 / (float)HN - mean * mean;
        mu[tt] = mean;
        rs[tt] = rsqrtf(var + 1e-5f);
    }
    __syncthreads();
    for (int idx = tid; idx < HN * 64; idx += 256) {
        int c = idx >> 6, t2 = idx & 63;
        float v = (s[c][t2] - mu[t2]) * rs[t2] * g[c] + bb[c];
        x[((size_t)b * HN + c) * TN + t0 + t2] = v;
    }
    for (int idx = tid; idx < 64 * 96; idx += 256) {
        int t2 = idx / 96, p = idx % 96;
        int c0 = 2 * p;
        float v0 = (s[c0][t2] - mu[t2]) * rs[t2] * g[c0] + bb[c0];
        float v1 = (s[c0 + 1][t2] - mu[t2]) * rs[t2] * g[c0 + 1] + bb[c0 + 1];
        if (t0 + t2 >= len) { v0 = 0.f; v1 = 0.f; }
        ((int*)xb)[((size_t)(b * TN + t0 + t2)) * 96 + p] = pack2(v0, v1);
    }
}

// ---------------------------------------------------------------------------
// Final: z = m + eps*exp(logs)*mask ; outputs (z, m, logs, x*mask, mask)
// ---------------------------------------------------------------------------
__global__ void k_final(const float* __restrict__ stats, const float* __restrict__ x,
        const float* __restrict__ eps, const int* __restrict__ lens,
        float* __restrict__ out) {
    int idx = blockIdx.x * 256 + threadIdx.x;
    int t = idx % TN;
    int o = (idx / TN) % OUTN;
    int b = idx / (TN * OUTN);
    float maskv = (t < lens[b]) ? 1.f : 0.f;
    const size_t S = (size_t)BN * OUTN * TN;
    float m = stats[((size_t)(b * 2 * OUTN) + o) * TN + t];
    float ls = stats[((size_t)(b * 2 * OUTN) + OUTN + o) * TN + t];
    float e = eps[idx];
    out[idx] = m + e * expf(ls) * maskv;
    out[S + idx] = m;
    out[2 * S + idx] = ls;
    out[3 * S + idx] = x[idx] * maskv;
    if (o == 0) out[4 * S + (size_t)b * TN + t] = maskv;
}

// ---------------------------------------------------------------------------
extern "C" void kernel_launch(void* const* d_in, const int* in_sizes, int n_in,
                              void* d_out, int out_size, void* d_ws, size_t ws_size,
                              hipStream_t stream) {
    const int* tok = (const int*)d_in[0];
    const int* lens = (const int*)d_in[1];
    const float* emb = (const float*)d_in[2];
    const float* qw = (const float*)d_in[3];
    const float* qb = (const float*)d_in[4];
    const float* kw = (const float*)d_in[5];
    const float* kb = (const float*)d_in[6];
    const float* vw = (const float*)d_in[7];
    const float* vb = (const float*)d_in[8];
    const float* ow = (const float*)d_in[9];
    const float* ob = (const float*)d_in[10];
    const float* relk = (const float*)d_in[11];
    const float* relv = (const float*)d_in[12];
    const float* ln1g = (const float*)d_in[13];
    const float* ln1b = (const float*)d_in[14];
    const float* f1w = (const float*)d_in[15];
    const float* f1b = (const float*)d_in[16];
    const float* f2w = (const float*)d_in[17];
    const float* f2b = (const float*)d_in[18];
    const float* ln2g = (const float*)d_in[19];
    const float* ln2b = (const float*)d_in[20];
    const float* pw = (const float*)d_in[21];
    const float* pb = (const float*)d_in[22];
    const float* eps = (const float*)d_in[23];

    const size_t BHT = (size_t)BN * HN * TN; // 1,572,864
    float* ws = (float*)d_ws;
    float* x = ws;                                   // fp32 ch-major
    float* yf = ws + BHT;                            // fp32 ch-major
    short* s_xb = (short*)(ws + 2 * BHT);            // bf16 t-major (qkv/stats in)
    short* s_ln = (short*)(ws + 2 * BHT + BHT / 2);  // bf16 t-major (f1 in)
    short* s_q  = (short*)(ws + 3 * BHT);
    short* s_k  = (short*)(ws + 3 * BHT + BHT / 2);
    short* s_v  = (short*)(ws + 4 * BHT);
    short* s_o  = (short*)(ws + 4 * BHT + BHT / 2);
    short* s_y1 = (short*)(ws + 5 * BHT);            // f1 out (B,T,FFN)
    float* stats = ws + 5 * BHT;                     // reused after layers
    short* wqkv = (short*)(ws + 7 * BHT);            // [L][576][192]
    short* wo16 = wqkv + (size_t)LN * 3 * HN * HN;
    short* wp16 = wo16 + (size_t)LN * HN * HN;
    short* wf1_16 = wp16 + (size_t)2 * OUTN * HN;
    short* wf2_16 = wf1_16 + (size_t)LN * 3 * FFNN * HN;
    float* bqkv = (float*)(wf2_16 + (size_t)LN * 3 * FFNN * HN);  // [L][576]

    // weight conversions
    {
        int nq = LN * 576 * 192;
        k_cvt_qkv<<<dim3((nq + 255) / 256), 256, 0, stream>>>(qw, kw, vw, wqkv, nq);
        int nqb = LN * 576;
        k_cvt_qkvb<<<dim3((nqb + 255) / 256), 256, 0, stream>>>(qb, kb, vb, bqkv, nqb);
        int n1 = LN * HN * HN;
        k_cvt<<<dim3((n1 + 255) / 256), 256, 0, stream>>>(ow, wo16, n1);
        int n2 = 2 * OUTN * HN;
        k_cvt<<<dim3((n2 + 255) / 256), 256, 0, stream>>>(pw, wp16, n2);
        int n3 = LN * FFNN * HN * 3;
        k_cvtconv<<<dim3((n3 + 255) / 256), 256, 0, stream>>>(f1w, wf1_16, FFNN, HN, n3);
        k_cvtconv<<<dim3((n3 + 255) / 256), 256, 0, stream>>>(f2w, wf2_16, HN, FFNN, n3);
    }

    dim3 gemb(TN / 64, BN);
    k_embed<<<gemb, 256, 0, stream>>>(tok, lens, emb, x, s_xb);

    dim3 gproj(TN / 64, HN / 64, BN);   // 16 x 3 x 8
    dim3 gqkv(TN / 64, 9, BN);          // 16 x 9 x 8
    dim3 gf1(TN / 64, FFNN / 64, BN);   // 16 x 12 x 8
    dim3 gattn(TN / 64, NHN, BN);       // 16 x 2 x 8 (512-thread blocks)
    dim3 gln(TN / 64, BN);              // 16 x 8

    for (int i = 0; i < LN; ++i) {
        const short* qkvwi = wqkv + (size_t)i * 576 * 192;
        const float* qkvbi = bqkv + (size_t)i * 576;
        const short* owi = wo16 + (size_t)i * HN * HN;
        const short* f1wi = wf1_16 + (size_t)i * 3 * FFNN * HN;
        const short* f2wi = wf2_16 + (size_t)i * 3 * FFNN * HN;
        const float* obi = ob + (size_t)i * HN;
        const float* rki = relk + (size_t)i * 9 * KCN;
        const float* rvi = relv + (size_t)i * 9 * KCN;
        const float* l1gi = ln1g + (size_t)i * HN;
        const float* l1bi = ln1b + (size_t)i * HN;
        const float* f1bi = f1b + (size_t)i * FFNN;
        const float* f2bi = f2b + (size_t)i * HN;
        const float* l2gi = ln2g + (size_t)i * HN;
        const float* l2bi = ln2b + (size_t)i * HN;

        k_qkv<<<gqkv, 256, 0, stream>>>(qkvwi, s_xb, qkvbi, s_q, s_k, s_v);
        k_attn2<<<gattn, 512, 0, stream>>>(s_q, s_k, s_v, rki, rvi, s_o, lens);
        k_mgemm<1, false, false, 0><<<gproj, 256, 0, stream>>>(owi, s_o, obi, yf, lens, HN, HN, 1.f);
        k_ln<<<gln, 256, 0, stream>>>(x, yf, l1gi, l1bi, s_ln, lens);
        k_mgemm<3, true, true, 1><<<gf1, 256, 0, stream>>>(f1wi, s_ln, f1bi, s_y1, lens, FFNN, HN, 1.f);
        k_mgemm<3, false, true, 0><<<gproj, 256, 0, stream>>>(f2wi, s_y1, f2bi, yf, lens, HN, FFNN, 1.f);
        k_ln<<<gln, 256, 0, stream>>>(x, yf, l2gi, l2bi, s_xb, lens);
    }

    dim3 gstat(TN / 64, (2 * OUTN) / 64, BN); // 16 x 6 x 8
    k_mgemm<1, false, true, 0><<<gstat, 256, 0, stream>>>(wp16, s_xb, pb, stats, lens, 2 * OUTN, HN, 1.f);
    k_final<<<dim3((unsigned)(BHT / 256)), 256, 0, stream>>>(stats, x, eps, lens, (float*)d_out);
}

// Round 6
// 955.562 us; speedup vs baseline: 9.8409x; 1.2147x over previous
//
#include <hip/hip_runtime.h>
#include <math.h>

#define BN 8
#define TN 1024
#define HN 192
#define NHN 2
#define KCN 96
#define LN 6
#define FFNN 768
#define OUTN 192
#define QSTR 104  // qs/kt LDS row stride in shorts: 13 granules (odd) -> conflict-free b128
#define M0S 12.0f // fixed softmax shift: scores are O(1); exp(s-12) safe to s~100

typedef short bfrag __attribute__((ext_vector_type(8)));
typedef float f32x4 __attribute__((ext_vector_type(4)));

__device__ __forceinline__ short f2bf(float f) {
    union { float f; unsigned u; } v; v.f = f;
    unsigned r = v.u + 0x7fffu + ((v.u >> 16) & 1u);
    return (short)(r >> 16);
}
__device__ __forceinline__ float bf2f(short s) {
    union { unsigned u; float f; } v;
    v.u = ((unsigned)(unsigned short)s) << 16;
    return v.f;
}
__device__ __forceinline__ int pack2(float a, float b) {
    return (int)(unsigned short)f2bf(a) | (((int)(unsigned short)f2bf(b)) << 16);
}

#define QSCALE 0.10206207261596575f  // 1/sqrt(96)

// ---------------------------------------------------------------------------
// Weight conversions
// ---------------------------------------------------------------------------
__global__ void k_cvt(const float* __restrict__ src, short* __restrict__ dst, int n) {
    int i = blockIdx.x * 256 + threadIdx.x;
    if (i < n) dst[i] = f2bf(src[i]);
}
// src [L][M][Cin][3] -> dst [L][3][M][Cin]
__global__ void k_cvtconv(const float* __restrict__ src, short* __restrict__ dst,
                          int M, int Cin, int n) {
    int i = blockIdx.x * 256 + threadIdx.x;
    if (i >= n) return;
    int tap = i % 3;
    int c = (i / 3) % Cin;
    int m = (i / (3 * Cin)) % M;
    int l = i / (3 * Cin * M);
    dst[(((size_t)l * 3 + tap) * M + m) * Cin + c] = f2bf(src[i]);
}
// qw/kw/vw [L][192][192] -> wqkv [L][576][192], q rows pre-scaled by 1/sqrt(KC)
__global__ void k_cvt_qkv(const float* __restrict__ qw, const float* __restrict__ kw,
                          const float* __restrict__ vw, short* __restrict__ dst, int n) {
    int i = blockIdx.x * 256 + threadIdx.x;
    if (i >= n) return;
    int c = i % 192;
    int r = (i / 192) % 576;
    int l = i / (192 * 576);
    float val, sc = 1.f;
    if (r < 192) { val = qw[((size_t)l * 192 + r) * 192 + c]; sc = QSCALE; }
    else if (r < 384) val = kw[((size_t)l * 192 + (r - 192)) * 192 + c];
    else val = vw[((size_t)l * 192 + (r - 384)) * 192 + c];
    dst[i] = f2bf(val * sc);
}
__global__ void k_cvt_qkvb(const float* __restrict__ qb, const float* __restrict__ kb,
                           const float* __restrict__ vb, float* __restrict__ dst, int n) {
    int i = blockIdx.x * 256 + threadIdx.x;
    if (i >= n) return;
    int r = i % 576;
    int l = i / 576;
    dst[i] = (r < 192) ? qb[l * 192 + r] * QSCALE
           : (r < 384) ? kb[l * 192 + r - 192]
                       : vb[l * 192 + r - 384];
}

// ---------------------------------------------------------------------------
// Embedding: x fp32 ch-major (B,H,T) + xb bf16 t-major (B,T,H), both masked.
// ---------------------------------------------------------------------------
__global__ __launch_bounds__(256) void k_embed(const int* __restrict__ tok,
        const int* __restrict__ lens, const float* __restrict__ emb,
        float* __restrict__ x, short* __restrict__ xb) {
    __shared__ float s[HN][65];
    const int b = blockIdx.y, t0 = blockIdx.x * 64, tid = threadIdx.x;
    const int len = lens[b];
    for (int idx = tid; idx < 64 * HN; idx += 256) {
        int tt = idx / HN, c = idx % HN;
        int t = t0 + tt;
        float v = 0.f;
        if (t < len) v = emb[tok[b * TN + t] * HN + c] * 13.856406460551018f; // sqrt(192)
        s[c][tt] = v;
    }
    __syncthreads();
    for (int idx = tid; idx < 64 * HN; idx += 256) {
        int c = idx >> 6, tt = idx & 63;
        x[((size_t)b * HN + c) * TN + t0 + tt] = s[c][tt];
    }
    for (int idx = tid; idx < 64 * 96; idx += 256) {
        int tt = idx / 96, p = idx % 96;
        ((int*)xb)[((size_t)(b * TN + t0 + tt)) * 96 + p] = pack2(s[2 * p][tt], s[2 * p + 1][tt]);
    }
}

// ---------------------------------------------------------------------------
// MFMA bf16 GEMM / K-tap SAME conv (o-proj, f1, f2, stats).
// KSPLIT2: grid.y doubled; kg selects the Cin half; kg==0 writes Yv (with
// bias), kg==1 writes the partial to Yv2 (no bias). OUTK=0 only.
// ---------------------------------------------------------------------------
template <int TAPS, bool RELU, bool MASK_OUT, int OUTK, bool KSPLIT2>
__global__ __launch_bounds__(256) void k_mgemm(
        const short* __restrict__ W, const short* __restrict__ X,
        const float* __restrict__ bias, void* __restrict__ Yv,
        float* __restrict__ Yv2,
        const int* __restrict__ lens, int M, int Cin, float oscale) {
    constexpr int P = (TAPS - 1) / 2;
    constexpr int XS = 72;
    __shared__ short Wt[TAPS][64][XS];
    __shared__ short Xt[64 + 2 * P][XS];

    const int b = blockIdx.z;
    const int mtiles = KSPLIT2 ? (gridDim.y >> 1) : gridDim.y;
    const int kg = KSPLIT2 ? (blockIdx.y / mtiles) : 0;
    const int m0 = (KSPLIT2 ? (blockIdx.y % mtiles) : blockIdx.y) * 64;
    const int t0 = blockIdx.x * 64;
    const int len = lens[b];
    const int tid = threadIdx.x;
    const int w = tid >> 6;
    const int lane = tid & 63;
    const int col = lane & 15;
    const int quad = lane >> 4;

    f32x4 acc[4];
#pragma unroll
    for (int st = 0; st < 4; ++st) acc[st] = (f32x4){0.f, 0.f, 0.f, 0.f};

    const int cbeg = KSPLIT2 ? kg * (Cin >> 1) : 0;
    const int cend = KSPLIT2 ? cbeg + (Cin >> 1) : Cin;
    for (int c0 = cbeg; c0 < cend; c0 += 64) {
        __syncthreads();
        for (int i = tid; i < TAPS * 64 * 8; i += 256) {
            int tap = i / (64 * 8);
            int mm = (i / 8) & 63;
            int part = i & 7;
            *(int4*)(&Wt[tap][mm][part * 8]) =
                *(const int4*)(W + ((size_t)tap * M + m0 + mm) * Cin + c0 + part * 8);
        }
        for (int i = tid; i < (64 + 2 * P) * 8; i += 256) {
            int tt = i >> 3;
            int part = i & 7;
            int t = t0 + tt - P;
            int4 v = {0, 0, 0, 0};
            if (t >= 0 && t < TN)
                v = *(const int4*)(X + ((size_t)b * TN + t) * Cin + c0 + part * 8);
            *(int4*)(&Xt[tt][part * 8]) = v;
        }
        __syncthreads();
#pragma unroll
        for (int ks = 0; ks < 2; ++ks) {
#pragma unroll
            for (int tap = 0; tap < TAPS; ++tap) {
                bfrag af = *(const bfrag*)(&Wt[tap][w * 16 + col][ks * 32 + quad * 8]);
#pragma unroll
                for (int st = 0; st < 4; ++st) {
                    bfrag bf = *(const bfrag*)(&Xt[st * 16 + col + tap][ks * 32 + quad * 8]);
                    acc[st] = __builtin_amdgcn_mfma_f32_16x16x32_bf16(af, bf, acc[st], 0, 0, 0);
                }
            }
        }
    }

    const int mbase = m0 + w * 16 + quad * 4;
    float bs[4];
#pragma unroll
    for (int reg = 0; reg < 4; ++reg)
        bs[reg] = (KSPLIT2 && kg) ? 0.f : bias[mbase + reg];
#pragma unroll
    for (int st = 0; st < 4; ++st) {
        int t = t0 + st * 16 + col;
        bool om = MASK_OUT && (t >= len);
        float v[4];
#pragma unroll
        for (int reg = 0; reg < 4; ++reg) {
            float u = (acc[st][reg] + bs[reg]) * oscale;
            if (RELU) u = fmaxf(u, 0.f);
            if (om) u = 0.f;
            v[reg] = u;
        }
        if (OUTK == 0) {
            float* dst = (KSPLIT2 && kg) ? Yv2 : (float*)Yv;
#pragma unroll
            for (int reg = 0; reg < 4; ++reg)
                dst[((size_t)b * M + mbase + reg) * TN + t] = v[reg];
        } else if (OUTK == 1) {
            int2 pk;
            pk.x = pack2(v[0], v[1]);
            pk.y = pack2(v[2], v[3]);
            *(int2*)((short*)Yv + ((size_t)(b * TN + t)) * M + mbase) = pk;
        } else {
#pragma unroll
            for (int reg = 0; reg < 4; ++reg)
                ((short*)Yv)[((size_t)b * M + mbase + reg) * TN + t] = f2bf(v[reg]);
        }
    }
}

// ---------------------------------------------------------------------------
// Fused QKV projection: W [576][192] (q rows pre-scaled), X bf16 t-major.
// ---------------------------------------------------------------------------
__global__ __launch_bounds__(256) void k_qkv(
        const short* __restrict__ W, const short* __restrict__ X,
        const float* __restrict__ bias, short* __restrict__ qo,
        short* __restrict__ ko, short* __restrict__ vo) {
    __shared__ short Wt[64][72];
    __shared__ short Xt[64][72];
    const int b = blockIdx.z;
    const int m0 = blockIdx.y * 64;
    const int t0 = blockIdx.x * 64;
    const int tid = threadIdx.x;
    const int w = tid >> 6;
    const int lane = tid & 63;
    const int col = lane & 15;
    const int quad = lane >> 4;

    f32x4 acc[4];
#pragma unroll
    for (int st = 0; st < 4; ++st) acc[st] = (f32x4){0.f, 0.f, 0.f, 0.f};

    for (int c0 = 0; c0 < 192; c0 += 64) {
        __syncthreads();
        for (int i = tid; i < 512; i += 256) {
            int mm = i >> 3, part = i & 7;
            *(int4*)(&Wt[mm][part * 8]) =
                *(const int4*)(W + ((size_t)(m0 + mm)) * 192 + c0 + part * 8);
        }
        for (int i = tid; i < 512; i += 256) {
            int tt = i >> 3, part = i & 7;
            *(int4*)(&Xt[tt][part * 8]) =
                *(const int4*)(X + ((size_t)(b * TN + t0 + tt)) * 192 + c0 + part * 8);
        }
        __syncthreads();
#pragma unroll
        for (int ks = 0; ks < 2; ++ks) {
            bfrag af = *(const bfrag*)(&Wt[w * 16 + col][ks * 32 + quad * 8]);
#pragma unroll
            for (int st = 0; st < 4; ++st) {
                bfrag bf = *(const bfrag*)(&Xt[st * 16 + col][ks * 32 + quad * 8]);
                acc[st] = __builtin_amdgcn_mfma_f32_16x16x32_bf16(af, bf, acc[st], 0, 0, 0);
            }
        }
    }

    const int mbase = m0 + w * 16 + quad * 4;
    const int proj = m0 / 192;           // block-uniform: 0=q 1=k 2=v
    const int mloc = mbase - proj * 192;
    float bs[4];
#pragma unroll
    for (int reg = 0; reg < 4; ++reg) bs[reg] = bias[mbase + reg];
#pragma unroll
    for (int st = 0; st < 4; ++st) {
        int t = t0 + st * 16 + col;
        float v[4];
#pragma unroll
        for (int reg = 0; reg < 4; ++reg) v[reg] = acc[st][reg] + bs[reg];
        if (proj < 2) {
            short* dst = (proj == 0) ? qo : ko;
            int2 pk;
            pk.x = pack2(v[0], v[1]);
            pk.y = pack2(v[2], v[3]);
            *(int2*)(dst + ((size_t)(b * TN + t)) * 192 + mloc) = pk;
        } else {
#pragma unroll
            for (int reg = 0; reg < 4; ++reg)
                vo[((size_t)b * 192 + mloc + reg) * TN + t] = f2bf(v[reg]);
        }
    }
}

// ---------------------------------------------------------------------------
// MFMA bf16 flash attention, fixed softmax shift M0S (no online rescale).
// 2 s-groups x 4 waves (512 thr); group g covers s in [g*512, g*512+512).
// p = exp(score - M0S); l accumulated per-lane, reduced once at end; group
// merge is a plain add. Masked rows -> l=0 -> linv=0 -> output 0 (finite).
// Q,K bf16 t-major (B,T,192) head at +h*96; V bf16 ch-major (B,192,T);
// O bf16 t-major (B,T,192).
// ---------------------------------------------------------------------------
__global__ __launch_bounds__(512) void k_attn3(
        const short* __restrict__ Q, const short* __restrict__ K,
        const short* __restrict__ V, const float* __restrict__ relk,
        const float* __restrict__ relv, short* __restrict__ O,
        const int* __restrict__ lens) {
    __shared__ short qs[64 * QSTR];
    __shared__ short kt[2][64 * QSTR];
    __shared__ short vt[2][96 * 72];
    __shared__ short Pt[2][64 * 72];
    __shared__ float rels[64 * 12];
    __shared__ float sband[64 * 12];
    __shared__ float rvs[9 * 96];
    __shared__ float lred[64];

    const int b = blockIdx.z, h = blockIdx.y;
    const int t0 = blockIdx.x * 64;
    const int len = lens[b];
    const int tid = threadIdx.x;
    const int g = tid >> 8;          // s-group
    const int w = (tid >> 6) & 3;    // wave within group
    const int lane = tid & 63;
    const int col = lane & 15;
    const int quad = lane >> 4;

    const short* Qb = Q + ((size_t)b * TN + t0) * HN + h * KCN;
    const short* Kg = K + ((size_t)b * TN + g * 512) * HN + h * KCN;
    const short* Vg = V + ((size_t)b * HN + h * KCN) * TN + g * 512;
    short* Ob = O + (size_t)b * TN * HN + h * KCN;

    for (int i = tid; i < 768; i += 512) {
        int row = i / 12, part = i % 12;
        *(int4*)(qs + row * QSTR + part * 8) = *(const int4*)(Qb + (size_t)row * HN + part * 8);
    }
    for (int i = tid; i < 9 * 96; i += 512) rvs[i] = relv[i];
    for (int i = tid; i < 768; i += 512) sband[i] = -1e30f;
    __syncthreads();
    for (int i = tid; i < 576; i += 512) {
        int lq = i / 9, d = i % 9;
        float s = 0.f;
        const float* rk = relk + d * 96;
        const short* qrow = qs + lq * QSTR;
#pragma unroll 4
        for (int c = 0; c < 96; c += 2)
            s += bf2f(qrow[c]) * rk[c] + bf2f(qrow[c + 1]) * rk[c + 1];
        rels[lq * 12 + d] = s;
    }
    // rels/sband/rvs become visible at the first in-loop barrier pair.

    float lsum[4];
    f32x4 accv[6];
#pragma unroll
    for (int r = 0; r < 4; ++r) lsum[r] = 0.f;
#pragma unroll
    for (int n = 0; n < 6; ++n) accv[n] = (f32x4){0.f, 0.f, 0.f, 0.f};

    const int lt = tid & 255;
    for (int j = 0; j < 8; ++j) {
        const int s0 = g * 512 + j * 64;
        const bool active = s0 < len;  // group 0: always (len >= 512)
        __syncthreads();  // prev iter's Pt/vt/kt reads done
        if (active) {
            for (int i = lt; i < 768; i += 256) {
                int row = i / 12, part = i % 12;
                *(int4*)(kt[g] + row * QSTR + part * 8) =
                    *(const int4*)(Kg + ((size_t)(j * 64 + row)) * HN + part * 8);
            }
            for (int i = lt; i < 768; i += 256) {
                int c = i >> 3, part = i & 7;
                *(int4*)(vt[g] + c * 72 + part * 8) =
                    *(const int4*)(Vg + (size_t)c * TN + j * 64 + part * 8);
            }
        }
        __syncthreads();
        if (!active) continue;

        f32x4 sacc[4];
#pragma unroll
        for (int st = 0; st < 4; ++st) sacc[st] = (f32x4){0.f, 0.f, 0.f, 0.f};
#pragma unroll
        for (int ks = 0; ks < 3; ++ks) {
            bfrag af = *(const bfrag*)(qs + (w * 16 + col) * QSTR + ks * 32 + quad * 8);
#pragma unroll
            for (int st = 0; st < 4; ++st) {
                bfrag bf = *(const bfrag*)(kt[g] + (st * 16 + col) * QSTR + ks * 32 + quad * 8);
                sacc[st] = __builtin_amdgcn_mfma_f32_16x16x32_bf16(af, bf, sacc[st], 0, 0, 0);
            }
        }

#pragma unroll
        for (int reg = 0; reg < 4; ++reg) {
            const int lq = w * 16 + quad * 4 + reg;
            const int qg = t0 + lq;
#pragma unroll
            for (int st = 0; st < 4; ++st) {
                int sg = s0 + st * 16 + col;
                float v = sacc[st][reg];
                int d = sg - qg + 4;
                bool inb = (d >= 0) && (d <= 8);
                if (inb) v += rels[lq * 12 + d];
                if (sg >= len) v = -1e4f;
                if (inb) sband[lq * 12 + d] = v;
                float p = __expf(v - M0S);
                lsum[reg] += p;
                Pt[g][lq * 72 + st * 16 + col] = f2bf(p);
            }
        }
        // Pt rows w*16.. are written and read by the same wave: no barrier.
#pragma unroll
        for (int ks = 0; ks < 2; ++ks) {
            bfrag af = *(const bfrag*)(Pt[g] + (w * 16 + col) * 72 + ks * 32 + quad * 8);
#pragma unroll
            for (int nt = 0; nt < 6; ++nt) {
                bfrag bf = *(const bfrag*)(vt[g] + (nt * 16 + col) * 72 + ks * 32 + quad * 8);
                accv[nt] = __builtin_amdgcn_mfma_f32_16x16x32_bf16(af, bf, accv[nt], 0, 0, 0);
            }
        }
    }

    // one l-reduction across the 16 cols (only col bits of lane vary)
#pragma unroll
    for (int reg = 0; reg < 4; ++reg) {
        lsum[reg] += __shfl_xor(lsum[reg], 1);
        lsum[reg] += __shfl_xor(lsum[reg], 2);
        lsum[reg] += __shfl_xor(lsum[reg], 4);
        lsum[reg] += __shfl_xor(lsum[reg], 8);
    }

    __syncthreads();
    float* facc = (float*)kt;  // 64*96 fp32 = 24.6 KB fits in kt (26.6 KB)
    if (g == 1) {
#pragma unroll
        for (int reg = 0; reg < 4; ++reg) {
            const int lq = w * 16 + quad * 4 + reg;
            if (col == 0) lred[lq] = lsum[reg];
#pragma unroll
            for (int nt = 0; nt < 6; ++nt)
                facc[lq * 96 + nt * 16 + col] = accv[nt][reg];
        }
    }
    __syncthreads();
    if (g == 0) {
#pragma unroll
        for (int reg = 0; reg < 4; ++reg) {
            const int lq = w * 16 + quad * 4 + reg;
            const int qg = t0 + lq;
            float l = lsum[reg] + lred[lq];
            float linv = (l > 0.f) ? 1.f / l : 0.f;
            float pb[9];
#pragma unroll
            for (int d = 0; d < 9; ++d)
                pb[d] = __expf(sband[lq * 12 + d] - M0S) * linv;
#pragma unroll
            for (int nt = 0; nt < 6; ++nt) {
                int c = nt * 16 + col;
                float r = (accv[nt][reg] + facc[lq * 96 + c]) * linv;
#pragma unroll
                for (int d = 0; d < 9; ++d) r += pb[d] * rvs[d * 96 + c];
                Ob[(size_t)qg * HN + c] = f2bf(r);
            }
        }
    }
}

// ---------------------------------------------------------------------------
// Residual + LayerNorm: x = LN(x + y [+ y2])*g + b (fp32 in-place, ch-major)
// plus masked bf16 t-major copy xb. 32-t blocks for 2x grid.
// ---------------------------------------------------------------------------
template <bool ADD2>
__global__ __launch_bounds__(256) void k_ln(float* __restrict__ x,
        const float* __restrict__ y, const float* __restrict__ y2,
        const float* __restrict__ g, const float* __restrict__ bb,
        short* __restrict__ xb, const int* __restrict__ lens) {
    __shared__ float s[HN][33];
    __shared__ float red1[256], red2[256];
    __shared__ float mu[32], rs[32];
    const int b = blockIdx.y;
    const int t0 = blockIdx.x * 32;
    const int tid = threadIdx.x;
    const int len = lens[b];

    for (int idx = tid; idx < HN * 32; idx += 256) {
        int c = idx >> 5, tt = idx & 31;
        size_t gi = ((size_t)b * HN + c) * TN + t0 + tt;
        float v = x[gi] + y[gi];
        if (ADD2) v += y2[gi];
        s[c][tt] = v;
    }
    __syncthreads();
    int tt = tid & 31, grp = tid >> 5;  // 8 groups x 24 channels
    float sum = 0.f, sum2 = 0.f;
    for (int c = grp * 24; c < grp * 24 + 24; ++c) {
        float v = s[c][tt];
        sum += v;
        sum2 += v * v;
    }
    red1[tid] = sum;
    red2[tid] = sum2;
    __syncthreads();
    if (tid < 32) {
        float tot = 0.f, tot2 = 0.f;
#pragma unroll
        for (int gg = 0; gg < 8; ++gg) { tot += red1[gg * 32 + tid]; tot2 += red2[gg * 32 + tid]; }
        float mean = tot / (float)HN;
        float var = tot2 / (float)HN - mean * mean;
        mu[tid] = mean;
        rs[tid] = rsqrtf(var + 1e-5f);
    }
    __syncthreads();
    for (int idx = tid; idx < HN * 32; idx += 256) {
        int c = idx >> 5, t2 = idx & 31;
        float v = (s[c][t2] - mu[t2]) * rs[t2] * g[c] + bb[c];
        x[((size_t)b * HN + c) * TN + t0 + t2] = v;
    }
    for (int idx = tid; idx < 32 * 96; idx += 256) {
        int t2 = idx / 96, p = idx % 96;
        int c0 = 2 * p;
        float v0 = (s[c0][t2] - mu[t2]) * rs[t2] * g[c0] + bb[c0];
        float v1 = (s[c0 + 1][t2] - mu[t2]) * rs[t2] * g[c0 + 1] + bb[c0 + 1];
        if (t0 + t2 >= len) { v0 = 0.f; v1 = 0.f; }
        ((int*)xb)[((size_t)(b * TN + t0 + t2)) * 96 + p] = pack2(v0, v1);
    }
}

// ---------------------------------------------------------------------------
// Final: z = m + eps*exp(logs)*mask ; outputs (z, m, logs, x*mask, mask)
// ---------------------------------------------------------------------------
__global__ void k_final(const float* __restrict__ stats, const float* __restrict__ x,
        const float* __restrict__ eps, const int* __restrict__ lens,
        float* __restrict__ out) {
    int idx = blockIdx.x * 256 + threadIdx.x;
    int t = idx % TN;
    int o = (idx / TN) % OUTN;
    int b = idx / (TN * OUTN);
    float maskv = (t < lens[b]) ? 1.f : 0.f;
    const size_t S = (size_t)BN * OUTN * TN;
    float m = stats[((size_t)(b * 2 * OUTN) + o) * TN + t];
    float ls = stats[((size_t)(b * 2 * OUTN) + OUTN + o) * TN + t];
    float e = eps[idx];
    out[idx] = m + e * expf(ls) * maskv;
    out[S + idx] = m;
    out[2 * S + idx] = ls;
    out[3 * S + idx] = x[idx] * maskv;
    if (o == 0) out[4 * S + (size_t)b * TN + t] = maskv;
}

// ---------------------------------------------------------------------------
extern "C" void kernel_launch(void* const* d_in, const int* in_sizes, int n_in,
                              void* d_out, int out_size, void* d_ws, size_t ws_size,
                              hipStream_t stream) {
    const int* tok = (const int*)d_in[0];
    const int* lens = (const int*)d_in[1];
    const float* emb = (const float*)d_in[2];
    const float* qw = (const float*)d_in[3];
    const float* qb = (const float*)d_in[4];
    const float* kw = (const float*)d_in[5];
    const float* kb = (const float*)d_in[6];
    const float* vw = (const float*)d_in[7];
    const float* vb = (const float*)d_in[8];
    const float* ow = (const float*)d_in[9];
    const float* ob = (const float*)d_in[10];
    const float* relk = (const float*)d_in[11];
    const float* relv = (const float*)d_in[12];
    const float* ln1g = (const float*)d_in[13];
    const float* ln1b = (const float*)d_in[14];
    const float* f1w = (const float*)d_in[15];
    const float* f1b = (const float*)d_in[16];
    const float* f2w = (const float*)d_in[17];
    const float* f2b = (const float*)d_in[18];
    const float* ln2g = (const float*)d_in[19];
    const float* ln2b = (const float*)d_in[20];
    const float* pw = (const float*)d_in[21];
    const float* pb = (const float*)d_in[22];
    const float* eps = (const float*)d_in[23];

    const size_t BHT = (size_t)BN * HN * TN; // 1,572,864
    float* ws = (float*)d_ws;
    float* x = ws;                                   // fp32 ch-major
    float* yf = ws + BHT;                            // fp32 ch-major
    short* s_xb = (short*)(ws + 2 * BHT);            // bf16 t-major (qkv/stats in)
    short* s_ln = (short*)(ws + 2 * BHT + BHT / 2);  // bf16 t-major (f1 in)
    short* s_q  = (short*)(ws + 3 * BHT);
    short* s_k  = (short*)(ws + 3 * BHT + BHT / 2);
    float* yf2  = ws + 3 * BHT;                      // f2 partial (overlaps s_q/s_k: both dead)
    short* s_v  = (short*)(ws + 4 * BHT);
    short* s_o  = (short*)(ws + 4 * BHT + BHT / 2);
    short* s_y1 = (short*)(ws + 5 * BHT);            // f1 out (B,T,FFN)
    float* stats = ws + 5 * BHT;                     // reused after layers
    short* wqkv = (short*)(ws + 7 * BHT);            // [L][576][192]
    short* wo16 = wqkv + (size_t)LN * 3 * HN * HN;
    short* wp16 = wo16 + (size_t)LN * HN * HN;
    short* wf1_16 = wp16 + (size_t)2 * OUTN * HN;
    short* wf2_16 = wf1_16 + (size_t)LN * 3 * FFNN * HN;
    float* bqkv = (float*)(wf2_16 + (size_t)LN * 3 * FFNN * HN);  // [L][576]

    // weight conversions
    {
        int nq = LN * 576 * 192;
        k_cvt_qkv<<<dim3((nq + 255) / 256), 256, 0, stream>>>(qw, kw, vw, wqkv, nq);
        int nqb = LN * 576;
        k_cvt_qkvb<<<dim3((nqb + 255) / 256), 256, 0, stream>>>(qb, kb, vb, bqkv, nqb);
        int n1 = LN * HN * HN;
        k_cvt<<<dim3((n1 + 255) / 256), 256, 0, stream>>>(ow, wo16, n1);
        int n2 = 2 * OUTN * HN;
        k_cvt<<<dim3((n2 + 255) / 256), 256, 0, stream>>>(pw, wp16, n2);
        int n3 = LN * FFNN * HN * 3;
        k_cvtconv<<<dim3((n3 + 255) / 256), 256, 0, stream>>>(f1w, wf1_16, FFNN, HN, n3);
        k_cvtconv<<<dim3((n3 + 255) / 256), 256, 0, stream>>>(f2w, wf2_16, HN, FFNN, n3);
    }

    dim3 gemb(TN / 64, BN);
    k_embed<<<gemb, 256, 0, stream>>>(tok, lens, emb, x, s_xb);

    dim3 gproj(TN / 64, HN / 64, BN);   // 16 x 3 x 8
    dim3 gqkv(TN / 64, 9, BN);          // 16 x 9 x 8
    dim3 gf1(TN / 64, FFNN / 64, BN);   // 16 x 12 x 8
    dim3 gf2(TN / 64, 6, BN);           // 16 x 6 x 8 (3 m-tiles x 2 k-halves)
    dim3 gattn(TN / 64, NHN, BN);       // 16 x 2 x 8 (512-thread blocks)
    dim3 gln(TN / 32, BN);              // 32 x 8

    for (int i = 0; i < LN; ++i) {
        const short* qkvwi = wqkv + (size_t)i * 576 * 192;
        const float* qkvbi = bqkv + (size_t)i * 576;
        const short* owi = wo16 + (size_t)i * HN * HN;
        const short* f1wi = wf1_16 + (size_t)i * 3 * FFNN * HN;
        const short* f2wi = wf2_16 + (size_t)i * 3 * FFNN * HN;
        const float* obi = ob + (size_t)i * HN;
        const float* rki = relk + (size_t)i * 9 * KCN;
        const float* rvi = relv + (size_t)i * 9 * KCN;
        const float* l1gi = ln1g + (size_t)i * HN;
        const float* l1bi = ln1b + (size_t)i * HN;
        const float* f1bi = f1b + (size_t)i * FFNN;
        const float* f2bi = f2b + (size_t)i * HN;
        const float* l2gi = ln2g + (size_t)i * HN;
        const float* l2bi = ln2b + (size_t)i * HN;

        k_qkv<<<gqkv, 256, 0, stream>>>(qkvwi, s_xb, qkvbi, s_q, s_k, s_v);
        k_attn3<<<gattn, 512, 0, stream>>>(s_q, s_k, s_v, rki, rvi, s_o, lens);
        k_mgemm<1, false, false, 0, false><<<gproj, 256, 0, stream>>>(owi, s_o, obi, yf, nullptr, lens, HN, HN, 1.f);
        k_ln<false><<<gln, 256, 0, stream>>>(x, yf, nullptr, l1gi, l1bi, s_ln, lens);
        k_mgemm<3, true, true, 1, false><<<gf1, 256, 0, stream>>>(f1wi, s_ln, f1bi, s_y1, nullptr, lens, FFNN, HN, 1.f);
        k_mgemm<3, false, true, 0, true><<<gf2, 256, 0, stream>>>(f2wi, s_y1, f2bi, yf, yf2, lens, HN, FFNN, 1.f);
        k_ln<true><<<gln, 256, 0, stream>>>(x, yf, yf2, l2gi, l2bi, s_xb, lens);
    }

    dim3 gstat(TN / 64, (2 * OUTN) / 64, BN); // 16 x 6 x 8
    k_mgemm<1, false, true, 0, false><<<gstat, 256, 0, stream>>>(wp16, s_xb, pb, stats, nullptr, lens, 2 * OUTN, HN, 1.f);
    k_final<<<dim3((unsigned)(BHT / 256)), 256, 0, stream>>>(stats, x, eps, lens, (float*)d_out);
}

// Round 7
// 888.398 us; speedup vs baseline: 10.5849x; 1.0756x over previous
//
#include <hip/hip_runtime.h>
#include <math.h>

#define BN 8
#define TN 1024
#define HN 192
#define NHN 2
#define KCN 96
#define LN 6
#define FFNN 768
#define OUTN 192
#define QSTR 104  // kt/rbt LDS row stride in shorts: 13 granules (odd) -> conflict-free b128
#define M0S 12.0f // fixed softmax shift: scores are O(1); exp(s-12) safe to s~100

typedef short bfrag __attribute__((ext_vector_type(8)));
typedef float f32x4 __attribute__((ext_vector_type(4)));

__device__ __forceinline__ short f2bf(float f) {
    union { float f; unsigned u; } v; v.f = f;
    unsigned r = v.u + 0x7fffu + ((v.u >> 16) & 1u);
    return (short)(r >> 16);
}
__device__ __forceinline__ float bf2f(short s) {
    union { unsigned u; float f; } v;
    v.u = ((unsigned)(unsigned short)s) << 16;
    return v.f;
}
__device__ __forceinline__ int pack2(float a, float b) {
    return (int)(unsigned short)f2bf(a) | (((int)(unsigned short)f2bf(b)) << 16);
}

#define QSCALE 0.10206207261596575f  // 1/sqrt(96)

// ---------------------------------------------------------------------------
// Weight conversions
// ---------------------------------------------------------------------------
__global__ void k_cvt(const float* __restrict__ src, short* __restrict__ dst, int n) {
    int i = blockIdx.x * 256 + threadIdx.x;
    if (i < n) dst[i] = f2bf(src[i]);
}
// src [L][M][Cin][3] -> dst [L][3][M][Cin]
__global__ void k_cvtconv(const float* __restrict__ src, short* __restrict__ dst,
                          int M, int Cin, int n) {
    int i = blockIdx.x * 256 + threadIdx.x;
    if (i >= n) return;
    int tap = i % 3;
    int c = (i / 3) % Cin;
    int m = (i / (3 * Cin)) % M;
    int l = i / (3 * Cin * M);
    dst[(((size_t)l * 3 + tap) * M + m) * Cin + c] = f2bf(src[i]);
}
// qw/kw/vw [L][192][192] -> wqkv [L][576][192], q rows pre-scaled by 1/sqrt(KC)
__global__ void k_cvt_qkv(const float* __restrict__ qw, const float* __restrict__ kw,
                          const float* __restrict__ vw, short* __restrict__ dst, int n) {
    int i = blockIdx.x * 256 + threadIdx.x;
    if (i >= n) return;
    int c = i % 192;
    int r = (i / 192) % 576;
    int l = i / (192 * 576);
    float val, sc = 1.f;
    if (r < 192) { val = qw[((size_t)l * 192 + r) * 192 + c]; sc = QSCALE; }
    else if (r < 384) val = kw[((size_t)l * 192 + (r - 192)) * 192 + c];
    else val = vw[((size_t)l * 192 + (r - 384)) * 192 + c];
    dst[i] = f2bf(val * sc);
}
__global__ void k_cvt_qkvb(const float* __restrict__ qb, const float* __restrict__ kb,
                           const float* __restrict__ vb, float* __restrict__ dst, int n) {
    int i = blockIdx.x * 256 + threadIdx.x;
    if (i >= n) return;
    int r = i % 576;
    int l = i / 576;
    dst[i] = (r < 192) ? qb[l * 192 + r] * QSCALE
           : (r < 384) ? kb[l * 192 + r - 192]
                       : vb[l * 192 + r - 384];
}

// ---------------------------------------------------------------------------
// Embedding: x fp32 ch-major (B,H,T) + xb bf16 t-major (B,T,H), both masked.
// ---------------------------------------------------------------------------
__global__ __launch_bounds__(256) void k_embed(const int* __restrict__ tok,
        const int* __restrict__ lens, const float* __restrict__ emb,
        float* __restrict__ x, short* __restrict__ xb) {
    __shared__ float s[HN][65];
    const int b = blockIdx.y, t0 = blockIdx.x * 64, tid = threadIdx.x;
    const int len = lens[b];
    for (int idx = tid; idx < 64 * HN; idx += 256) {
        int tt = idx / HN, c = idx % HN;
        int t = t0 + tt;
        float v = 0.f;
        if (t < len) v = emb[tok[b * TN + t] * HN + c] * 13.856406460551018f; // sqrt(192)
        s[c][tt] = v;
    }
    __syncthreads();
    for (int idx = tid; idx < 64 * HN; idx += 256) {
        int c = idx >> 6, tt = idx & 63;
        x[((size_t)b * HN + c) * TN + t0 + tt] = s[c][tt];
    }
    for (int idx = tid; idx < 64 * 96; idx += 256) {
        int tt = idx / 96, p = idx % 96;
        ((int*)xb)[((size_t)(b * TN + t0 + tt)) * 96 + p] = pack2(s[2 * p][tt], s[2 * p + 1][tt]);
    }
}

// ---------------------------------------------------------------------------
// MFMA bf16 GEMM / K-tap SAME conv (o-proj, f1, f2, stats).
// KSPLIT2: grid.y doubled; kg selects the Cin half; kg==0 writes Yv (with
// bias), kg==1 writes the partial to Yv2 (no bias). OUTK=0 only.
// ---------------------------------------------------------------------------
template <int TAPS, bool RELU, bool MASK_OUT, int OUTK, bool KSPLIT2>
__global__ __launch_bounds__(256) void k_mgemm(
        const short* __restrict__ W, const short* __restrict__ X,
        const float* __restrict__ bias, void* __restrict__ Yv,
        float* __restrict__ Yv2,
        const int* __restrict__ lens, int M, int Cin, float oscale) {
    constexpr int P = (TAPS - 1) / 2;
    constexpr int XS = 72;
    __shared__ short Wt[TAPS][64][XS];
    __shared__ short Xt[64 + 2 * P][XS];

    const int b = blockIdx.z;
    const int mtiles = KSPLIT2 ? (gridDim.y >> 1) : gridDim.y;
    const int kg = KSPLIT2 ? (blockIdx.y / mtiles) : 0;
    const int m0 = (KSPLIT2 ? (blockIdx.y % mtiles) : blockIdx.y) * 64;
    const int t0 = blockIdx.x * 64;
    const int len = lens[b];
    const int tid = threadIdx.x;
    const int w = tid >> 6;
    const int lane = tid & 63;
    const int col = lane & 15;
    const int quad = lane >> 4;

    f32x4 acc[4];
#pragma unroll
    for (int st = 0; st < 4; ++st) acc[st] = (f32x4){0.f, 0.f, 0.f, 0.f};

    const int cbeg = KSPLIT2 ? kg * (Cin >> 1) : 0;
    const int cend = KSPLIT2 ? cbeg + (Cin >> 1) : Cin;
    for (int c0 = cbeg; c0 < cend; c0 += 64) {
        __syncthreads();
        for (int i = tid; i < TAPS * 64 * 8; i += 256) {
            int tap = i / (64 * 8);
            int mm = (i / 8) & 63;
            int part = i & 7;
            *(int4*)(&Wt[tap][mm][part * 8]) =
                *(const int4*)(W + ((size_t)tap * M + m0 + mm) * Cin + c0 + part * 8);
        }
        for (int i = tid; i < (64 + 2 * P) * 8; i += 256) {
            int tt = i >> 3;
            int part = i & 7;
            int t = t0 + tt - P;
            int4 v = {0, 0, 0, 0};
            if (t >= 0 && t < TN)
                v = *(const int4*)(X + ((size_t)b * TN + t) * Cin + c0 + part * 8);
            *(int4*)(&Xt[tt][part * 8]) = v;
        }
        __syncthreads();
#pragma unroll
        for (int ks = 0; ks < 2; ++ks) {
#pragma unroll
            for (int tap = 0; tap < TAPS; ++tap) {
                bfrag af = *(const bfrag*)(&Wt[tap][w * 16 + col][ks * 32 + quad * 8]);
#pragma unroll
                for (int st = 0; st < 4; ++st) {
                    bfrag bf = *(const bfrag*)(&Xt[st * 16 + col + tap][ks * 32 + quad * 8]);
                    acc[st] = __builtin_amdgcn_mfma_f32_16x16x32_bf16(af, bf, acc[st], 0, 0, 0);
                }
            }
        }
    }

    const int mbase = m0 + w * 16 + quad * 4;
    float bs[4];
#pragma unroll
    for (int reg = 0; reg < 4; ++reg)
        bs[reg] = (KSPLIT2 && kg) ? 0.f : bias[mbase + reg];
#pragma unroll
    for (int st = 0; st < 4; ++st) {
        int t = t0 + st * 16 + col;
        bool om = MASK_OUT && (t >= len);
        float v[4];
#pragma unroll
        for (int reg = 0; reg < 4; ++reg) {
            float u = (acc[st][reg] + bs[reg]) * oscale;
            if (RELU) u = fmaxf(u, 0.f);
            if (om) u = 0.f;
            v[reg] = u;
        }
        if (OUTK == 0) {
            float* dst = (KSPLIT2 && kg) ? Yv2 : (float*)Yv;
#pragma unroll
            for (int reg = 0; reg < 4; ++reg)
                dst[((size_t)b * M + mbase + reg) * TN + t] = v[reg];
        } else if (OUTK == 1) {
            int2 pk;
            pk.x = pack2(v[0], v[1]);
            pk.y = pack2(v[2], v[3]);
            *(int2*)((short*)Yv + ((size_t)(b * TN + t)) * M + mbase) = pk;
        } else {
#pragma unroll
            for (int reg = 0; reg < 4; ++reg)
                ((short*)Yv)[((size_t)b * M + mbase + reg) * TN + t] = f2bf(v[reg]);
        }
    }
}

// ---------------------------------------------------------------------------
// Fused QKV projection: W [576][192] (q rows pre-scaled), X bf16 t-major.
// ---------------------------------------------------------------------------
__global__ __launch_bounds__(256) void k_qkv(
        const short* __restrict__ W, const short* __restrict__ X,
        const float* __restrict__ bias, short* __restrict__ qo,
        short* __restrict__ ko, short* __restrict__ vo) {
    __shared__ short Wt[64][72];
    __shared__ short Xt[64][72];
    const int b = blockIdx.z;
    const int m0 = blockIdx.y * 64;
    const int t0 = blockIdx.x * 64;
    const int tid = threadIdx.x;
    const int w = tid >> 6;
    const int lane = tid & 63;
    const int col = lane & 15;
    const int quad = lane >> 4;

    f32x4 acc[4];
#pragma unroll
    for (int st = 0; st < 4; ++st) acc[st] = (f32x4){0.f, 0.f, 0.f, 0.f};

    for (int c0 = 0; c0 < 192; c0 += 64) {
        __syncthreads();
        for (int i = tid; i < 512; i += 256) {
            int mm = i >> 3, part = i & 7;
            *(int4*)(&Wt[mm][part * 8]) =
                *(const int4*)(W + ((size_t)(m0 + mm)) * 192 + c0 + part * 8);
        }
        for (int i = tid; i < 512; i += 256) {
            int tt = i >> 3, part = i & 7;
            *(int4*)(&Xt[tt][part * 8]) =
                *(const int4*)(X + ((size_t)(b * TN + t0 + tt)) * 192 + c0 + part * 8);
        }
        __syncthreads();
#pragma unroll
        for (int ks = 0; ks < 2; ++ks) {
            bfrag af = *(const bfrag*)(&Wt[w * 16 + col][ks * 32 + quad * 8]);
#pragma unroll
            for (int st = 0; st < 4; ++st) {
                bfrag bf = *(const bfrag*)(&Xt[st * 16 + col][ks * 32 + quad * 8]);
                acc[st] = __builtin_amdgcn_mfma_f32_16x16x32_bf16(af, bf, acc[st], 0, 0, 0);
            }
        }
    }

    const int mbase = m0 + w * 16 + quad * 4;
    const int proj = m0 / 192;           // block-uniform: 0=q 1=k 2=v
    const int mloc = mbase - proj * 192;
    float bs[4];
#pragma unroll
    for (int reg = 0; reg < 4; ++reg) bs[reg] = bias[mbase + reg];
#pragma unroll
    for (int st = 0; st < 4; ++st) {
        int t = t0 + st * 16 + col;
        float v[4];
#pragma unroll
        for (int reg = 0; reg < 4; ++reg) v[reg] = acc[st][reg] + bs[reg];
        if (proj < 2) {
            short* dst = (proj == 0) ? qo : ko;
            int2 pk;
            pk.x = pack2(v[0], v[1]);
            pk.y = pack2(v[2], v[3]);
            *(int2*)(dst + ((size_t)(b * TN + t)) * 192 + mloc) = pk;
        } else {
#pragma unroll
            for (int reg = 0; reg < 4; ++reg)
                vo[((size_t)b * 192 + mloc + reg) * TN + t] = f2bf(v[reg]);
        }
    }
}

// ---------------------------------------------------------------------------
// MFMA bf16 flash attention, partial-sum formulation.
// Block = 8 waves, 128 q-rows (wave w owns rows [w*16,w*16+16)), one s-quarter
// (256 s, 4 j-iters of 64). Fixed softmax shift M0S; no online rescale.
// Q fragments held in registers (loaded once from global); rel-k bias computed
// via 3 MFMA against a zero-padded relk B-tile. Band rel_v contribution is
// added (unnormalized) into the partial accumulator. Output: unnormalized
// bf16 partial O (per s-quarter) + fp32 partial l; k_amerge combines.
// Q,K bf16 t-major (B,T,192) head at +h*96; V bf16 ch-major (B,192,T).
// grid (8 q-tiles, h*4+sh, B).
// ---------------------------------------------------------------------------
__global__ __launch_bounds__(512, 4) void k_attn4(
        const short* __restrict__ Q, const short* __restrict__ K,
        const short* __restrict__ V, const float* __restrict__ relk,
        const float* __restrict__ relv, short* __restrict__ accP,
        float* __restrict__ lP, const int* __restrict__ lens) {
    __shared__ short kt[64 * QSTR];
    __shared__ short vt[96 * 72];
    __shared__ short Pt[128 * 72];
    __shared__ short rbt[16 * QSTR];   // relk as bf16 B-tile (rows 9..15 zero)
    __shared__ float rels[128 * 12];
    __shared__ float sband[128 * 12];
    __shared__ float rvs[9 * 96];

    const int b = blockIdx.z;
    const int h = blockIdx.y >> 2, sh = blockIdx.y & 3;
    const int t0 = blockIdx.x * 128;
    const int len = lens[b];
    const int tid = threadIdx.x;
    const int w = tid >> 6;
    const int lane = tid & 63;
    const int col = lane & 15;
    const int quad = lane >> 4;

    const short* Qb = Q + ((size_t)b * TN + t0) * HN + h * KCN;
    const short* Kb = K + ((size_t)b * TN + sh * 256) * HN + h * KCN;
    const short* Vb = V + ((size_t)b * HN + h * KCN) * TN + sh * 256;

    // Q fragments in registers: wave w's 16 q-rows
    bfrag qf[3];
#pragma unroll
    for (int ks = 0; ks < 3; ++ks)
        qf[ks] = *(const bfrag*)(Qb + (size_t)(w * 16 + col) * HN + ks * 32 + quad * 8);

    for (int i = tid; i < 9 * 96; i += 512) rvs[i] = relv[i];
    for (int i = tid; i < 16 * 96; i += 512) {
        int r = i / 96, c = i % 96;
        rbt[r * QSTR + c] = (r < 9) ? f2bf(relk[r * 96 + c]) : (short)0;
    }
    for (int i = tid; i < 128 * 12; i += 512) sband[i] = -1e30f;
    __syncthreads();

    // rels[q][d] = q . relk_d  via MFMA (cols 9..15 multiply zero rows)
    {
        f32x4 rc = (f32x4){0.f, 0.f, 0.f, 0.f};
#pragma unroll
        for (int ks = 0; ks < 3; ++ks) {
            bfrag bf = *(const bfrag*)(rbt + col * QSTR + ks * 32 + quad * 8);
            rc = __builtin_amdgcn_mfma_f32_16x16x32_bf16(qf[ks], bf, rc, 0, 0, 0);
        }
        if (col < 12) {
#pragma unroll
            for (int reg = 0; reg < 4; ++reg)
                rels[(w * 16 + quad * 4 + reg) * 12 + col] = rc[reg];
        }
    }

    float lsum[4];
    f32x4 accv[6];
#pragma unroll
    for (int r = 0; r < 4; ++r) lsum[r] = 0.f;
#pragma unroll
    for (int n = 0; n < 6; ++n) accv[n] = (f32x4){0.f, 0.f, 0.f, 0.f};

    const int rem = len - sh * 256;
    const int nj = (rem <= 0) ? 0 : ((rem >= 256) ? 4 : ((rem + 63) >> 6));

    for (int j = 0; j < nj; ++j) {
        const int s0g = sh * 256 + j * 64;
        __syncthreads();  // prev iter's kt/vt reads done (also covers rels/rbt)
        for (int i = tid; i < 768; i += 512) {
            int row = i / 12, part = i % 12;
            *(int4*)(kt + row * QSTR + part * 8) =
                *(const int4*)(Kb + ((size_t)(j * 64 + row)) * HN + part * 8);
        }
        for (int i = tid; i < 768; i += 512) {
            int c = i >> 3, part = i & 7;
            *(int4*)(vt + c * 72 + part * 8) =
                *(const int4*)(Vb + (size_t)c * TN + j * 64 + part * 8);
        }
        __syncthreads();

        f32x4 sacc[4];
#pragma unroll
        for (int st = 0; st < 4; ++st) sacc[st] = (f32x4){0.f, 0.f, 0.f, 0.f};
#pragma unroll
        for (int ks = 0; ks < 3; ++ks) {
#pragma unroll
            for (int st = 0; st < 4; ++st) {
                bfrag bf = *(const bfrag*)(kt + (st * 16 + col) * QSTR + ks * 32 + quad * 8);
                sacc[st] = __builtin_amdgcn_mfma_f32_16x16x32_bf16(qf[ks], bf, sacc[st], 0, 0, 0);
            }
        }

#pragma unroll
        for (int reg = 0; reg < 4; ++reg) {
            const int lq = w * 16 + quad * 4 + reg;
            const int qg = t0 + lq;
#pragma unroll
            for (int st = 0; st < 4; ++st) {
                int sg = s0g + st * 16 + col;
                float v = sacc[st][reg];
                int d = sg - qg + 4;
                bool inb = (d >= 0) && (d <= 8);
                if (inb) v += rels[lq * 12 + d];
                if (sg >= len) v = -1e4f;
                if (inb) sband[lq * 12 + d] = v;
                float p = __expf(v - M0S);
                lsum[reg] += p;
                Pt[lq * 72 + st * 16 + col] = f2bf(p);
            }
        }
        // Pt rows w*16.. written & read by the same wave: no barrier needed.
#pragma unroll
        for (int ks = 0; ks < 2; ++ks) {
            bfrag af = *(const bfrag*)(Pt + (w * 16 + col) * 72 + ks * 32 + quad * 8);
#pragma unroll
            for (int nt = 0; nt < 6; ++nt) {
                bfrag bf = *(const bfrag*)(vt + (nt * 16 + col) * 72 + ks * 32 + quad * 8);
                accv[nt] = __builtin_amdgcn_mfma_f32_16x16x32_bf16(af, bf, accv[nt], 0, 0, 0);
            }
        }
    }

    // l-reduction across the 16 cols (col bits of lane)
#pragma unroll
    for (int reg = 0; reg < 4; ++reg) {
        lsum[reg] += __shfl_xor(lsum[reg], 1);
        lsum[reg] += __shfl_xor(lsum[reg], 2);
        lsum[reg] += __shfl_xor(lsum[reg], 4);
        lsum[reg] += __shfl_xor(lsum[reg], 8);
    }
    __syncthreads();  // sband visibility (same-wave anyway; safety)

    short* aout = accP + (size_t)sh * BN * TN * HN;
#pragma unroll
    for (int reg = 0; reg < 4; ++reg) {
        const int lq = w * 16 + quad * 4 + reg;
        const int qg = t0 + lq;
        float pb[9];
#pragma unroll
        for (int d = 0; d < 9; ++d)
            pb[d] = __expf(sband[lq * 12 + d] - M0S);  // -1e30 -> 0 for foreign band
#pragma unroll
        for (int nt = 0; nt < 6; ++nt) {
            int c = nt * 16 + col;
            float r = accv[nt][reg];
#pragma unroll
            for (int d = 0; d < 9; ++d) r += pb[d] * rvs[d * 96 + c];
            aout[((size_t)(b * TN + qg)) * HN + h * KCN + c] = f2bf(r);
        }
        if (col == 0)
            lP[(((size_t)sh * BN + b) * NHN + h) * TN + qg] = lsum[reg];
    }
}

// ---------------------------------------------------------------------------
// Merge 4 s-quarter partials: O = (sum accP) / (sum lP), bf16 t-major.
// ---------------------------------------------------------------------------
__global__ __launch_bounds__(256) void k_amerge(const short* __restrict__ accP,
        const float* __restrict__ lP, short* __restrict__ O) {
    const int idx = blockIdx.x * 256 + threadIdx.x;  // over B*T*96 bf16-pairs
    const int p = idx % 96;
    const int t = (idx / 96) % TN;
    const int b = idx / (96 * TN);
    const int h = p / 48;
    const size_t HS = (size_t)BN * TN * HN / 2;  // ints per quarter
    float a0 = 0.f, a1 = 0.f, l = 0.f;
#pragma unroll
    for (int sh = 0; sh < 4; ++sh) {
        int v = ((const int*)accP)[HS * sh + idx];
        a0 += bf2f((short)(v & 0xffff));
        a1 += bf2f((short)(v >> 16));
        l += lP[(((size_t)sh * BN + b) * NHN + h) * TN + t];
    }
    float linv = (l > 0.f) ? 1.f / l : 0.f;
    ((int*)O)[idx] = pack2(a0 * linv, a1 * linv);
}

// ---------------------------------------------------------------------------
// Residual + LayerNorm: x = LN(x + y [+ y2])*g + b (fp32 in-place, ch-major)
// plus masked bf16 t-major copy xb. 32-t blocks.
// ---------------------------------------------------------------------------
template <bool ADD2>
__global__ __launch_bounds__(256) void k_ln(float* __restrict__ x,
        const float* __restrict__ y, const float* __restrict__ y2,
        const float* __restrict__ g, const float* __restrict__ bb,
        short* __restrict__ xb, const int* __restrict__ lens) {
    __shared__ float s[HN][33];
    __shared__ float red1[256], red2[256];
    __shared__ float mu[32], rs[32];
    const int b = blockIdx.y;
    const int t0 = blockIdx.x * 32;
    const int tid = threadIdx.x;
    const int len = lens[b];

    for (int idx = tid; idx < HN * 32; idx += 256) {
        int c = idx >> 5, tt = idx & 31;
        size_t gi = ((size_t)b * HN + c) * TN + t0 + tt;
        float v = x[gi] + y[gi];
        if (ADD2) v += y2[gi];
        s[c][tt] = v;
    }
    __syncthreads();
    int tt = tid & 31, grp = tid >> 5;  // 8 groups x 24 channels
    float sum = 0.f, sum2 = 0.f;
    for (int c = grp * 24; c < grp * 24 + 24; ++c) {
        float v = s[c][tt];
        sum += v;
        sum2 += v * v;
    }
    red1[tid] = sum;
    red2[tid] = sum2;
    __syncthreads();
    if (tid < 32) {
        float tot = 0.f, tot2 = 0.f;
#pragma unroll
        for (int gg = 0; gg < 8; ++gg) { tot += red1[gg * 32 + tid]; tot2 += red2[gg * 32 + tid]; }
        float mean = tot / (float)HN;
        float var = tot2 / (float)HN - mean * mean;
        mu[tid] = mean;
        rs[tid] = rsqrtf(var + 1e-5f);
    }
    __syncthreads();
    for (int idx = tid; idx < HN * 32; idx += 256) {
        int c = idx >> 5, t2 = idx & 31;
        float v = (s[c][t2] - mu[t2]) * rs[t2] * g[c] + bb[c];
        x[((size_t)b * HN + c) * TN + t0 + t2] = v;
    }
    for (int idx = tid; idx < 32 * 96; idx += 256) {
        int t2 = idx / 96, p = idx % 96;
        int c0 = 2 * p;
        float v0 = (s[c0][t2] - mu[t2]) * rs[t2] * g[c0] + bb[c0];
        float v1 = (s[c0 + 1][t2] - mu[t2]) * rs[t2] * g[c0 + 1] + bb[c0 + 1];
        if (t0 + t2 >= len) { v0 = 0.f; v1 = 0.f; }
        ((int*)xb)[((size_t)(b * TN + t0 + t2)) * 96 + p] = pack2(v0, v1);
    }
}

// ---------------------------------------------------------------------------
// Final: z = m + eps*exp(logs)*mask ; outputs (z, m, logs, x*mask, mask)
// ---------------------------------------------------------------------------
__global__ void k_final(const float* __restrict__ stats, const float* __restrict__ x,
        const float* __restrict__ eps, const int* __restrict__ lens,
        float* __restrict__ out) {
    int idx = blockIdx.x * 256 + threadIdx.x;
    int t = idx % TN;
    int o = (idx / TN) % OUTN;
    int b = idx / (TN * OUTN);
    float maskv = (t < lens[b]) ? 1.f : 0.f;
    const size_t S = (size_t)BN * OUTN * TN;
    float m = stats[((size_t)(b * 2 * OUTN) + o) * TN + t];
    float ls = stats[((size_t)(b * 2 * OUTN) + OUTN + o) * TN + t];
    float e = eps[idx];
    out[idx] = m + e * expf(ls) * maskv;
    out[S + idx] = m;
    out[2 * S + idx] = ls;
    out[3 * S + idx] = x[idx] * maskv;
    if (o == 0) out[4 * S + (size_t)b * TN + t] = maskv;
}

// ---------------------------------------------------------------------------
extern "C" void kernel_launch(void* const* d_in, const int* in_sizes, int n_in,
                              void* d_out, int out_size, void* d_ws, size_t ws_size,
                              hipStream_t stream) {
    const int* tok = (const int*)d_in[0];
    const int* lens = (const int*)d_in[1];
    const float* emb = (const float*)d_in[2];
    const float* qw = (const float*)d_in[3];
    const float* qb = (const float*)d_in[4];
    const float* kw = (const float*)d_in[5];
    const float* kb = (const float*)d_in[6];
    const float* vw = (const float*)d_in[7];
    const float* vb = (const float*)d_in[8];
    const float* ow = (const float*)d_in[9];
    const float* ob = (const float*)d_in[10];
    const float* relk = (const float*)d_in[11];
    const float* relv = (const float*)d_in[12];
    const float* ln1g = (const float*)d_in[13];
    const float* ln1b = (const float*)d_in[14];
    const float* f1w = (const float*)d_in[15];
    const float* f1b = (const float*)d_in[16];
    const float* f2w = (const float*)d_in[17];
    const float* f2b = (const float*)d_in[18];
    const float* ln2g = (const float*)d_in[19];
    const float* ln2b = (const float*)d_in[20];
    const float* pw = (const float*)d_in[21];
    const float* pb = (const float*)d_in[22];
    const float* eps = (const float*)d_in[23];

    const size_t BHT = (size_t)BN * HN * TN; // 1,572,864
    float* ws = (float*)d_ws;
    float* x = ws;                                   // fp32 ch-major
    float* yf = ws + BHT;                            // fp32 ch-major
    short* s_xb = (short*)(ws + 2 * BHT);            // bf16 t-major (qkv/stats in)
    short* s_ln = (short*)(ws + 2 * BHT + BHT / 2);  // bf16 t-major (f1 in)
    short* s_q  = (short*)(ws + 3 * BHT);
    short* s_k  = (short*)(ws + 3 * BHT + BHT / 2);
    float* yf2  = ws + 3 * BHT;                      // f2 partial (overlaps s_q/s_k: both dead)
    short* s_v  = (short*)(ws + 4 * BHT);
    short* s_o  = (short*)(ws + 4 * BHT + BHT / 2);
    short* accP = (short*)(ws + 5 * BHT);            // 4 x BHT shorts (attn partials)
    short* s_y1 = (short*)(ws + 5 * BHT);            // f1 out (B,T,FFN), after attn done
    float* stats = ws + 5 * BHT;                     // reused after layers
    short* wqkv = (short*)(ws + 7 * BHT);            // [L][576][192]
    short* wo16 = wqkv + (size_t)LN * 3 * HN * HN;
    short* wp16 = wo16 + (size_t)LN * HN * HN;
    short* wf1_16 = wp16 + (size_t)2 * OUTN * HN;
    short* wf2_16 = wf1_16 + (size_t)LN * 3 * FFNN * HN;
    float* bqkv = (float*)(wf2_16 + (size_t)LN * 3 * FFNN * HN);  // [L][576]
    float* lP = bqkv + (size_t)LN * 576;             // 4 x B x NH x T floats

    // weight conversions
    {
        int nq = LN * 576 * 192;
        k_cvt_qkv<<<dim3((nq + 255) / 256), 256, 0, stream>>>(qw, kw, vw, wqkv, nq);
        int nqb = LN * 576;
        k_cvt_qkvb<<<dim3((nqb + 255) / 256), 256, 0, stream>>>(qb, kb, vb, bqkv, nqb);
        int n1 = LN * HN * HN;
        k_cvt<<<dim3((n1 + 255) / 256), 256, 0, stream>>>(ow, wo16, n1);
        int n2 = 2 * OUTN * HN;
        k_cvt<<<dim3((n2 + 255) / 256), 256, 0, stream>>>(pw, wp16, n2);
        int n3 = LN * FFNN * HN * 3;
        k_cvtconv<<<dim3((n3 + 255) / 256), 256, 0, stream>>>(f1w, wf1_16, FFNN, HN, n3);
        k_cvtconv<<<dim3((n3 + 255) / 256), 256, 0, stream>>>(f2w, wf2_16, HN, FFNN, n3);
    }

    dim3 gemb(TN / 64, BN);
    k_embed<<<gemb, 256, 0, stream>>>(tok, lens, emb, x, s_xb);

    dim3 gproj(TN / 64, HN / 64, BN);   // 16 x 3 x 8
    dim3 gqkv(TN / 64, 9, BN);          // 16 x 9 x 8
    dim3 gf1(TN / 64, FFNN / 64, BN);   // 16 x 12 x 8
    dim3 gf2(TN / 64, 6, BN);           // 16 x 6 x 8 (3 m-tiles x 2 k-halves)
    dim3 gattn(TN / 128, NHN * 4, BN);  // 8 x 8 x 8 (512-thread blocks)
    dim3 gmerge((unsigned)(BN * TN * 96 / 256));
    dim3 gln(TN / 32, BN);              // 32 x 8

    for (int i = 0; i < LN; ++i) {
        const short* qkvwi = wqkv + (size_t)i * 576 * 192;
        const float* qkvbi = bqkv + (size_t)i * 576;
        const short* owi = wo16 + (size_t)i * HN * HN;
        const short* f1wi = wf1_16 + (size_t)i * 3 * FFNN * HN;
        const short* f2wi = wf2_16 + (size_t)i * 3 * FFNN * HN;
        const float* obi = ob + (size_t)i * HN;
        const float* rki = relk + (size_t)i * 9 * KCN;
        const float* rvi = relv + (size_t)i * 9 * KCN;
        const float* l1gi = ln1g + (size_t)i * HN;
        const float* l1bi = ln1b + (size_t)i * HN;
        const float* f1bi = f1b + (size_t)i * FFNN;
        const float* f2bi = f2b + (size_t)i * HN;
        const float* l2gi = ln2g + (size_t)i * HN;
        const float* l2bi = ln2b + (size_t)i * HN;

        k_qkv<<<gqkv, 256, 0, stream>>>(qkvwi, s_xb, qkvbi, s_q, s_k, s_v);
        k_attn4<<<gattn, 512, 0, stream>>>(s_q, s_k, s_v, rki, rvi, accP, lP, lens);
        k_amerge<<<gmerge, 256, 0, stream>>>(accP, lP, s_o);
        k_mgemm<1, false, false, 0, false><<<gproj, 256, 0, stream>>>(owi, s_o, obi, yf, nullptr, lens, HN, HN, 1.f);
        k_ln<false><<<gln, 256, 0, stream>>>(x, yf, nullptr, l1gi, l1bi, s_ln, lens);
        k_mgemm<3, true, true, 1, false><<<gf1, 256, 0, stream>>>(f1wi, s_ln, f1bi, s_y1, nullptr, lens, FFNN, HN, 1.f);
        k_mgemm<3, false, true, 0, true><<<gf2, 256, 0, stream>>>(f2wi, s_y1, f2bi, yf, yf2, lens, HN, FFNN, 1.f);
        k_ln<true><<<gln, 256, 0, stream>>>(x, yf, yf2, l2gi, l2bi, s_xb, lens);
    }

    dim3 gstat(TN / 64, (2 * OUTN) / 64, BN); // 16 x 6 x 8
    k_mgemm<1, false, true, 0, false><<<gstat, 256, 0, stream>>>(wp16, s_xb, pb, stats, nullptr, lens, 2 * OUTN, HN, 1.f);
    k_final<<<dim3((unsigned)(BHT / 256)), 256, 0, stream>>>(stats, x, eps, lens, (float*)d_out);
}

// Round 8
// 880.109 us; speedup vs baseline: 10.6846x; 1.0094x over previous
//
#include <hip/hip_runtime.h>
#include <math.h>

#define BN 8
#define TN 1024
#define HN 192
#define NHN 2
#define KCN 96
#define LN 6
#define FFNN 768
#define OUTN 192
#define QSTR 104  // kt/rbt LDS row stride in shorts: 13 granules (odd) -> conflict-free b128
#define GSTR 200  // k_g192 LDS row stride (192 data + pad): 25 granules (odd)
#define M0S 12.0f // fixed softmax shift: scores are O(1); exp(s-12) safe to s~100

typedef short bfrag __attribute__((ext_vector_type(8)));
typedef float f32x4 __attribute__((ext_vector_type(4)));

__device__ __forceinline__ short f2bf(float f) {
    union { float f; unsigned u; } v; v.f = f;
    unsigned r = v.u + 0x7fffu + ((v.u >> 16) & 1u);
    return (short)(r >> 16);
}
__device__ __forceinline__ float bf2f(short s) {
    union { unsigned u; float f; } v;
    v.u = ((unsigned)(unsigned short)s) << 16;
    return v.f;
}
__device__ __forceinline__ int pack2(float a, float b) {
    return (int)(unsigned short)f2bf(a) | (((int)(unsigned short)f2bf(b)) << 16);
}

#define QSCALE 0.10206207261596575f  // 1/sqrt(96)

// ---------------------------------------------------------------------------
// Weight conversions
// ---------------------------------------------------------------------------
__global__ void k_cvt(const float* __restrict__ src, short* __restrict__ dst, int n) {
    int i = blockIdx.x * 256 + threadIdx.x;
    if (i < n) dst[i] = f2bf(src[i]);
}
// src [L][M][Cin][3] -> dst [L][3][M][Cin]
__global__ void k_cvtconv(const float* __restrict__ src, short* __restrict__ dst,
                          int M, int Cin, int n) {
    int i = blockIdx.x * 256 + threadIdx.x;
    if (i >= n) return;
    int tap = i % 3;
    int c = (i / 3) % Cin;
    int m = (i / (3 * Cin)) % M;
    int l = i / (3 * Cin * M);
    dst[(((size_t)l * 3 + tap) * M + m) * Cin + c] = f2bf(src[i]);
}
// qw/kw/vw [L][192][192] -> wqkv [L][576][192], q rows pre-scaled by 1/sqrt(KC)
__global__ void k_cvt_qkv(const float* __restrict__ qw, const float* __restrict__ kw,
                          const float* __restrict__ vw, short* __restrict__ dst, int n) {
    int i = blockIdx.x * 256 + threadIdx.x;
    if (i >= n) return;
    int c = i % 192;
    int r = (i / 192) % 576;
    int l = i / (192 * 576);
    float val, sc = 1.f;
    if (r < 192) { val = qw[((size_t)l * 192 + r) * 192 + c]; sc = QSCALE; }
    else if (r < 384) val = kw[((size_t)l * 192 + (r - 192)) * 192 + c];
    else val = vw[((size_t)l * 192 + (r - 384)) * 192 + c];
    dst[i] = f2bf(val * sc);
}
__global__ void k_cvt_qkvb(const float* __restrict__ qb, const float* __restrict__ kb,
                           const float* __restrict__ vb, float* __restrict__ dst, int n) {
    int i = blockIdx.x * 256 + threadIdx.x;
    if (i >= n) return;
    int r = i % 576;
    int l = i / 576;
    dst[i] = (r < 192) ? qb[l * 192 + r] * QSCALE
           : (r < 384) ? kb[l * 192 + r - 192]
                       : vb[l * 192 + r - 384];
}

// ---------------------------------------------------------------------------
// Embedding: x fp32 ch-major (B,H,T) + xb bf16 t-major (B,T,H), both masked.
// ---------------------------------------------------------------------------
__global__ __launch_bounds__(256) void k_embed(const int* __restrict__ tok,
        const int* __restrict__ lens, const float* __restrict__ emb,
        float* __restrict__ x, short* __restrict__ xb) {
    __shared__ float s[HN][65];
    const int b = blockIdx.y, t0 = blockIdx.x * 64, tid = threadIdx.x;
    const int len = lens[b];
    for (int idx = tid; idx < 64 * HN; idx += 256) {
        int tt = idx / HN, c = idx % HN;
        int t = t0 + tt;
        float v = 0.f;
        if (t < len) v = emb[tok[b * TN + t] * HN + c] * 13.856406460551018f; // sqrt(192)
        s[c][tt] = v;
    }
    __syncthreads();
    for (int idx = tid; idx < 64 * HN; idx += 256) {
        int c = idx >> 6, tt = idx & 63;
        x[((size_t)b * HN + c) * TN + t0 + tt] = s[c][tt];
    }
    for (int idx = tid; idx < 64 * 96; idx += 256) {
        int tt = idx / 96, p = idx % 96;
        ((int*)xb)[((size_t)(b * TN + t0 + tt)) * 96 + p] = pack2(s[2 * p][tt], s[2 * p + 1][tt]);
    }
}

// ---------------------------------------------------------------------------
// Single-stage K=192 GEMM (o-proj with fused attention-partial merge; stats).
// W bf16 [M][192]; X bf16 t-major (B,T,192) OR (MERGE) 4 attn partials accP
// + partial-l lP merged on the fly. Output fp32 ch-major (B,M,T).
// 64m x 64t tile, 4 waves, one barrier pair, 24 MFMA/wave.
// ---------------------------------------------------------------------------
template <bool MERGE, bool MASK_OUT>
__global__ __launch_bounds__(256) void k_g192(
        const short* __restrict__ W, const short* __restrict__ X,
        const float* __restrict__ bias, float* __restrict__ Y,
        const short* __restrict__ accP, const float* __restrict__ lPp,
        const int* __restrict__ lens, int M) {
    __shared__ short Wt[64 * GSTR];
    __shared__ short Xt[64 * GSTR];
    __shared__ float linv[128];
    const int b = blockIdx.z, m0 = blockIdx.y * 64, t0 = blockIdx.x * 64;
    const int len = lens[b];
    const int tid = threadIdx.x;
    const int w = tid >> 6, lane = tid & 63, col = lane & 15, quad = lane >> 4;

    if (MERGE) {
        if (tid < 128) {
            int tt = tid & 63, h = tid >> 6;
            float l = 0.f;
#pragma unroll
            for (int sh = 0; sh < 4; ++sh)
                l += lPp[(((size_t)sh * BN + b) * NHN + h) * TN + t0 + tt];
            linv[tid] = (l > 0.f) ? 1.f / l : 0.f;
        }
        __syncthreads();
    }
    for (int i = tid; i < 1536; i += 256) {
        int mm = i / 24, part = i % 24;
        *(int4*)(Wt + mm * GSTR + part * 8) =
            *(const int4*)(W + ((size_t)(m0 + mm)) * 192 + part * 8);
    }
    for (int i = tid; i < 1536; i += 256) {
        int tt = i / 24, part = i % 24;
        if (!MERGE) {
            *(int4*)(Xt + tt * GSTR + part * 8) =
                *(const int4*)(X + ((size_t)(b * TN + t0 + tt)) * 192 + part * 8);
        } else {
            const size_t base = ((size_t)(b * TN + t0 + tt)) * 192 + part * 8;
            const size_t HSq = (size_t)BN * TN * HN;
            float a[8];
#pragma unroll
            for (int c = 0; c < 8; ++c) a[c] = 0.f;
#pragma unroll
            for (int sh = 0; sh < 4; ++sh) {
                int4 v = *(const int4*)(accP + sh * HSq + base);
                const short* sv = (const short*)&v;
#pragma unroll
                for (int c = 0; c < 8; ++c) a[c] += bf2f(sv[c]);
            }
            float li = linv[(part >= 12 ? 64 : 0) + tt];
            int4 o;
            int* oi = (int*)&o;
#pragma unroll
            for (int c = 0; c < 4; ++c) oi[c] = pack2(a[2 * c] * li, a[2 * c + 1] * li);
            *(int4*)(Xt + tt * GSTR + part * 8) = o;
        }
    }
    __syncthreads();

    f32x4 acc[4];
#pragma unroll
    for (int st = 0; st < 4; ++st) acc[st] = (f32x4){0.f, 0.f, 0.f, 0.f};
#pragma unroll
    for (int ks = 0; ks < 6; ++ks) {
        bfrag af = *(const bfrag*)(Wt + (w * 16 + col) * GSTR + ks * 32 + quad * 8);
#pragma unroll
        for (int st = 0; st < 4; ++st) {
            bfrag bf = *(const bfrag*)(Xt + (st * 16 + col) * GSTR + ks * 32 + quad * 8);
            acc[st] = __builtin_amdgcn_mfma_f32_16x16x32_bf16(af, bf, acc[st], 0, 0, 0);
        }
    }

    const int mbase = m0 + w * 16 + quad * 4;
    float bs[4];
#pragma unroll
    for (int reg = 0; reg < 4; ++reg) bs[reg] = bias[mbase + reg];
#pragma unroll
    for (int st = 0; st < 4; ++st) {
        int t = t0 + st * 16 + col;
        bool om = MASK_OUT && (t >= len);
#pragma unroll
        for (int reg = 0; reg < 4; ++reg) {
            float u = acc[st][reg] + bs[reg];
            if (om) u = 0.f;
            Y[((size_t)b * M + mbase + reg) * TN + t] = u;
        }
    }
}

// ---------------------------------------------------------------------------
// Single-stage fused QKV projection: W [576][192] (q pre-scaled), X bf16
// t-major. q,k -> bf16 t-major (B,T,192); v -> bf16 ch-major (B,192,T).
// ---------------------------------------------------------------------------
__global__ __launch_bounds__(256) void k_qkv2(
        const short* __restrict__ W, const short* __restrict__ X,
        const float* __restrict__ bias, short* __restrict__ qo,
        short* __restrict__ ko, short* __restrict__ vo) {
    __shared__ short Wt[64 * GSTR];
    __shared__ short Xt[64 * GSTR];
    const int b = blockIdx.z, m0 = blockIdx.y * 64, t0 = blockIdx.x * 64;
    const int tid = threadIdx.x;
    const int w = tid >> 6, lane = tid & 63, col = lane & 15, quad = lane >> 4;

    for (int i = tid; i < 1536; i += 256) {
        int mm = i / 24, part = i % 24;
        *(int4*)(Wt + mm * GSTR + part * 8) =
            *(const int4*)(W + ((size_t)(m0 + mm)) * 192 + part * 8);
    }
    for (int i = tid; i < 1536; i += 256) {
        int tt = i / 24, part = i % 24;
        *(int4*)(Xt + tt * GSTR + part * 8) =
            *(const int4*)(X + ((size_t)(b * TN + t0 + tt)) * 192 + part * 8);
    }
    __syncthreads();

    f32x4 acc[4];
#pragma unroll
    for (int st = 0; st < 4; ++st) acc[st] = (f32x4){0.f, 0.f, 0.f, 0.f};
#pragma unroll
    for (int ks = 0; ks < 6; ++ks) {
        bfrag af = *(const bfrag*)(Wt + (w * 16 + col) * GSTR + ks * 32 + quad * 8);
#pragma unroll
        for (int st = 0; st < 4; ++st) {
            bfrag bf = *(const bfrag*)(Xt + (st * 16 + col) * GSTR + ks * 32 + quad * 8);
            acc[st] = __builtin_amdgcn_mfma_f32_16x16x32_bf16(af, bf, acc[st], 0, 0, 0);
        }
    }

    const int mbase = m0 + w * 16 + quad * 4;
    const int proj = m0 / 192;           // block-uniform: 0=q 1=k 2=v
    const int mloc = mbase - proj * 192;
    float bs[4];
#pragma unroll
    for (int reg = 0; reg < 4; ++reg) bs[reg] = bias[mbase + reg];
#pragma unroll
    for (int st = 0; st < 4; ++st) {
        int t = t0 + st * 16 + col;
        float v[4];
#pragma unroll
        for (int reg = 0; reg < 4; ++reg) v[reg] = acc[st][reg] + bs[reg];
        if (proj < 2) {
            short* dst = (proj == 0) ? qo : ko;
            int2 pk;
            pk.x = pack2(v[0], v[1]);
            pk.y = pack2(v[2], v[3]);
            *(int2*)(dst + ((size_t)(b * TN + t)) * 192 + mloc) = pk;
        } else {
#pragma unroll
            for (int reg = 0; reg < 4; ++reg)
                vo[((size_t)b * 192 + mloc + reg) * TN + t] = f2bf(v[reg]);
        }
    }
}

// ---------------------------------------------------------------------------
// MFMA bf16 conv (f1, f2). TT-wide t-tiles. KSPLIT>1: grid.y = mtiles*KSPLIT;
// kg selects a Cin span; kg==0 -> Yv (with bias), kg==1 -> Yv2, kg==2 -> Yv3.
// OUTK: 0 fp32 ch-major; 1 bf16 t-major.
// ---------------------------------------------------------------------------
template <int TAPS, int TT, bool RELU, bool MASK_OUT, int OUTK, int KSPLIT>
__global__ __launch_bounds__(256) void k_mgemm(
        const short* __restrict__ W, const short* __restrict__ X,
        const float* __restrict__ bias, void* __restrict__ Yv,
        float* __restrict__ Yv2, float* __restrict__ Yv3,
        const int* __restrict__ lens, int M, int Cin) {
    constexpr int P = (TAPS - 1) / 2;
    constexpr int NST = TT / 16;
    __shared__ short Wt[TAPS][64][72];
    __shared__ short Xt[TT + 2 * P][72];

    const int b = blockIdx.z;
    const int mtiles = gridDim.y / KSPLIT;
    const int kg = blockIdx.y / mtiles;
    const int m0 = (blockIdx.y % mtiles) * 64;
    const int t0 = blockIdx.x * TT;
    const int len = lens[b];
    const int tid = threadIdx.x;
    const int w = tid >> 6;
    const int lane = tid & 63;
    const int col = lane & 15;
    const int quad = lane >> 4;

    f32x4 acc[NST];
#pragma unroll
    for (int st = 0; st < NST; ++st) acc[st] = (f32x4){0.f, 0.f, 0.f, 0.f};

    const int cspan = Cin / KSPLIT;
    const int cbeg = kg * cspan;
    const int cend = cbeg + cspan;
    for (int c0 = cbeg; c0 < cend; c0 += 64) {
        __syncthreads();
        for (int i = tid; i < TAPS * 64 * 8; i += 256) {
            int tap = i / (64 * 8);
            int mm = (i / 8) & 63;
            int part = i & 7;
            *(int4*)(&Wt[tap][mm][part * 8]) =
                *(const int4*)(W + ((size_t)tap * M + m0 + mm) * Cin + c0 + part * 8);
        }
        for (int i = tid; i < (TT + 2 * P) * 8; i += 256) {
            int tt = i >> 3;
            int part = i & 7;
            int t = t0 + tt - P;
            int4 v = {0, 0, 0, 0};
            if (t >= 0 && t < TN)
                v = *(const int4*)(X + ((size_t)b * TN + t) * Cin + c0 + part * 8);
            *(int4*)(&Xt[tt][part * 8]) = v;
        }
        __syncthreads();
#pragma unroll
        for (int ks = 0; ks < 2; ++ks) {
#pragma unroll
            for (int tap = 0; tap < TAPS; ++tap) {
                bfrag af = *(const bfrag*)(&Wt[tap][w * 16 + col][ks * 32 + quad * 8]);
#pragma unroll
                for (int st = 0; st < NST; ++st) {
                    bfrag bf = *(const bfrag*)(&Xt[st * 16 + col + tap][ks * 32 + quad * 8]);
                    acc[st] = __builtin_amdgcn_mfma_f32_16x16x32_bf16(af, bf, acc[st], 0, 0, 0);
                }
            }
        }
    }

    const int mbase = m0 + w * 16 + quad * 4;
    float bs[4];
#pragma unroll
    for (int reg = 0; reg < 4; ++reg)
        bs[reg] = (KSPLIT > 1 && kg) ? 0.f : bias[mbase + reg];
#pragma unroll
    for (int st = 0; st < NST; ++st) {
        int t = t0 + st * 16 + col;
        bool om = MASK_OUT && (t >= len);
        float v[4];
#pragma unroll
        for (int reg = 0; reg < 4; ++reg) {
            float u = acc[st][reg] + bs[reg];
            if (RELU) u = fmaxf(u, 0.f);
            if (om) u = 0.f;
            v[reg] = u;
        }
        if (OUTK == 0) {
            float* dst = (KSPLIT > 1) ? (kg == 0 ? (float*)Yv : (kg == 1 ? Yv2 : Yv3))
                                      : (float*)Yv;
#pragma unroll
            for (int reg = 0; reg < 4; ++reg)
                dst[((size_t)b * M + mbase + reg) * TN + t] = v[reg];
        } else {
            int2 pk;
            pk.x = pack2(v[0], v[1]);
            pk.y = pack2(v[2], v[3]);
            *(int2*)((short*)Yv + ((size_t)(b * TN + t)) * M + mbase) = pk;
        }
    }
}

// ---------------------------------------------------------------------------
// MFMA bf16 flash attention, partial-sum formulation (see R7 notes).
// grid (8 q-tiles, h*4+sh, B); 512 thr; outputs unnormalized bf16 partial O
// per s-quarter + fp32 partial l. Merge happens inside the o-proj GEMM.
// ---------------------------------------------------------------------------
__global__ __launch_bounds__(512, 4) void k_attn4(
        const short* __restrict__ Q, const short* __restrict__ K,
        const short* __restrict__ V, const float* __restrict__ relk,
        const float* __restrict__ relv, short* __restrict__ accP,
        float* __restrict__ lP, const int* __restrict__ lens) {
    __shared__ short kt[64 * QSTR];
    __shared__ short vt[96 * 72];
    __shared__ short Pt[128 * 72];
    __shared__ short rbt[16 * QSTR];   // relk as bf16 B-tile (rows 9..15 zero)
    __shared__ float rels[128 * 12];
    __shared__ float sband[128 * 12];
    __shared__ float rvs[9 * 96];

    const int b = blockIdx.z;
    const int h = blockIdx.y >> 2, sh = blockIdx.y & 3;
    const int t0 = blockIdx.x * 128;
    const int len = lens[b];
    const int tid = threadIdx.x;
    const int w = tid >> 6;
    const int lane = tid & 63;
    const int col = lane & 15;
    const int quad = lane >> 4;

    const short* Qb = Q + ((size_t)b * TN + t0) * HN + h * KCN;
    const short* Kb = K + ((size_t)b * TN + sh * 256) * HN + h * KCN;
    const short* Vb = V + ((size_t)b * HN + h * KCN) * TN + sh * 256;

    bfrag qf[3];
#pragma unroll
    for (int ks = 0; ks < 3; ++ks)
        qf[ks] = *(const bfrag*)(Qb + (size_t)(w * 16 + col) * HN + ks * 32 + quad * 8);

    for (int i = tid; i < 9 * 96; i += 512) rvs[i] = relv[i];
    for (int i = tid; i < 16 * 96; i += 512) {
        int r = i / 96, c = i % 96;
        rbt[r * QSTR + c] = (r < 9) ? f2bf(relk[r * 96 + c]) : (short)0;
    }
    for (int i = tid; i < 128 * 12; i += 512) sband[i] = -1e30f;
    __syncthreads();

    {
        f32x4 rc = (f32x4){0.f, 0.f, 0.f, 0.f};
#pragma unroll
        for (int ks = 0; ks < 3; ++ks) {
            bfrag bf = *(const bfrag*)(rbt + col * QSTR + ks * 32 + quad * 8);
            rc = __builtin_amdgcn_mfma_f32_16x16x32_bf16(qf[ks], bf, rc, 0, 0, 0);
        }
        if (col < 12) {
#pragma unroll
            for (int reg = 0; reg < 4; ++reg)
                rels[(w * 16 + quad * 4 + reg) * 12 + col] = rc[reg];
        }
    }

    float lsum[4];
    f32x4 accv[6];
#pragma unroll
    for (int r = 0; r < 4; ++r) lsum[r] = 0.f;
#pragma unroll
    for (int n = 0; n < 6; ++n) accv[n] = (f32x4){0.f, 0.f, 0.f, 0.f};

    const int rem = len - sh * 256;
    const int nj = (rem <= 0) ? 0 : ((rem >= 256) ? 4 : ((rem + 63) >> 6));

    for (int j = 0; j < nj; ++j) {
        const int s0g = sh * 256 + j * 64;
        __syncthreads();
        for (int i = tid; i < 768; i += 512) {
            int row = i / 12, part = i % 12;
            *(int4*)(kt + row * QSTR + part * 8) =
                *(const int4*)(Kb + ((size_t)(j * 64 + row)) * HN + part * 8);
        }
        for (int i = tid; i < 768; i += 512) {
            int c = i >> 3, part = i & 7;
            *(int4*)(vt + c * 72 + part * 8) =
                *(const int4*)(Vb + (size_t)c * TN + j * 64 + part * 8);
        }
        __syncthreads();

        f32x4 sacc[4];
#pragma unroll
        for (int st = 0; st < 4; ++st) sacc[st] = (f32x4){0.f, 0.f, 0.f, 0.f};
#pragma unroll
        for (int ks = 0; ks < 3; ++ks) {
#pragma unroll
            for (int st = 0; st < 4; ++st) {
                bfrag bf = *(const bfrag*)(kt + (st * 16 + col) * QSTR + ks * 32 + quad * 8);
                sacc[st] = __builtin_amdgcn_mfma_f32_16x16x32_bf16(qf[ks], bf, sacc[st], 0, 0, 0);
            }
        }

#pragma unroll
        for (int reg = 0; reg < 4; ++reg) {
            const int lq = w * 16 + quad * 4 + reg;
            const int qg = t0 + lq;
#pragma unroll
            for (int st = 0; st < 4; ++st) {
                int sg = s0g + st * 16 + col;
                float v = sacc[st][reg];
                int d = sg - qg + 4;
                bool inb = (d >= 0) && (d <= 8);
                if (inb) v += rels[lq * 12 + d];
                if (sg >= len) v = -1e4f;
                if (inb) sband[lq * 12 + d] = v;
                float p = __expf(v - M0S);
                lsum[reg] += p;
                Pt[lq * 72 + st * 16 + col] = f2bf(p);
            }
        }
#pragma unroll
        for (int ks = 0; ks < 2; ++ks) {
            bfrag af = *(const bfrag*)(Pt + (w * 16 + col) * 72 + ks * 32 + quad * 8);
#pragma unroll
            for (int nt = 0; nt < 6; ++nt) {
                bfrag bf = *(const bfrag*)(vt + (nt * 16 + col) * 72 + ks * 32 + quad * 8);
                accv[nt] = __builtin_amdgcn_mfma_f32_16x16x32_bf16(af, bf, accv[nt], 0, 0, 0);
            }
        }
    }

#pragma unroll
    for (int reg = 0; reg < 4; ++reg) {
        lsum[reg] += __shfl_xor(lsum[reg], 1);
        lsum[reg] += __shfl_xor(lsum[reg], 2);
        lsum[reg] += __shfl_xor(lsum[reg], 4);
        lsum[reg] += __shfl_xor(lsum[reg], 8);
    }
    __syncthreads();

    short* aout = accP + (size_t)sh * BN * TN * HN;
#pragma unroll
    for (int reg = 0; reg < 4; ++reg) {
        const int lq = w * 16 + quad * 4 + reg;
        const int qg = t0 + lq;
        float pb[9];
#pragma unroll
        for (int d = 0; d < 9; ++d)
            pb[d] = __expf(sband[lq * 12 + d] - M0S);
#pragma unroll
        for (int nt = 0; nt < 6; ++nt) {
            int c = nt * 16 + col;
            float r = accv[nt][reg];
#pragma unroll
            for (int d = 0; d < 9; ++d) r += pb[d] * rvs[d * 96 + c];
            aout[((size_t)(b * TN + qg)) * HN + h * KCN + c] = f2bf(r);
        }
        if (col == 0)
            lP[(((size_t)sh * BN + b) * NHN + h) * TN + qg] = lsum[reg];
    }
}

// ---------------------------------------------------------------------------
// Residual + LayerNorm: x = LN(x + y [+ y2 [+ y3]])*g + b, fp32 in-place;
// masked bf16 t-major copy xb. 32-t blocks.
// ---------------------------------------------------------------------------
template <int NADD>
__global__ __launch_bounds__(256) void k_ln(float* __restrict__ x,
        const float* __restrict__ y, const float* __restrict__ y2,
        const float* __restrict__ y3, const float* __restrict__ g,
        const float* __restrict__ bb, short* __restrict__ xb,
        const int* __restrict__ lens) {
    __shared__ float s[HN][33];
    __shared__ float red1[256], red2[256];
    __shared__ float mu[32], rs[32];
    const int b = blockIdx.y;
    const int t0 = blockIdx.x * 32;
    const int tid = threadIdx.x;
    const int len = lens[b];

    for (int idx = tid; idx < HN * 32; idx += 256) {
        int c = idx >> 5, tt = idx & 31;
        size_t gi = ((size_t)b * HN + c) * TN + t0 + tt;
        float v = x[gi] + y[gi];
        if (NADD >= 2) v += y2[gi];
        if (NADD >= 3) v += y3[gi];
        s[c][tt] = v;
    }
    __syncthreads();
    int tt = tid & 31, grp = tid >> 5;  // 8 groups x 24 channels
    float sum = 0.f, sum2 = 0.f;
    for (int c = grp * 24; c < grp * 24 + 24; ++c) {
        float v = s[c][tt];
        sum += v;
        sum2 += v * v;
    }
    red1[tid] = sum;
    red2[tid] = sum2;
    __syncthreads();
    if (tid < 32) {
        float tot = 0.f, tot2 = 0.f;
#pragma unroll
        for (int gg = 0; gg < 8; ++gg) { tot += red1[gg * 32 + tid]; tot2 += red2[gg * 32 + tid]; }
        float mean = tot / (float)HN;
        float var = tot2 / (float)HN - mean * mean;
        mu[tid] = mean;
        rs[tid] = rsqrtf(var + 1e-5f);
    }
    __syncthreads();
    for (int idx = tid; idx < HN * 32; idx += 256) {
        int c = idx >> 5, t2 = idx & 31;
        float v = (s[c][t2] - mu[t2]) * rs[t2] * g[c] + bb[c];
        x[((size_t)b * HN + c) * TN + t0 + t2] = v;
    }
    for (int idx = tid; idx < 32 * 96; idx += 256) {
        int t2 = idx / 96, p = idx % 96;
        int c0 = 2 * p;
        float v0 = (s[c0][t2] - mu[t2]) * rs[t2] * g[c0] + bb[c0];
        float v1 = (s[c0 + 1][t2] - mu[t2]) * rs[t2] * g[c0 + 1] + bb[c0 + 1];
        if (t0 + t2 >= len) { v0 = 0.f; v1 = 0.f; }
        ((int*)xb)[((size_t)(b * TN + t0 + t2)) * 96 + p] = pack2(v0, v1);
    }
}

// ---------------------------------------------------------------------------
// Final: z = m + eps*exp(logs)*mask ; outputs (z, m, logs, x*mask, mask)
// ---------------------------------------------------------------------------
__global__ void k_final(const float* __restrict__ stats, const float* __restrict__ x,
        const float* __restrict__ eps, const int* __restrict__ lens,
        float* __restrict__ out) {
    int idx = blockIdx.x * 256 + threadIdx.x;
    int t = idx % TN;
    int o = (idx / TN) % OUTN;
    int b = idx / (TN * OUTN);
    float maskv = (t < lens[b]) ? 1.f : 0.f;
    const size_t S = (size_t)BN * OUTN * TN;
    float m = stats[((size_t)(b * 2 * OUTN) + o) * TN + t];
    float ls = stats[((size_t)(b * 2 * OUTN) + OUTN + o) * TN + t];
    float e = eps[idx];
    out[idx] = m + e * expf(ls) * maskv;
    out[S + idx] = m;
    out[2 * S + idx] = ls;
    out[3 * S + idx] = x[idx] * maskv;
    if (o == 0) out[4 * S + (size_t)b * TN + t] = maskv;
}

// ---------------------------------------------------------------------------
extern "C" void kernel_launch(void* const* d_in, const int* in_sizes, int n_in,
                              void* d_out, int out_size, void* d_ws, size_t ws_size,
                              hipStream_t stream) {
    const int* tok = (const int*)d_in[0];
    const int* lens = (const int*)d_in[1];
    const float* emb = (const float*)d_in[2];
    const float* qw = (const float*)d_in[3];
    const float* qb = (const float*)d_in[4];
    const float* kw = (const float*)d_in[5];
    const float* kb = (const float*)d_in[6];
    const float* vw = (const float*)d_in[7];
    const float* vb = (const float*)d_in[8];
    const float* ow = (const float*)d_in[9];
    const float* ob = (const float*)d_in[10];
    const float* relk = (const float*)d_in[11];
    const float* relv = (const float*)d_in[12];
    const float* ln1g = (const float*)d_in[13];
    const float* ln1b = (const float*)d_in[14];
    const float* f1w = (const float*)d_in[15];
    const float* f1b = (const float*)d_in[16];
    const float* f2w = (const float*)d_in[17];
    const float* f2b = (const float*)d_in[18];
    const float* ln2g = (const float*)d_in[19];
    const float* ln2b = (const float*)d_in[20];
    const float* pw = (const float*)d_in[21];
    const float* pb = (const float*)d_in[22];
    const float* eps = (const float*)d_in[23];

    const size_t BHT = (size_t)BN * HN * TN; // 1,572,864
    float* ws = (float*)d_ws;
    float* x = ws;                                   // fp32 ch-major
    float* yf = ws + BHT;                            // fp32 ch-major
    short* s_xb = (short*)(ws + 2 * BHT);            // bf16 t-major (qkv/stats in)
    short* s_ln = (short*)(ws + 2 * BHT + BHT / 2);  // bf16 t-major (f1 in)
    short* s_q  = (short*)(ws + 3 * BHT);
    short* s_k  = (short*)(ws + 3 * BHT + BHT / 2);
    short* s_v  = (short*)(ws + 4 * BHT);
    float* p1   = ws + 3 * BHT;   // f2 partial kg=1 (overlays s_q/s_k: dead by then)
    float* p2   = ws + 4 * BHT;   // f2 partial kg=2 (overlays s_v + free slot)
    short* accP = (short*)(ws + 5 * BHT);            // 4 x BHT shorts (attn partials)
    short* s_y1 = (short*)(ws + 5 * BHT);            // f1 out (B,T,FFN), after attn consumed
    float* stats = ws + 5 * BHT;                     // reused after layers
    short* wqkv = (short*)(ws + 7 * BHT);            // [L][576][192]
    short* wo16 = wqkv + (size_t)LN * 3 * HN * HN;
    short* wp16 = wo16 + (size_t)LN * HN * HN;
    short* wf1_16 = wp16 + (size_t)2 * OUTN * HN;
    short* wf2_16 = wf1_16 + (size_t)LN * 3 * FFNN * HN;
    float* bqkv = (float*)(wf2_16 + (size_t)LN * 3 * FFNN * HN);  // [L][576]
    float* lP = bqkv + (size_t)LN * 576;             // 4 x B x NH x T floats

    // weight conversions
    {
        int nq = LN * 576 * 192;
        k_cvt_qkv<<<dim3((nq + 255) / 256), 256, 0, stream>>>(qw, kw, vw, wqkv, nq);
        int nqb = LN * 576;
        k_cvt_qkvb<<<dim3((nqb + 255) / 256), 256, 0, stream>>>(qb, kb, vb, bqkv, nqb);
        int n1 = LN * HN * HN;
        k_cvt<<<dim3((n1 + 255) / 256), 256, 0, stream>>>(ow, wo16, n1);
        int n2 = 2 * OUTN * HN;
        k_cvt<<<dim3((n2 + 255) / 256), 256, 0, stream>>>(pw, wp16, n2);
        int n3 = LN * FFNN * HN * 3;
        k_cvtconv<<<dim3((n3 + 255) / 256), 256, 0, stream>>>(f1w, wf1_16, FFNN, HN, n3);
        k_cvtconv<<<dim3((n3 + 255) / 256), 256, 0, stream>>>(f2w, wf2_16, HN, FFNN, n3);
    }

    dim3 gemb(TN / 64, BN);
    k_embed<<<gemb, 256, 0, stream>>>(tok, lens, emb, x, s_xb);

    dim3 gqkv(TN / 64, 9, BN);          // 16 x 9 x 8
    dim3 gattn(TN / 128, NHN * 4, BN);  // 8 x 8 x 8 (512-thread blocks)
    dim3 goproj(TN / 64, HN / 64, BN);  // 16 x 3 x 8
    dim3 gf1(TN / 128, FFNN / 64, BN);  // 8 x 12 x 8
    dim3 gf2(TN / 128, 9, BN);          // 8 x (3m x 3kg) x 8
    dim3 gln(TN / 32, BN);              // 32 x 8

    for (int i = 0; i < LN; ++i) {
        const short* qkvwi = wqkv + (size_t)i * 576 * 192;
        const float* qkvbi = bqkv + (size_t)i * 576;
        const short* owi = wo16 + (size_t)i * HN * HN;
        const short* f1wi = wf1_16 + (size_t)i * 3 * FFNN * HN;
        const short* f2wi = wf2_16 + (size_t)i * 3 * FFNN * HN;
        const float* obi = ob + (size_t)i * HN;
        const float* rki = relk + (size_t)i * 9 * KCN;
        const float* rvi = relv + (size_t)i * 9 * KCN;
        const float* l1gi = ln1g + (size_t)i * HN;
        const float* l1bi = ln1b + (size_t)i * HN;
        const float* f1bi = f1b + (size_t)i * FFNN;
        const float* f2bi = f2b + (size_t)i * HN;
        const float* l2gi = ln2g + (size_t)i * HN;
        const float* l2bi = ln2b + (size_t)i * HN;

        k_qkv2<<<gqkv, 256, 0, stream>>>(qkvwi, s_xb, qkvbi, s_q, s_k, s_v);
        k_attn4<<<gattn, 512, 0, stream>>>(s_q, s_k, s_v, rki, rvi, accP, lP, lens);
        k_g192<true, false><<<goproj, 256, 0, stream>>>(owi, nullptr, obi, yf, accP, lP, lens, HN);
        k_ln<1><<<gln, 256, 0, stream>>>(x, yf, nullptr, nullptr, l1gi, l1bi, s_ln, lens);
        k_mgemm<3, 128, true, true, 1, 1><<<gf1, 256, 0, stream>>>(f1wi, s_ln, f1bi, s_y1, nullptr, nullptr, lens, FFNN, HN);
        k_mgemm<3, 128, false, true, 0, 3><<<gf2, 256, 0, stream>>>(f2wi, s_y1, f2bi, yf, p1, p2, lens, HN, FFNN);
        k_ln<3><<<gln, 256, 0, stream>>>(x, yf, p1, p2, l2gi, l2bi, s_xb, lens);
    }

    dim3 gstat(TN / 64, (2 * OUTN) / 64, BN); // 16 x 6 x 8
    k_g192<false, true><<<gstat, 256, 0, stream>>>(wp16, s_xb, pb, stats, nullptr, nullptr, lens, 2 * OUTN);
    k_final<<<dim3((unsigned)(BHT / 256)), 256, 0, stream>>>(stats, x, eps, lens, (float*)d_out);
}

// Round 9
// 847.129 us; speedup vs baseline: 11.1005x; 1.0389x over previous
//
#include <hip/hip_runtime.h>
#include <math.h>

#define BN 8
#define TN 1024
#define HN 192
#define NHN 2
#define KCN 96
#define LN 6
#define FFNN 768
#define OUTN 192
#define QSTR 104  // kt/rbt LDS row stride in shorts: 13 granules (odd) -> conflict-free b128
#define GSTR 200  // k_g192 LDS row stride (192 data + pad): 25 granules (odd)
#define M0S 12.0f // fixed softmax shift: scores are O(1); exp(s-12) safe to s~100

typedef short bfrag __attribute__((ext_vector_type(8)));
typedef float f32x4 __attribute__((ext_vector_type(4)));

__device__ __forceinline__ short f2bf(float f) {
    union { float f; unsigned u; } v; v.f = f;
    unsigned r = v.u + 0x7fffu + ((v.u >> 16) & 1u);
    return (short)(r >> 16);
}
__device__ __forceinline__ float bf2f(short s) {
    union { unsigned u; float f; } v;
    v.u = ((unsigned)(unsigned short)s) << 16;
    return v.f;
}
__device__ __forceinline__ int pack2(float a, float b) {
    return (int)(unsigned short)f2bf(a) | (((int)(unsigned short)f2bf(b)) << 16);
}

#define QSCALE 0.10206207261596575f  // 1/sqrt(96)

// ---------------------------------------------------------------------------
// Fused weight conversions (one launch). Index ranges:
// [0,N0)   qkv fused weights -> wqkv [L][576][192], q rows pre-scaled
// [.,+N1)  qkv bias -> bqkv [L][576]
// [.,+N2)  o-proj -> wo16
// [.,+N3)  stats proj -> wp16
// [.,+N4)  f1 conv [L][M][C][3] -> [L][3][M][C]
// [.,+N4)  f2 conv likewise
// ---------------------------------------------------------------------------
__global__ void k_cvtall(const float* __restrict__ qw, const float* __restrict__ kw,
        const float* __restrict__ vw, const float* __restrict__ qb,
        const float* __restrict__ kb, const float* __restrict__ vb,
        const float* __restrict__ ow, const float* __restrict__ pw,
        const float* __restrict__ f1w, const float* __restrict__ f2w,
        short* __restrict__ wqkv, float* __restrict__ bqkv,
        short* __restrict__ wo16, short* __restrict__ wp16,
        short* __restrict__ wf1, short* __restrict__ wf2) {
    const int N0 = LN * 576 * 192;
    const int N1 = LN * 576;
    const int N2 = LN * HN * HN;
    const int N3 = 2 * OUTN * HN;
    const int N4 = LN * FFNN * HN * 3;
    int i = blockIdx.x * 256 + threadIdx.x;
    if (i < N0) {
        int c = i % 192, r = (i / 192) % 576, l = i / (192 * 576);
        float val, sc = 1.f;
        if (r < 192) { val = qw[((size_t)l * 192 + r) * 192 + c]; sc = QSCALE; }
        else if (r < 384) val = kw[((size_t)l * 192 + (r - 192)) * 192 + c];
        else val = vw[((size_t)l * 192 + (r - 384)) * 192 + c];
        wqkv[i] = f2bf(val * sc);
        return;
    }
    i -= N0;
    if (i < N1) {
        int r = i % 576, l = i / 576;
        bqkv[i] = (r < 192) ? qb[l * 192 + r] * QSCALE
                : (r < 384) ? kb[l * 192 + r - 192]
                            : vb[l * 192 + r - 384];
        return;
    }
    i -= N1;
    if (i < N2) { wo16[i] = f2bf(ow[i]); return; }
    i -= N2;
    if (i < N3) { wp16[i] = f2bf(pw[i]); return; }
    i -= N3;
    if (i < N4) {
        int tap = i % 3, c = (i / 3) % HN, m = (i / (3 * HN)) % FFNN, l = i / (3 * HN * FFNN);
        wf1[(((size_t)l * 3 + tap) * FFNN + m) * HN + c] = f2bf(f1w[i]);
        return;
    }
    i -= N4;
    if (i < N4) {
        int tap = i % 3, c = (i / 3) % FFNN, m = (i / (3 * FFNN)) % HN, l = i / (3 * FFNN * HN);
        wf2[(((size_t)l * 3 + tap) * HN + m) * FFNN + c] = f2bf(f2w[i]);
    }
}

// ---------------------------------------------------------------------------
// Embedding: x fp32 ch-major (B,H,T) + xb bf16 t-major (B,T,H), both masked.
// ---------------------------------------------------------------------------
__global__ __launch_bounds__(256) void k_embed(const int* __restrict__ tok,
        const int* __restrict__ lens, const float* __restrict__ emb,
        float* __restrict__ x, short* __restrict__ xb) {
    __shared__ float s[HN][65];
    const int b = blockIdx.y, t0 = blockIdx.x * 64, tid = threadIdx.x;
    const int len = lens[b];
    for (int idx = tid; idx < 64 * HN; idx += 256) {
        int tt = idx / HN, c = idx % HN;
        int t = t0 + tt;
        float v = 0.f;
        if (t < len) v = emb[tok[b * TN + t] * HN + c] * 13.856406460551018f; // sqrt(192)
        s[c][tt] = v;
    }
    __syncthreads();
    for (int idx = tid; idx < 64 * HN; idx += 256) {
        int c = idx >> 6, tt = idx & 63;
        x[((size_t)b * HN + c) * TN + t0 + tt] = s[c][tt];
    }
    for (int idx = tid; idx < 64 * 96; idx += 256) {
        int tt = idx / 96, p = idx % 96;
        ((int*)xb)[((size_t)(b * TN + t0 + tt)) * 96 + p] = pack2(s[2 * p][tt], s[2 * p + 1][tt]);
    }
}

// ---------------------------------------------------------------------------
// Single-stage K=192 GEMM (o-proj with fused attention-partial merge; stats).
// Masked tiles: MERGE -> plain return (stale yf never observable);
// MASK_OUT (stats) -> exact-zero fill (k_final requires it).
// ---------------------------------------------------------------------------
template <bool MERGE, bool MASK_OUT>
__global__ __launch_bounds__(256) void k_g192(
        const short* __restrict__ W, const short* __restrict__ X,
        const float* __restrict__ bias, float* __restrict__ Y,
        const short* __restrict__ accP, const float* __restrict__ lPp,
        const int* __restrict__ lens, int M) {
    __shared__ short Wt[64 * GSTR];
    __shared__ short Xt[64 * GSTR];
    __shared__ float linv[128];
    const int b = blockIdx.z, m0 = blockIdx.y * 64, t0 = blockIdx.x * 64;
    const int len = lens[b];
    const int tid = threadIdx.x;
    const int w = tid >> 6, lane = tid & 63, col = lane & 15, quad = lane >> 4;

    if (t0 >= len) {
        if (MASK_OUT) {
            const int mbase = m0 + w * 16 + quad * 4;
#pragma unroll
            for (int st = 0; st < 4; ++st) {
                int t = t0 + st * 16 + col;
#pragma unroll
                for (int reg = 0; reg < 4; ++reg)
                    Y[((size_t)b * M + mbase + reg) * TN + t] = 0.f;
            }
        }
        return;
    }

    if (MERGE) {
        if (tid < 128) {
            int tt = tid & 63, h = tid >> 6;
            float l = 0.f;
#pragma unroll
            for (int sh = 0; sh < 4; ++sh)
                l += lPp[(((size_t)sh * BN + b) * NHN + h) * TN + t0 + tt];
            linv[tid] = (l > 0.f) ? 1.f / l : 0.f;
        }
        __syncthreads();
    }
    for (int i = tid; i < 1536; i += 256) {
        int mm = i / 24, part = i % 24;
        *(int4*)(Wt + mm * GSTR + part * 8) =
            *(const int4*)(W + ((size_t)(m0 + mm)) * 192 + part * 8);
    }
    for (int i = tid; i < 1536; i += 256) {
        int tt = i / 24, part = i % 24;
        if (!MERGE) {
            *(int4*)(Xt + tt * GSTR + part * 8) =
                *(const int4*)(X + ((size_t)(b * TN + t0 + tt)) * 192 + part * 8);
        } else {
            const size_t base = ((size_t)(b * TN + t0 + tt)) * 192 + part * 8;
            const size_t HSq = (size_t)BN * TN * HN;
            float a[8];
#pragma unroll
            for (int c = 0; c < 8; ++c) a[c] = 0.f;
#pragma unroll
            for (int sh = 0; sh < 4; ++sh) {
                int4 v = *(const int4*)(accP + sh * HSq + base);
                const short* sv = (const short*)&v;
#pragma unroll
                for (int c = 0; c < 8; ++c) a[c] += bf2f(sv[c]);
            }
            float li = linv[(part >= 12 ? 64 : 0) + tt];
            int4 o;
            int* oi = (int*)&o;
#pragma unroll
            for (int c = 0; c < 4; ++c) oi[c] = pack2(a[2 * c] * li, a[2 * c + 1] * li);
            *(int4*)(Xt + tt * GSTR + part * 8) = o;
        }
    }
    __syncthreads();

    f32x4 acc[4];
#pragma unroll
    for (int st = 0; st < 4; ++st) acc[st] = (f32x4){0.f, 0.f, 0.f, 0.f};
#pragma unroll
    for (int ks = 0; ks < 6; ++ks) {
        bfrag af = *(const bfrag*)(Wt + (w * 16 + col) * GSTR + ks * 32 + quad * 8);
#pragma unroll
        for (int st = 0; st < 4; ++st) {
            bfrag bf = *(const bfrag*)(Xt + (st * 16 + col) * GSTR + ks * 32 + quad * 8);
            acc[st] = __builtin_amdgcn_mfma_f32_16x16x32_bf16(af, bf, acc[st], 0, 0, 0);
        }
    }

    const int mbase = m0 + w * 16 + quad * 4;
    float bs[4];
#pragma unroll
    for (int reg = 0; reg < 4; ++reg) bs[reg] = bias[mbase + reg];
#pragma unroll
    for (int st = 0; st < 4; ++st) {
        int t = t0 + st * 16 + col;
        bool om = MASK_OUT && (t >= len);
#pragma unroll
        for (int reg = 0; reg < 4; ++reg) {
            float u = acc[st][reg] + bs[reg];
            if (om) u = 0.f;
            Y[((size_t)b * M + mbase + reg) * TN + t] = u;
        }
    }
}

// ---------------------------------------------------------------------------
// Single-stage fused QKV projection. Masked t-tiles: zero-fill q and v
// (q rows must be finite for attention; v multiplies exact-0 p but stale
// bytes could be bf16-NaN since this region overlays fp32 partials);
// k blocks return (scores at masked s are unconditionally set to -1e4).
// ---------------------------------------------------------------------------
__global__ __launch_bounds__(256) void k_qkv2(
        const short* __restrict__ W, const short* __restrict__ X,
        const float* __restrict__ bias, short* __restrict__ qo,
        short* __restrict__ ko, short* __restrict__ vo,
        const int* __restrict__ lens) {
    __shared__ short Wt[64 * GSTR];
    __shared__ short Xt[64 * GSTR];
    const int b = blockIdx.z, m0 = blockIdx.y * 64, t0 = blockIdx.x * 64;
    const int len = lens[b];
    const int tid = threadIdx.x;
    const int w = tid >> 6, lane = tid & 63, col = lane & 15, quad = lane >> 4;
    const int proj = m0 / 192;           // block-uniform: 0=q 1=k 2=v
    const int mbase = m0 + w * 16 + quad * 4;
    const int mloc = mbase - proj * 192;

    if (t0 >= len) {
        if (proj == 1) return;
#pragma unroll
        for (int st = 0; st < 4; ++st) {
            int t = t0 + st * 16 + col;
            if (proj == 0) {
                int2 z = {0, 0};
                *(int2*)(qo + ((size_t)(b * TN + t)) * 192 + mloc) = z;
            } else {
#pragma unroll
                for (int reg = 0; reg < 4; ++reg)
                    vo[((size_t)b * 192 + mloc + reg) * TN + t] = 0;
            }
        }
        return;
    }

    for (int i = tid; i < 1536; i += 256) {
        int mm = i / 24, part = i % 24;
        *(int4*)(Wt + mm * GSTR + part * 8) =
            *(const int4*)(W + ((size_t)(m0 + mm)) * 192 + part * 8);
    }
    for (int i = tid; i < 1536; i += 256) {
        int tt = i / 24, part = i % 24;
        *(int4*)(Xt + tt * GSTR + part * 8) =
            *(const int4*)(X + ((size_t)(b * TN + t0 + tt)) * 192 + part * 8);
    }
    __syncthreads();

    f32x4 acc[4];
#pragma unroll
    for (int st = 0; st < 4; ++st) acc[st] = (f32x4){0.f, 0.f, 0.f, 0.f};
#pragma unroll
    for (int ks = 0; ks < 6; ++ks) {
        bfrag af = *(const bfrag*)(Wt + (w * 16 + col) * GSTR + ks * 32 + quad * 8);
#pragma unroll
        for (int st = 0; st < 4; ++st) {
            bfrag bf = *(const bfrag*)(Xt + (st * 16 + col) * GSTR + ks * 32 + quad * 8);
            acc[st] = __builtin_amdgcn_mfma_f32_16x16x32_bf16(af, bf, acc[st], 0, 0, 0);
        }
    }

    float bs[4];
#pragma unroll
    for (int reg = 0; reg < 4; ++reg) bs[reg] = bias[mbase + reg];
#pragma unroll
    for (int st = 0; st < 4; ++st) {
        int t = t0 + st * 16 + col;
        float v[4];
#pragma unroll
        for (int reg = 0; reg < 4; ++reg) v[reg] = acc[st][reg] + bs[reg];
        if (proj < 2) {
            short* dst = (proj == 0) ? qo : ko;
            int2 pk;
            pk.x = pack2(v[0], v[1]);
            pk.y = pack2(v[2], v[3]);
            *(int2*)(dst + ((size_t)(b * TN + t)) * 192 + mloc) = pk;
        } else {
#pragma unroll
            for (int reg = 0; reg < 4; ++reg)
                vo[((size_t)b * 192 + mloc + reg) * TN + t] = f2bf(v[reg]);
        }
    }
}

// ---------------------------------------------------------------------------
// MFMA bf16 conv (f1, f2). Masked t-tiles: zero-fill output, skip compute.
// ---------------------------------------------------------------------------
template <int TAPS, int TT, bool RELU, bool MASK_OUT, int OUTK, int KSPLIT>
__global__ __launch_bounds__(256) void k_mgemm(
        const short* __restrict__ W, const short* __restrict__ X,
        const float* __restrict__ bias, void* __restrict__ Yv,
        float* __restrict__ Yv2, float* __restrict__ Yv3,
        const int* __restrict__ lens, int M, int Cin) {
    constexpr int P = (TAPS - 1) / 2;
    constexpr int NST = TT / 16;
    __shared__ short Wt[TAPS][64][72];
    __shared__ short Xt[TT + 2 * P][72];

    const int b = blockIdx.z;
    const int mtiles = gridDim.y / KSPLIT;
    const int kg = blockIdx.y / mtiles;
    const int m0 = (blockIdx.y % mtiles) * 64;
    const int t0 = blockIdx.x * TT;
    const int len = lens[b];
    const int tid = threadIdx.x;
    const int w = tid >> 6;
    const int lane = tid & 63;
    const int col = lane & 15;
    const int quad = lane >> 4;
    const int mbase = m0 + w * 16 + quad * 4;

    if (MASK_OUT && t0 >= len) {
#pragma unroll
        for (int st = 0; st < NST; ++st) {
            int t = t0 + st * 16 + col;
            if (OUTK == 0) {
                float* dst = (KSPLIT > 1) ? (kg == 0 ? (float*)Yv : (kg == 1 ? Yv2 : Yv3))
                                          : (float*)Yv;
#pragma unroll
                for (int reg = 0; reg < 4; ++reg)
                    dst[((size_t)b * M + mbase + reg) * TN + t] = 0.f;
            } else {
                int2 z = {0, 0};
                *(int2*)((short*)Yv + ((size_t)(b * TN + t)) * M + mbase) = z;
            }
        }
        return;
    }

    f32x4 acc[NST];
#pragma unroll
    for (int st = 0; st < NST; ++st) acc[st] = (f32x4){0.f, 0.f, 0.f, 0.f};

    const int cspan = Cin / KSPLIT;
    const int cbeg = kg * cspan;
    const int cend = cbeg + cspan;
    for (int c0 = cbeg; c0 < cend; c0 += 64) {
        __syncthreads();
        for (int i = tid; i < TAPS * 64 * 8; i += 256) {
            int tap = i / (64 * 8);
            int mm = (i / 8) & 63;
            int part = i & 7;
            *(int4*)(&Wt[tap][mm][part * 8]) =
                *(const int4*)(W + ((size_t)tap * M + m0 + mm) * Cin + c0 + part * 8);
        }
        for (int i = tid; i < (TT + 2 * P) * 8; i += 256) {
            int tt = i >> 3;
            int part = i & 7;
            int t = t0 + tt - P;
            int4 v = {0, 0, 0, 0};
            if (t >= 0 && t < TN)
                v = *(const int4*)(X + ((size_t)b * TN + t) * Cin + c0 + part * 8);
            *(int4*)(&Xt[tt][part * 8]) = v;
        }
        __syncthreads();
#pragma unroll
        for (int ks = 0; ks < 2; ++ks) {
#pragma unroll
            for (int tap = 0; tap < TAPS; ++tap) {
                bfrag af = *(const bfrag*)(&Wt[tap][w * 16 + col][ks * 32 + quad * 8]);
#pragma unroll
                for (int st = 0; st < NST; ++st) {
                    bfrag bf = *(const bfrag*)(&Xt[st * 16 + col + tap][ks * 32 + quad * 8]);
                    acc[st] = __builtin_amdgcn_mfma_f32_16x16x32_bf16(af, bf, acc[st], 0, 0, 0);
                }
            }
        }
    }

    float bs[4];
#pragma unroll
    for (int reg = 0; reg < 4; ++reg)
        bs[reg] = (KSPLIT > 1 && kg) ? 0.f : bias[mbase + reg];
#pragma unroll
    for (int st = 0; st < NST; ++st) {
        int t = t0 + st * 16 + col;
        bool om = MASK_OUT && (t >= len);
        float v[4];
#pragma unroll
        for (int reg = 0; reg < 4; ++reg) {
            float u = acc[st][reg] + bs[reg];
            if (RELU) u = fmaxf(u, 0.f);
            if (om) u = 0.f;
            v[reg] = u;
        }
        if (OUTK == 0) {
            float* dst = (KSPLIT > 1) ? (kg == 0 ? (float*)Yv : (kg == 1 ? Yv2 : Yv3))
                                      : (float*)Yv;
#pragma unroll
            for (int reg = 0; reg < 4; ++reg)
                dst[((size_t)b * M + mbase + reg) * TN + t] = v[reg];
        } else {
            int2 pk;
            pk.x = pack2(v[0], v[1]);
            pk.y = pack2(v[2], v[3]);
            *(int2*)((short*)Yv + ((size_t)(b * TN + t)) * M + mbase) = pk;
        }
    }
}

// ---------------------------------------------------------------------------
// MFMA bf16 flash attention, partial-sum formulation (R7 notes).
// Masked q-tiles: write lP=0 (merge linv=0 kills stale accP) and return.
// ---------------------------------------------------------------------------
__global__ __launch_bounds__(512, 4) void k_attn4(
        const short* __restrict__ Q, const short* __restrict__ K,
        const short* __restrict__ V, const float* __restrict__ relk,
        const float* __restrict__ relv, short* __restrict__ accP,
        float* __restrict__ lP, const int* __restrict__ lens) {
    __shared__ short kt[64 * QSTR];
    __shared__ short vt[96 * 72];
    __shared__ short Pt[128 * 72];
    __shared__ short rbt[16 * QSTR];   // relk as bf16 B-tile (rows 9..15 zero)
    __shared__ float rels[128 * 12];
    __shared__ float sband[128 * 12];
    __shared__ float rvs[9 * 96];

    const int b = blockIdx.z;
    const int h = blockIdx.y >> 2, sh = blockIdx.y & 3;
    const int t0 = blockIdx.x * 128;
    const int len = lens[b];
    const int tid = threadIdx.x;
    const int w = tid >> 6;
    const int lane = tid & 63;
    const int col = lane & 15;
    const int quad = lane >> 4;

    if (t0 >= len) {
        if (tid < 128)
            lP[(((size_t)sh * BN + b) * NHN + h) * TN + t0 + tid] = 0.f;
        return;
    }

    const short* Qb = Q + ((size_t)b * TN + t0) * HN + h * KCN;
    const short* Kb = K + ((size_t)b * TN + sh * 256) * HN + h * KCN;
    const short* Vb = V + ((size_t)b * HN + h * KCN) * TN + sh * 256;

    bfrag qf[3];
#pragma unroll
    for (int ks = 0; ks < 3; ++ks)
        qf[ks] = *(const bfrag*)(Qb + (size_t)(w * 16 + col) * HN + ks * 32 + quad * 8);

    for (int i = tid; i < 9 * 96; i += 512) rvs[i] = relv[i];
    for (int i = tid; i < 16 * 96; i += 512) {
        int r = i / 96, c = i % 96;
        rbt[r * QSTR + c] = (r < 9) ? f2bf(relk[r * 96 + c]) : (short)0;
    }
    for (int i = tid; i < 128 * 12; i += 512) sband[i] = -1e30f;
    __syncthreads();

    {
        f32x4 rc = (f32x4){0.f, 0.f, 0.f, 0.f};
#pragma unroll
        for (int ks = 0; ks < 3; ++ks) {
            bfrag bf = *(const bfrag*)(rbt + col * QSTR + ks * 32 + quad * 8);
            rc = __builtin_amdgcn_mfma_f32_16x16x32_bf16(qf[ks], bf, rc, 0, 0, 0);
        }
        if (col < 12) {
#pragma unroll
            for (int reg = 0; reg < 4; ++reg)
                rels[(w * 16 + quad * 4 + reg) * 12 + col] = rc[reg];
        }
    }

    float lsum[4];
    f32x4 accv[6];
#pragma unroll
    for (int r = 0; r < 4; ++r) lsum[r] = 0.f;
#pragma unroll
    for (int n = 0; n < 6; ++n) accv[n] = (f32x4){0.f, 0.f, 0.f, 0.f};

    const int rem = len - sh * 256;
    const int nj = (rem <= 0) ? 0 : ((rem >= 256) ? 4 : ((rem + 63) >> 6));

    for (int j = 0; j < nj; ++j) {
        const int s0g = sh * 256 + j * 64;
        __syncthreads();
        for (int i = tid; i < 768; i += 512) {
            int row = i / 12, part = i % 12;
            *(int4*)(kt + row * QSTR + part * 8) =
                *(const int4*)(Kb + ((size_t)(j * 64 + row)) * HN + part * 8);
        }
        for (int i = tid; i < 768; i += 512) {
            int c = i >> 3, part = i & 7;
            *(int4*)(vt + c * 72 + part * 8) =
                *(const int4*)(Vb + (size_t)c * TN + j * 64 + part * 8);
        }
        __syncthreads();

        f32x4 sacc[4];
#pragma unroll
        for (int st = 0; st < 4; ++st) sacc[st] = (f32x4){0.f, 0.f, 0.f, 0.f};
#pragma unroll
        for (int ks = 0; ks < 3; ++ks) {
#pragma unroll
            for (int st = 0; st < 4; ++st) {
                bfrag bf = *(const bfrag*)(kt + (st * 16 + col) * QSTR + ks * 32 + quad * 8);
                sacc[st] = __builtin_amdgcn_mfma_f32_16x16x32_bf16(qf[ks], bf, sacc[st], 0, 0, 0);
            }
        }

#pragma unroll
        for (int reg = 0; reg < 4; ++reg) {
            const int lq = w * 16 + quad * 4 + reg;
            const int qg = t0 + lq;
#pragma unroll
            for (int st = 0; st < 4; ++st) {
                int sg = s0g + st * 16 + col;
                float v = sacc[st][reg];
                int d = sg - qg + 4;
                bool inb = (d >= 0) && (d <= 8);
                if (inb) v += rels[lq * 12 + d];
                if (sg >= len) v = -1e4f;
                if (inb) sband[lq * 12 + d] = v;
                float p = __expf(v - M0S);
                lsum[reg] += p;
                Pt[lq * 72 + st * 16 + col] = f2bf(p);
            }
        }
#pragma unroll
        for (int ks = 0; ks < 2; ++ks) {
            bfrag af = *(const bfrag*)(Pt + (w * 16 + col) * 72 + ks * 32 + quad * 8);
#pragma unroll
            for (int nt = 0; nt < 6; ++nt) {
                bfrag bf = *(const bfrag*)(vt + (nt * 16 + col) * 72 + ks * 32 + quad * 8);
                accv[nt] = __builtin_amdgcn_mfma_f32_16x16x32_bf16(af, bf, accv[nt], 0, 0, 0);
            }
        }
    }

#pragma unroll
    for (int reg = 0; reg < 4; ++reg) {
        lsum[reg] += __shfl_xor(lsum[reg], 1);
        lsum[reg] += __shfl_xor(lsum[reg], 2);
        lsum[reg] += __shfl_xor(lsum[reg], 4);
        lsum[reg] += __shfl_xor(lsum[reg], 8);
    }
    __syncthreads();

    short* aout = accP + (size_t)sh * BN * TN * HN;
#pragma unroll
    for (int reg = 0; reg < 4; ++reg) {
        const int lq = w * 16 + quad * 4 + reg;
        const int qg = t0 + lq;
        float pb[9];
#pragma unroll
        for (int d = 0; d < 9; ++d)
            pb[d] = __expf(sband[lq * 12 + d] - M0S);
#pragma unroll
        for (int nt = 0; nt < 6; ++nt) {
            int c = nt * 16 + col;
            float r = accv[nt][reg];
#pragma unroll
            for (int d = 0; d < 9; ++d) r += pb[d] * rvs[d * 96 + c];
            aout[((size_t)(b * TN + qg)) * HN + h * KCN + c] = f2bf(r);
        }
        if (col == 0)
            lP[(((size_t)sh * BN + b) * NHN + h) * TN + qg] = lsum[reg];
    }
}

// ---------------------------------------------------------------------------
// Residual + LayerNorm: x = LN(x + y [+ y2 [+ y3]])*g + b, fp32 in-place;
// masked bf16 t-major copy xb. Fully-masked tiles: zero xb only (x is dead).
// ---------------------------------------------------------------------------
template <int NADD>
__global__ __launch_bounds__(256) void k_ln(float* __restrict__ x,
        const float* __restrict__ y, const float* __restrict__ y2,
        const float* __restrict__ y3, const float* __restrict__ g,
        const float* __restrict__ bb, short* __restrict__ xb,
        const int* __restrict__ lens) {
    __shared__ float s[HN][33];
    __shared__ float red1[256], red2[256];
    __shared__ float mu[32], rs[32];
    const int b = blockIdx.y;
    const int t0 = blockIdx.x * 32;
    const int tid = threadIdx.x;
    const int len = lens[b];

    if (t0 >= len) {
        for (int idx = tid; idx < 32 * 96; idx += 256)
            ((int*)xb)[((size_t)(b * TN + t0 + idx / 96)) * 96 + idx % 96] = 0;
        return;
    }

    for (int idx = tid; idx < HN * 32; idx += 256) {
        int c = idx >> 5, tt = idx & 31;
        size_t gi = ((size_t)b * HN + c) * TN + t0 + tt;
        float v = x[gi] + y[gi];
        if (NADD >= 2) v += y2[gi];
        if (NADD >= 3) v += y3[gi];
        s[c][tt] = v;
    }
    __syncthreads();
    int tt = tid & 31, grp = tid >> 5;  // 8 groups x 24 channels
    float sum = 0.f, sum2 = 0.f;
    for (int c = grp * 24; c < grp * 24 + 24; ++c) {
        float v = s[c][tt];
        sum += v;
        sum2 += v * v;
    }
    red1[tid] = sum;
    red2[tid] = sum2;
    __syncthreads();
    if (tid < 32) {
        float tot = 0.f, tot2 = 0.f;
#pragma unroll
        for (int gg = 0; gg < 8; ++gg) { tot += red1[gg * 32 + tid]; tot2 += red2[gg * 32 + tid]; }
        float mean = tot / (float)HN;
        float var = tot2 / (float)HN - mean * mean;
        mu[tid] = mean;
        rs[tid] = rsqrtf(var + 1e-5f);
    }
    __syncthreads();
    for (int idx = tid; idx < HN * 32; idx += 256) {
        int c = idx >> 5, t2 = idx & 31;
        float v = (s[c][t2] - mu[t2]) * rs[t2] * g[c] + bb[c];
        x[((size_t)b * HN + c) * TN + t0 + t2] = v;
    }
    for (int idx = tid; idx < 32 * 96; idx += 256) {
        int t2 = idx / 96, p = idx % 96;
        int c0 = 2 * p;
        float v0 = (s[c0][t2] - mu[t2]) * rs[t2] * g[c0] + bb[c0];
        float v1 = (s[c0 + 1][t2] - mu[t2]) * rs[t2] * g[c0 + 1] + bb[c0 + 1];
        if (t0 + t2 >= len) { v0 = 0.f; v1 = 0.f; }
        ((int*)xb)[((size_t)(b * TN + t0 + t2)) * 96 + p] = pack2(v0, v1);
    }
}

// ---------------------------------------------------------------------------
// Final: z = m + eps*exp(logs)*mask ; outputs (z, m, logs, x*mask, mask)
// ---------------------------------------------------------------------------
__global__ void k_final(const float* __restrict__ stats, const float* __restrict__ x,
        const float* __restrict__ eps, const int* __restrict__ lens,
        float* __restrict__ out) {
    int idx = blockIdx.x * 256 + threadIdx.x;
    int t = idx % TN;
    int o = (idx / TN) % OUTN;
    int b = idx / (TN * OUTN);
    float maskv = (t < lens[b]) ? 1.f : 0.f;
    const size_t S = (size_t)BN * OUTN * TN;
    float m = stats[((size_t)(b * 2 * OUTN) + o) * TN + t];
    float ls = stats[((size_t)(b * 2 * OUTN) + OUTN + o) * TN + t];
    float e = eps[idx];
    out[idx] = m + e * expf(ls) * maskv;
    out[S + idx] = m;
    out[2 * S + idx] = ls;
    out[3 * S + idx] = x[idx] * maskv;
    if (o == 0) out[4 * S + (size_t)b * TN + t] = maskv;
}

// ---------------------------------------------------------------------------
extern "C" void kernel_launch(void* const* d_in, const int* in_sizes, int n_in,
                              void* d_out, int out_size, void* d_ws, size_t ws_size,
                              hipStream_t stream) {
    const int* tok = (const int*)d_in[0];
    const int* lens = (const int*)d_in[1];
    const float* emb = (const float*)d_in[2];
    const float* qw = (const float*)d_in[3];
    const float* qb = (const float*)d_in[4];
    const float* kw = (const float*)d_in[5];
    const float* kb = (const float*)d_in[6];
    const float* vw = (const float*)d_in[7];
    const float* vb = (const float*)d_in[8];
    const float* ow = (const float*)d_in[9];
    const float* ob = (const float*)d_in[10];
    const float* relk = (const float*)d_in[11];
    const float* relv = (const float*)d_in[12];
    const float* ln1g = (const float*)d_in[13];
    const float* ln1b = (const float*)d_in[14];
    const float* f1w = (const float*)d_in[15];
    const float* f1b = (const float*)d_in[16];
    const float* f2w = (const float*)d_in[17];
    const float* f2b = (const float*)d_in[18];
    const float* ln2g = (const float*)d_in[19];
    const float* ln2b = (const float*)d_in[20];
    const float* pw = (const float*)d_in[21];
    const float* pb = (const float*)d_in[22];
    const float* eps = (const float*)d_in[23];

    const size_t BHT = (size_t)BN * HN * TN; // 1,572,864
    float* ws = (float*)d_ws;
    float* x = ws;                                   // fp32 ch-major
    float* yf = ws + BHT;                            // fp32 ch-major
    short* s_xb = (short*)(ws + 2 * BHT);            // bf16 t-major (qkv/stats in)
    short* s_ln = (short*)(ws + 2 * BHT + BHT / 2);  // bf16 t-major (f1 in)
    short* s_q  = (short*)(ws + 3 * BHT);
    short* s_k  = (short*)(ws + 3 * BHT + BHT / 2);
    short* s_v  = (short*)(ws + 4 * BHT);
    float* p1   = ws + 3 * BHT;   // f2 partial kg=1 (overlays s_q/s_k: dead by then)
    float* p2   = ws + 4 * BHT;   // f2 partial kg=2 (overlays s_v + free slot)
    short* accP = (short*)(ws + 5 * BHT);            // 4 x BHT shorts (attn partials)
    short* s_y1 = (short*)(ws + 5 * BHT);            // f1 out (B,T,FFN), after attn consumed
    float* stats = ws + 5 * BHT;                     // reused after layers
    short* wqkv = (short*)(ws + 7 * BHT);            // [L][576][192]
    short* wo16 = wqkv + (size_t)LN * 3 * HN * HN;
    short* wp16 = wo16 + (size_t)LN * HN * HN;
    short* wf1_16 = wp16 + (size_t)2 * OUTN * HN;
    short* wf2_16 = wf1_16 + (size_t)LN * 3 * FFNN * HN;
    float* bqkv = (float*)(wf2_16 + (size_t)LN * 3 * FFNN * HN);  // [L][576]
    float* lP = bqkv + (size_t)LN * 576;             // 4 x B x NH x T floats

    // fused weight conversion (single launch)
    {
        long total = (long)LN * 576 * 192 + LN * 576 + LN * HN * HN + 2 * OUTN * HN
                   + 2L * LN * FFNN * HN * 3;
        k_cvtall<<<dim3((unsigned)((total + 255) / 256)), 256, 0, stream>>>(
            qw, kw, vw, qb, kb, vb, ow, pw, f1w, f2w,
            wqkv, bqkv, wo16, wp16, wf1_16, wf2_16);
    }

    dim3 gemb(TN / 64, BN);
    k_embed<<<gemb, 256, 0, stream>>>(tok, lens, emb, x, s_xb);

    dim3 gqkv(TN / 64, 9, BN);          // 16 x 9 x 8
    dim3 gattn(TN / 128, NHN * 4, BN);  // 8 x 8 x 8 (512-thread blocks)
    dim3 goproj(TN / 64, HN / 64, BN);  // 16 x 3 x 8
    dim3 gf1(TN / 128, FFNN / 64, BN);  // 8 x 12 x 8
    dim3 gf2(TN / 128, 9, BN);          // 8 x (3m x 3kg) x 8
    dim3 gln(TN / 32, BN);              // 32 x 8

    for (int i = 0; i < LN; ++i) {
        const short* qkvwi = wqkv + (size_t)i * 576 * 192;
        const float* qkvbi = bqkv + (size_t)i * 576;
        const short* owi = wo16 + (size_t)i * HN * HN;
        const short* f1wi = wf1_16 + (size_t)i * 3 * FFNN * HN;
        const short* f2wi = wf2_16 + (size_t)i * 3 * FFNN * HN;
        const float* obi = ob + (size_t)i * HN;
        const float* rki = relk + (size_t)i * 9 * KCN;
        const float* rvi = relv + (size_t)i * 9 * KCN;
        const float* l1gi = ln1g + (size_t)i * HN;
        const float* l1bi = ln1b + (size_t)i * HN;
        const float* f1bi = f1b + (size_t)i * FFNN;
        const float* f2bi = f2b + (size_t)i * HN;
        const float* l2gi = ln2g + (size_t)i * HN;
        const float* l2bi = ln2b + (size_t)i * HN;

        k_qkv2<<<gqkv, 256, 0, stream>>>(qkvwi, s_xb, qkvbi, s_q, s_k, s_v, lens);
        k_attn4<<<gattn, 512, 0, stream>>>(s_q, s_k, s_v, rki, rvi, accP, lP, lens);
        k_g192<true, false><<<goproj, 256, 0, stream>>>(owi, nullptr, obi, yf, accP, lP, lens, HN);
        k_ln<1><<<gln, 256, 0, stream>>>(x, yf, nullptr, nullptr, l1gi, l1bi, s_ln, lens);
        k_mgemm<3, 128, true, true, 1, 1><<<gf1, 256, 0, stream>>>(f1wi, s_ln, f1bi, s_y1, nullptr, nullptr, lens, FFNN, HN);
        k_mgemm<3, 128, false, true, 0, 3><<<gf2, 256, 0, stream>>>(f2wi, s_y1, f2bi, yf, p1, p2, lens, HN, FFNN);
        k_ln<3><<<gln, 256, 0, stream>>>(x, yf, p1, p2, l2gi, l2bi, s_xb, lens);
    }

    dim3 gstat(TN / 64, (2 * OUTN) / 64, BN); // 16 x 6 x 8
    k_g192<false, true><<<gstat, 256, 0, stream>>>(wp16, s_xb, pb, stats, nullptr, nullptr, lens, 2 * OUTN);
    k_final<<<dim3((unsigned)(BHT / 256)), 256, 0, stream>>>(stats, x, eps, lens, (float*)d_out);
}